// Round 2
// baseline (1041.130 us; speedup 1.0000x reference)
//
#include <hip/hip_runtime.h>
#include <hip/hip_bf16.h>

// ---------------------------------------------------------------------------
// GNN classifier on MI355X.
//   h0 = relu([shape_emb[x0]|color_emb[x1]] @ W_in + b_in)   -> 64-entry table
//   conv1: h1 = relu( seg_sum(hltab[type[src]],dst)/deg + hrtab[type] )
//          hltab = h0tab@W1l, hrtab = h0tab@W1r + b1          (linearity)
//   conv2 by linearity:  g1 = h1@W2l, r1 = h1@W2r + b2  (dense GEMM)
//          h2 = relu( seg_sum(g1[src],dst)/deg + r1 )
//   out   = seg_sum(h2@W_out, batch)/cnt + b_out   (fused into the gather)
// Aggregations via per-call CSR (counting sort by dst) -> gathers.
// ---------------------------------------------------------------------------

__global__ void k_tab0(const float* __restrict__ se, const float* __restrict__ ce,
                       const float* __restrict__ Win, const float* __restrict__ bin,
                       float* __restrict__ h0tab) {
    int t = blockIdx.x, j = threadIdx.x;        // 64 blocks x 64 threads
    int s = t >> 3, c = t & 7;
    float acc = bin[j];
    for (int k = 0; k < 64; ++k) {
        acc += se[s * 64 + k] * Win[k * 64 + j];
        acc += ce[c * 64 + k] * Win[(64 + k) * 64 + j];
    }
    h0tab[t * 64 + j] = fmaxf(acc, 0.f);
}

__global__ void k_tab1(const float* __restrict__ h0tab, const float* __restrict__ W1l,
                       const float* __restrict__ W1r, const float* __restrict__ b1,
                       float* __restrict__ hltab, float* __restrict__ hrtab) {
    int t = blockIdx.x, j = threadIdx.x;        // 64 blocks x 64 threads
    float al = 0.f, ar = b1[j];
    for (int k = 0; k < 64; ++k) {
        float h = h0tab[t * 64 + k];
        al += h * W1l[k * 64 + j];
        ar += h * W1r[k * 64 + j];
    }
    hltab[t * 64 + j] = al;
    hrtab[t * 64 + j] = ar;
}

__global__ void k_prep(const int* __restrict__ x, const int* __restrict__ batch,
                       int* __restrict__ ntype, float* __restrict__ cnt, int n_nodes) {
    int n = blockIdx.x * 256 + threadIdx.x;
    if (n < n_nodes) {
        ntype[n] = x[2 * n] * 8 + x[2 * n + 1];
        atomicAdd(&cnt[batch[n]], 1.0f);
    }
}

__global__ void k_count(const int* __restrict__ dst, int* __restrict__ deg_i, int n_edges) {
    int e = blockIdx.x * 256 + threadIdx.x;
    if (e < n_edges) atomicAdd(&deg_i[dst[e]], 1);
}

// exclusive scan, 3-kernel two-level
__global__ void k_scan1(const int* __restrict__ deg_i, int* __restrict__ off,
                        int* __restrict__ bsum, int n) {
    __shared__ int sbuf[2][256];
    int tid = threadIdx.x;
    int i = blockIdx.x * 256 + tid;
    int d = (i < n) ? deg_i[i] : 0;
    int cur = 0;
    sbuf[0][tid] = d;
    __syncthreads();
    for (int ofs = 1; ofs < 256; ofs <<= 1) {
        int v = sbuf[cur][tid];
        if (tid >= ofs) v += sbuf[cur][tid - ofs];
        sbuf[cur ^ 1][tid] = v;
        cur ^= 1;
        __syncthreads();
    }
    if (i < n) off[i] = sbuf[cur][tid] - d;
    if (tid == 255) bsum[blockIdx.x] = sbuf[cur][tid];
}

__global__ void k_scan2(const int* __restrict__ bsum, int* __restrict__ bofs, int nb) {
    __shared__ int sbuf[2][512];
    int tid = threadIdx.x;
    int d = (tid < nb) ? bsum[tid] : 0;
    int cur = 0;
    sbuf[0][tid] = d;
    __syncthreads();
    for (int ofs = 1; ofs < 512; ofs <<= 1) {
        int v = sbuf[cur][tid];
        if (tid >= ofs) v += sbuf[cur][tid - ofs];
        sbuf[cur ^ 1][tid] = v;
        cur ^= 1;
        __syncthreads();
    }
    if (tid < nb) bofs[tid] = sbuf[cur][tid] - d;
}

__global__ void k_scan3(int* __restrict__ off, int* __restrict__ cursor,
                        const int* __restrict__ bofs, const int* __restrict__ deg_i,
                        float* __restrict__ inv, int n) {
    int i = blockIdx.x * 256 + threadIdx.x;
    if (i < n) {
        int o = off[i] + bofs[blockIdx.x];
        off[i] = o;
        cursor[i] = o;
        inv[i] = 1.0f / fmaxf((float)deg_i[i], 1.0f);
    }
}

__global__ void k_fill(const int* __restrict__ src, const int* __restrict__ dst,
                       int* __restrict__ cursor, int* __restrict__ csr, int n_edges) {
    int e = blockIdx.x * 256 + threadIdx.x;
    if (e < n_edges) {
        int pos = atomicAdd(&cursor[dst[e]], 1);
        csr[pos] = src[e];
    }
}

// conv1: wave per node (contiguous chunks), lane = feature dim, tables in LDS.
__global__ __launch_bounds__(256) void k_gather1(
    const int* __restrict__ csr, const int* __restrict__ off,
    const int* __restrict__ deg_i, const float* __restrict__ inv,
    const int* __restrict__ ntype, const float* __restrict__ hltab,
    const float* __restrict__ hrtab, float* __restrict__ h1, int n_nodes) {
    __shared__ float tl[4096];
    __shared__ float tr_[4096];
    for (int i = threadIdx.x; i < 4096; i += 256) { tl[i] = hltab[i]; tr_[i] = hrtab[i]; }
    __syncthreads();
    int lane = threadIdx.x & 63;
    int w = blockIdx.x * 4 + (threadIdx.x >> 6);
    int nw = gridDim.x * 4;
    int per = (n_nodes + nw - 1) / nw;
    int n = w * per;
    int nend = n + per; if (nend > n_nodes) nend = n_nodes;
    for (; n < nend; ++n) {
        int o = off[n], d = deg_i[n];
        float acc = 0.f;
        int i = 0;
        for (; i + 3 < d; i += 4) {
            int s0 = csr[o + i], s1 = csr[o + i + 1];
            int s2 = csr[o + i + 2], s3 = csr[o + i + 3];
            int t0 = ntype[s0], t1 = ntype[s1], t2 = ntype[s2], t3 = ntype[s3];
            acc += (tl[t0 * 64 + lane] + tl[t1 * 64 + lane]) +
                   (tl[t2 * 64 + lane] + tl[t3 * 64 + lane]);
        }
        for (; i < d; ++i) acc += tl[ntype[csr[o + i]] * 64 + lane];
        h1[(size_t)n * 64 + lane] = fmaxf(acc * inv[n] + tr_[ntype[n] * 64 + lane], 0.f);
    }
}

// dense conv2 GEMMs: g1 = h1@W2l, r1 = h1@W2r + b2. LDS-staged h1 tile + weights.
#define SH_LD 68   // 64 + 4 pad: keeps float4 alignment, 2-way (free) bank aliasing
__global__ __launch_bounds__(256) void k_lin2(
    const float* __restrict__ h1, const float* __restrict__ W2l,
    const float* __restrict__ W2r, const float* __restrict__ b2,
    float* __restrict__ g1, float* __restrict__ r1, int n_nodes) {
    __shared__ float sWl[4096];
    __shared__ float sWr[4096];
    __shared__ float sb2[64];
    __shared__ float sh[64 * SH_LD];
    int tid = threadIdx.x;
    for (int i = tid; i < 4096; i += 256) { sWl[i] = W2l[i]; sWr[i] = W2r[i]; }
    if (tid < 64) sb2[tid] = b2[tid];

    int ntile = (n_nodes + 63) >> 6;
    int tr = tid >> 4, tc = tid & 15;
    int r0 = tr * 4, c0 = tc * 4;

    for (int t = blockIdx.x; t < ntile; t += gridDim.x) {
        int n0 = t << 6;
        __syncthreads();   // weights ready (1st iter) / prev readers done
        // cooperative load of 64x64 h1 tile (float4-coalesced), zero-pad tail
        {
            int lim = (n_nodes - n0) * 16;           // valid float4s
            const float4* s4 = (const float4*)(h1 + (size_t)n0 * 64);
            for (int i = tid; i < 1024; i += 256) {
                int row = i >> 4, col = i & 15;
                float4 v = (i < lim) ? s4[i] : make_float4(0.f, 0.f, 0.f, 0.f);
                *(float4*)(sh + row * SH_LD + col * 4) = v;
            }
        }
        __syncthreads();

        float accl[4][4] = {{0.f}}, accr[4][4] = {{0.f}};
#pragma unroll
        for (int k = 0; k < 64; k += 4) {
            float4 hv[4];
#pragma unroll
            for (int i = 0; i < 4; ++i)
                hv[i] = *(const float4*)(sh + (r0 + i) * SH_LD + k);
#pragma unroll
            for (int kk = 0; kk < 4; ++kk) {
                float4 wl = *(const float4*)(sWl + (k + kk) * 64 + c0);
                float4 wr = *(const float4*)(sWr + (k + kk) * 64 + c0);
#pragma unroll
                for (int i = 0; i < 4; ++i) {
                    float h = (&hv[i].x)[kk];
                    accl[i][0] += h * wl.x; accr[i][0] += h * wr.x;
                    accl[i][1] += h * wl.y; accr[i][1] += h * wr.y;
                    accl[i][2] += h * wl.z; accr[i][2] += h * wr.z;
                    accl[i][3] += h * wl.w; accr[i][3] += h * wr.w;
                }
            }
        }
#pragma unroll
        for (int i = 0; i < 4; ++i) {
            int n = n0 + r0 + i;
            if (n < n_nodes) {
                float4 gl = make_float4(accl[i][0], accl[i][1], accl[i][2], accl[i][3]);
                float4 rr = make_float4(accr[i][0] + sb2[c0 + 0], accr[i][1] + sb2[c0 + 1],
                                        accr[i][2] + sb2[c0 + 2], accr[i][3] + sb2[c0 + 3]);
                *(float4*)(g1 + (size_t)n * 64 + c0) = gl;
                *(float4*)(r1 + (size_t)n * 64 + c0) = rr;
            }
        }
    }
}

// conv2 aggregation fused with relu, W_out projection, and graph pooling.
// Wave owns a contiguous node chunk; batch is sorted -> defer atomics until
// the graph id changes (1-2 flushes per wave).
__global__ __launch_bounds__(256) void k_gather2(
    const int* __restrict__ csr, const int* __restrict__ off,
    const int* __restrict__ deg_i, const float* __restrict__ inv,
    const float* __restrict__ g1, const float* __restrict__ r1,
    const int* __restrict__ batch, const float* __restrict__ Wout,
    float* __restrict__ outacc, int n_nodes) {
    int lane = threadIdx.x & 63;
    int w = blockIdx.x * 4 + (threadIdx.x >> 6);
    int nw = gridDim.x * 4;
    int per = (n_nodes + nw - 1) / nw;
    int n = w * per;
    int nend = n + per; if (nend > n_nodes) nend = n_nodes;
    float wo0 = Wout[lane * 2 + 0], wo1 = Wout[lane * 2 + 1];
    float p0 = 0.f, p1 = 0.f;
    int curg = (n < nend) ? (int)batch[n] : -1;
    for (; n < nend; ++n) {
        int o = off[n], d = deg_i[n];
        float acc = 0.f;
        int i = 0;
        for (; i + 3 < d; i += 4) {
            int s0 = csr[o + i], s1 = csr[o + i + 1];
            int s2 = csr[o + i + 2], s3 = csr[o + i + 3];
            float a0 = g1[(size_t)s0 * 64 + lane];
            float a1 = g1[(size_t)s1 * 64 + lane];
            float a2 = g1[(size_t)s2 * 64 + lane];
            float a3 = g1[(size_t)s3 * 64 + lane];
            acc += (a0 + a1) + (a2 + a3);
        }
        for (; i < d; ++i) acc += g1[(size_t)csr[o + i] * 64 + lane];
        float v = fmaxf(acc * inv[n] + r1[(size_t)n * 64 + lane], 0.f);
        int g = batch[n];
        if (g != curg) {            // wave-uniform branch
            float q0 = p0, q1 = p1;
#pragma unroll
            for (int m = 1; m < 64; m <<= 1) { q0 += __shfl_xor(q0, m); q1 += __shfl_xor(q1, m); }
            if (lane == 0 && curg >= 0) {
                atomicAdd(&outacc[curg * 2 + 0], q0);
                atomicAdd(&outacc[curg * 2 + 1], q1);
            }
            p0 = 0.f; p1 = 0.f; curg = g;
        }
        p0 += v * wo0;
        p1 += v * wo1;
    }
    {
        float q0 = p0, q1 = p1;
#pragma unroll
        for (int m = 1; m < 64; m <<= 1) { q0 += __shfl_xor(q0, m); q1 += __shfl_xor(q1, m); }
        if (lane == 0 && curg >= 0) {
            atomicAdd(&outacc[curg * 2 + 0], q0);
            atomicAdd(&outacc[curg * 2 + 1], q1);
        }
    }
}

__global__ void k_out(const float* __restrict__ outacc, const float* __restrict__ cnt,
                      const float* __restrict__ bout, float* __restrict__ out, int n_graphs) {
    int i = blockIdx.x * 256 + threadIdx.x;
    if (i < n_graphs * 2) {
        int g = i >> 1, c = i & 1;
        out[i] = outacc[i] / fmaxf(cnt[g], 1.0f) + bout[c];
    }
}

extern "C" void kernel_launch(void* const* d_in, const int* in_sizes, int n_in,
                              void* d_out, int out_size, void* d_ws, size_t ws_size,
                              hipStream_t stream) {
    const int* x     = (const int*)d_in[0];
    const int* ei    = (const int*)d_in[1];
    const int* batch = (const int*)d_in[2];
    const float* se   = (const float*)d_in[4];
    const float* ce   = (const float*)d_in[5];
    const float* Win  = (const float*)d_in[6];
    const float* bin  = (const float*)d_in[7];
    const float* W1l  = (const float*)d_in[8];
    const float* b1   = (const float*)d_in[9];
    const float* W1r  = (const float*)d_in[10];
    const float* W2l  = (const float*)d_in[11];
    const float* b2   = (const float*)d_in[12];
    const float* W2r  = (const float*)d_in[13];
    const float* Wout = (const float*)d_in[14];
    const float* bout = (const float*)d_in[15];
    float* out = (float*)d_out;

    int n_nodes  = in_sizes[0] / 2;
    int n_edges  = in_sizes[1] / 2;
    int n_graphs = out_size / 2;
    const int* src = ei;
    const int* dst = ei + n_edges;

    char* p = (char*)d_ws;
    auto take = [&](size_t bytes) { char* r = p; p += (bytes + 255) & ~(size_t)255; return r; };
    float* h1     = (float*)take((size_t)n_nodes * 64 * 4);
    float* g1     = (float*)take((size_t)n_nodes * 64 * 4);
    float* r1     = (float*)take((size_t)n_nodes * 64 * 4);
    int*   csr    = (int*)take((size_t)n_edges * 4);
    int*   ntype  = (int*)take((size_t)n_nodes * 4);
    int*   deg_i  = (int*)take((size_t)n_nodes * 4);
    int*   off    = (int*)take((size_t)n_nodes * 4);
    int*   cursor = (int*)take((size_t)n_nodes * 4);
    float* inv    = (float*)take((size_t)n_nodes * 4);
    int*   bsum   = (int*)take(512 * 4);
    int*   bofs   = (int*)take(512 * 4);
    float* cnt    = (float*)take((size_t)n_graphs * 4);
    float* outacc = (float*)take((size_t)n_graphs * 8);
    float* h0tab  = (float*)take(4096 * 4);
    float* hltab  = (float*)take(4096 * 4);
    float* hrtab  = (float*)take(4096 * 4);

    int nbN = (n_nodes + 255) / 256;
    int nbE = (n_edges + 255) / 256;

    hipMemsetAsync(deg_i, 0, (size_t)n_nodes * 4, stream);
    hipMemsetAsync(cnt, 0, (size_t)n_graphs * 4, stream);
    hipMemsetAsync(outacc, 0, (size_t)n_graphs * 8, stream);

    k_tab0<<<64, 64, 0, stream>>>(se, ce, Win, bin, h0tab);
    k_tab1<<<64, 64, 0, stream>>>(h0tab, W1l, W1r, b1, hltab, hrtab);
    k_prep<<<nbN, 256, 0, stream>>>(x, batch, ntype, cnt, n_nodes);
    k_count<<<nbE, 256, 0, stream>>>(dst, deg_i, n_edges);
    k_scan1<<<nbN, 256, 0, stream>>>(deg_i, off, bsum, n_nodes);
    k_scan2<<<1, 512, 0, stream>>>(bsum, bofs, nbN);
    k_scan3<<<nbN, 256, 0, stream>>>(off, cursor, bofs, deg_i, inv, n_nodes);
    k_fill<<<nbE, 256, 0, stream>>>(src, dst, cursor, csr, n_edges);
    k_gather1<<<2048, 256, 0, stream>>>(csr, off, deg_i, inv, ntype, hltab, hrtab, h1, n_nodes);
    k_lin2<<<768, 256, 0, stream>>>(h1, W2l, W2r, b2, g1, r1, n_nodes);
    k_gather2<<<2048, 256, 0, stream>>>(csr, off, deg_i, inv, g1, r1, batch, Wout,
                                        outacc, n_nodes);
    k_out<<<(n_graphs * 2 + 255) / 256, 256, 0, stream>>>(outacc, cnt, bout, out, n_graphs);
}

// Round 3
// 416.418 us; speedup vs baseline: 2.5002x; 2.5002x over previous
//
#include <hip/hip_runtime.h>
#include <hip/hip_bf16.h>

// ---------------------------------------------------------------------------
// GNN classifier on MI355X.
//   h0 = relu([shape_emb[x0]|color_emb[x1]] @ W_in + b_in)   -> 64-entry table
//   conv1: h1 = relu( seg_sum(hltab[type[src]],dst)/deg + hrtab[type] )
//          hltab = h0tab@W1l, hrtab = h0tab@W1r + b1          (linearity)
//   conv2 by linearity:  g1 = h1@W2l, r1 = h1@W2r + b2  (dense GEMM)
//          h2 = relu( seg_sum(g1[src],dst)/deg + r1 )
//   out   = seg_sum(h2@W_out, batch)/cnt + b_out   (fused into the gather)
// Aggregations via per-call CSR (counting sort by dst) -> gathers.
//
// R2 lesson (rocprof): full `#pragma unroll` on the 64-step k-loop in k_lin2
// hoisted all LDS loads -> 256 VGPRs -> scratch spills -> 1.9 GB/dispatch of
// HBM traffic. Keep the k-loop at unroll 2 (VGPR ~100, no spill).
// ---------------------------------------------------------------------------

__global__ void k_tab0(const float* __restrict__ se, const float* __restrict__ ce,
                       const float* __restrict__ Win, const float* __restrict__ bin,
                       float* __restrict__ h0tab) {
    int t = blockIdx.x, j = threadIdx.x;        // 64 blocks x 64 threads
    int s = t >> 3, c = t & 7;
    float acc = bin[j];
    for (int k = 0; k < 64; ++k) {
        acc += se[s * 64 + k] * Win[k * 64 + j];
        acc += ce[c * 64 + k] * Win[(64 + k) * 64 + j];
    }
    h0tab[t * 64 + j] = fmaxf(acc, 0.f);
}

__global__ void k_tab1(const float* __restrict__ h0tab, const float* __restrict__ W1l,
                       const float* __restrict__ W1r, const float* __restrict__ b1,
                       float* __restrict__ hltab, float* __restrict__ hrtab) {
    int t = blockIdx.x, j = threadIdx.x;        // 64 blocks x 64 threads
    float al = 0.f, ar = b1[j];
    for (int k = 0; k < 64; ++k) {
        float h = h0tab[t * 64 + k];
        al += h * W1l[k * 64 + j];
        ar += h * W1r[k * 64 + j];
    }
    hltab[t * 64 + j] = al;
    hrtab[t * 64 + j] = ar;
}

__global__ void k_prep(const int* __restrict__ x, const int* __restrict__ batch,
                       int* __restrict__ ntype, float* __restrict__ cnt, int n_nodes) {
    int n = blockIdx.x * 256 + threadIdx.x;
    if (n < n_nodes) {
        ntype[n] = x[2 * n] * 8 + x[2 * n + 1];
        atomicAdd(&cnt[batch[n]], 1.0f);
    }
}

__global__ void k_count(const int* __restrict__ dst, int* __restrict__ deg_i, int n_edges) {
    int e = blockIdx.x * 256 + threadIdx.x;
    if (e < n_edges) atomicAdd(&deg_i[dst[e]], 1);
}

// exclusive scan, 3-kernel two-level
__global__ void k_scan1(const int* __restrict__ deg_i, int* __restrict__ off,
                        int* __restrict__ bsum, int n) {
    __shared__ int sbuf[2][256];
    int tid = threadIdx.x;
    int i = blockIdx.x * 256 + tid;
    int d = (i < n) ? deg_i[i] : 0;
    int cur = 0;
    sbuf[0][tid] = d;
    __syncthreads();
    for (int ofs = 1; ofs < 256; ofs <<= 1) {
        int v = sbuf[cur][tid];
        if (tid >= ofs) v += sbuf[cur][tid - ofs];
        sbuf[cur ^ 1][tid] = v;
        cur ^= 1;
        __syncthreads();
    }
    if (i < n) off[i] = sbuf[cur][tid] - d;
    if (tid == 255) bsum[blockIdx.x] = sbuf[cur][tid];
}

__global__ void k_scan2(const int* __restrict__ bsum, int* __restrict__ bofs, int nb) {
    __shared__ int sbuf[2][512];
    int tid = threadIdx.x;
    int d = (tid < nb) ? bsum[tid] : 0;
    int cur = 0;
    sbuf[0][tid] = d;
    __syncthreads();
    for (int ofs = 1; ofs < 512; ofs <<= 1) {
        int v = sbuf[cur][tid];
        if (tid >= ofs) v += sbuf[cur][tid - ofs];
        sbuf[cur ^ 1][tid] = v;
        cur ^= 1;
        __syncthreads();
    }
    if (tid < nb) bofs[tid] = sbuf[cur][tid] - d;
}

__global__ void k_scan3(int* __restrict__ off, int* __restrict__ cursor,
                        const int* __restrict__ bofs, const int* __restrict__ deg_i,
                        float* __restrict__ inv, int n) {
    int i = blockIdx.x * 256 + threadIdx.x;
    if (i < n) {
        int o = off[i] + bofs[blockIdx.x];
        off[i] = o;
        cursor[i] = o;
        inv[i] = 1.0f / fmaxf((float)deg_i[i], 1.0f);
    }
}

__global__ void k_fill(const int* __restrict__ src, const int* __restrict__ dst,
                       int* __restrict__ cursor, int* __restrict__ csr, int n_edges) {
    int e = blockIdx.x * 256 + threadIdx.x;
    if (e < n_edges) {
        int pos = atomicAdd(&cursor[dst[e]], 1);
        csr[pos] = src[e];
    }
}

// conv1: wave per node (contiguous chunks), lane = feature dim, tables in LDS.
__global__ __launch_bounds__(256) void k_gather1(
    const int* __restrict__ csr, const int* __restrict__ off,
    const int* __restrict__ deg_i, const float* __restrict__ inv,
    const int* __restrict__ ntype, const float* __restrict__ hltab,
    const float* __restrict__ hrtab, float* __restrict__ h1, int n_nodes) {
    __shared__ float tl[4096];
    __shared__ float tr_[4096];
    for (int i = threadIdx.x; i < 4096; i += 256) { tl[i] = hltab[i]; tr_[i] = hrtab[i]; }
    __syncthreads();
    int lane = threadIdx.x & 63;
    int w = blockIdx.x * 4 + (threadIdx.x >> 6);
    int nw = gridDim.x * 4;
    int per = (n_nodes + nw - 1) / nw;
    int n = w * per;
    int nend = n + per; if (nend > n_nodes) nend = n_nodes;
    for (; n < nend; ++n) {
        int o = off[n], d = deg_i[n];
        float acc = 0.f;
        int i = 0;
        for (; i + 3 < d; i += 4) {
            int s0 = csr[o + i], s1 = csr[o + i + 1];
            int s2 = csr[o + i + 2], s3 = csr[o + i + 3];
            int t0 = ntype[s0], t1 = ntype[s1], t2 = ntype[s2], t3 = ntype[s3];
            acc += (tl[t0 * 64 + lane] + tl[t1 * 64 + lane]) +
                   (tl[t2 * 64 + lane] + tl[t3 * 64 + lane]);
        }
        for (; i < d; ++i) acc += tl[ntype[csr[o + i]] * 64 + lane];
        h1[(size_t)n * 64 + lane] = fmaxf(acc * inv[n] + tr_[ntype[n] * 64 + lane], 0.f);
    }
}

// dense conv2 GEMMs: g1 = h1@W2l, r1 = h1@W2r + b2. LDS-staged h1 tile + weights.
#define SH_LD 68   // 64 + 4 pad: keeps float4 alignment, 2-way (free) bank aliasing
__global__ __launch_bounds__(256) void k_lin2(
    const float* __restrict__ h1, const float* __restrict__ W2l,
    const float* __restrict__ W2r, const float* __restrict__ b2,
    float* __restrict__ g1, float* __restrict__ r1, int n_nodes) {
    __shared__ float sWl[4096];
    __shared__ float sWr[4096];
    __shared__ float sb2[64];
    __shared__ float sh[64 * SH_LD];
    int tid = threadIdx.x;
    for (int i = tid; i < 4096; i += 256) { sWl[i] = W2l[i]; sWr[i] = W2r[i]; }
    if (tid < 64) sb2[tid] = b2[tid];

    int ntile = (n_nodes + 63) >> 6;
    int tr = tid >> 4, tc = tid & 15;
    int r0 = tr * 4, c0 = tc * 4;

    for (int t = blockIdx.x; t < ntile; t += gridDim.x) {
        int n0 = t << 6;
        __syncthreads();   // weights ready (1st iter) / prev readers done
        // cooperative load of 64x64 h1 tile (float4-coalesced), zero-pad tail
        {
            int lim = (n_nodes - n0) * 16;           // valid float4s
            const float4* s4 = (const float4*)(h1 + (size_t)n0 * 64);
            for (int i = tid; i < 1024; i += 256) {
                int row = i >> 4, col = i & 15;
                float4 v = (i < lim) ? s4[i] : make_float4(0.f, 0.f, 0.f, 0.f);
                *(float4*)(sh + row * SH_LD + col * 4) = v;
            }
        }
        __syncthreads();

        float accl[4][4] = {{0.f}}, accr[4][4] = {{0.f}};
#pragma unroll 2            // R2: full unroll spilled (256 VGPR, 1.9GB scratch)
        for (int k = 0; k < 64; k += 4) {
            float4 hv[4];
#pragma unroll
            for (int i = 0; i < 4; ++i)
                hv[i] = *(const float4*)(sh + (r0 + i) * SH_LD + k);
#pragma unroll
            for (int kk = 0; kk < 4; ++kk) {
                float4 wl = *(const float4*)(sWl + (k + kk) * 64 + c0);
                float4 wr = *(const float4*)(sWr + (k + kk) * 64 + c0);
#pragma unroll
                for (int i = 0; i < 4; ++i) {
                    float h = (&hv[i].x)[kk];
                    accl[i][0] += h * wl.x; accr[i][0] += h * wr.x;
                    accl[i][1] += h * wl.y; accr[i][1] += h * wr.y;
                    accl[i][2] += h * wl.z; accr[i][2] += h * wr.z;
                    accl[i][3] += h * wl.w; accr[i][3] += h * wr.w;
                }
            }
        }
#pragma unroll
        for (int i = 0; i < 4; ++i) {
            int n = n0 + r0 + i;
            if (n < n_nodes) {
                float4 gl = make_float4(accl[i][0], accl[i][1], accl[i][2], accl[i][3]);
                float4 rr = make_float4(accr[i][0] + sb2[c0 + 0], accr[i][1] + sb2[c0 + 1],
                                        accr[i][2] + sb2[c0 + 2], accr[i][3] + sb2[c0 + 3]);
                *(float4*)(g1 + (size_t)n * 64 + c0) = gl;
                *(float4*)(r1 + (size_t)n * 64 + c0) = rr;
            }
        }
    }
}

// conv2 aggregation fused with relu, W_out projection, and graph pooling.
// Wave owns a contiguous node chunk; batch is sorted -> defer atomics until
// the graph id changes (1-2 flushes per wave).
__global__ __launch_bounds__(256) void k_gather2(
    const int* __restrict__ csr, const int* __restrict__ off,
    const int* __restrict__ deg_i, const float* __restrict__ inv,
    const float* __restrict__ g1, const float* __restrict__ r1,
    const int* __restrict__ batch, const float* __restrict__ Wout,
    float* __restrict__ outacc, int n_nodes) {
    int lane = threadIdx.x & 63;
    int w = blockIdx.x * 4 + (threadIdx.x >> 6);
    int nw = gridDim.x * 4;
    int per = (n_nodes + nw - 1) / nw;
    int n = w * per;
    int nend = n + per; if (nend > n_nodes) nend = n_nodes;
    float wo0 = Wout[lane * 2 + 0], wo1 = Wout[lane * 2 + 1];
    float p0 = 0.f, p1 = 0.f;
    int curg = (n < nend) ? (int)batch[n] : -1;
    for (; n < nend; ++n) {
        int o = off[n], d = deg_i[n];
        float acc = 0.f;
        int i = 0;
        for (; i + 3 < d; i += 4) {
            int s0 = csr[o + i], s1 = csr[o + i + 1];
            int s2 = csr[o + i + 2], s3 = csr[o + i + 3];
            float a0 = g1[(size_t)s0 * 64 + lane];
            float a1 = g1[(size_t)s1 * 64 + lane];
            float a2 = g1[(size_t)s2 * 64 + lane];
            float a3 = g1[(size_t)s3 * 64 + lane];
            acc += (a0 + a1) + (a2 + a3);
        }
        for (; i < d; ++i) acc += g1[(size_t)csr[o + i] * 64 + lane];
        float v = fmaxf(acc * inv[n] + r1[(size_t)n * 64 + lane], 0.f);
        int g = batch[n];
        if (g != curg) {            // wave-uniform branch
            float q0 = p0, q1 = p1;
#pragma unroll
            for (int m = 1; m < 64; m <<= 1) { q0 += __shfl_xor(q0, m); q1 += __shfl_xor(q1, m); }
            if (lane == 0 && curg >= 0) {
                atomicAdd(&outacc[curg * 2 + 0], q0);
                atomicAdd(&outacc[curg * 2 + 1], q1);
            }
            p0 = 0.f; p1 = 0.f; curg = g;
        }
        p0 += v * wo0;
        p1 += v * wo1;
    }
    {
        float q0 = p0, q1 = p1;
#pragma unroll
        for (int m = 1; m < 64; m <<= 1) { q0 += __shfl_xor(q0, m); q1 += __shfl_xor(q1, m); }
        if (lane == 0 && curg >= 0) {
            atomicAdd(&outacc[curg * 2 + 0], q0);
            atomicAdd(&outacc[curg * 2 + 1], q1);
        }
    }
}

__global__ void k_out(const float* __restrict__ outacc, const float* __restrict__ cnt,
                      const float* __restrict__ bout, float* __restrict__ out, int n_graphs) {
    int i = blockIdx.x * 256 + threadIdx.x;
    if (i < n_graphs * 2) {
        int g = i >> 1, c = i & 1;
        out[i] = outacc[i] / fmaxf(cnt[g], 1.0f) + bout[c];
    }
}

extern "C" void kernel_launch(void* const* d_in, const int* in_sizes, int n_in,
                              void* d_out, int out_size, void* d_ws, size_t ws_size,
                              hipStream_t stream) {
    const int* x     = (const int*)d_in[0];
    const int* ei    = (const int*)d_in[1];
    const int* batch = (const int*)d_in[2];
    const float* se   = (const float*)d_in[4];
    const float* ce   = (const float*)d_in[5];
    const float* Win  = (const float*)d_in[6];
    const float* bin  = (const float*)d_in[7];
    const float* W1l  = (const float*)d_in[8];
    const float* b1   = (const float*)d_in[9];
    const float* W1r  = (const float*)d_in[10];
    const float* W2l  = (const float*)d_in[11];
    const float* b2   = (const float*)d_in[12];
    const float* W2r  = (const float*)d_in[13];
    const float* Wout = (const float*)d_in[14];
    const float* bout = (const float*)d_in[15];
    float* out = (float*)d_out;

    int n_nodes  = in_sizes[0] / 2;
    int n_edges  = in_sizes[1] / 2;
    int n_graphs = out_size / 2;
    const int* src = ei;
    const int* dst = ei + n_edges;

    char* p = (char*)d_ws;
    auto take = [&](size_t bytes) { char* r = p; p += (bytes + 255) & ~(size_t)255; return r; };
    float* h1     = (float*)take((size_t)n_nodes * 64 * 4);
    float* g1     = (float*)take((size_t)n_nodes * 64 * 4);
    float* r1     = (float*)take((size_t)n_nodes * 64 * 4);
    int*   csr    = (int*)take((size_t)n_edges * 4);
    int*   ntype  = (int*)take((size_t)n_nodes * 4);
    int*   deg_i  = (int*)take((size_t)n_nodes * 4);
    int*   off    = (int*)take((size_t)n_nodes * 4);
    int*   cursor = (int*)take((size_t)n_nodes * 4);
    float* inv    = (float*)take((size_t)n_nodes * 4);
    int*   bsum   = (int*)take(512 * 4);
    int*   bofs   = (int*)take(512 * 4);
    float* cnt    = (float*)take((size_t)n_graphs * 4);
    float* outacc = (float*)take((size_t)n_graphs * 8);
    float* h0tab  = (float*)take(4096 * 4);
    float* hltab  = (float*)take(4096 * 4);
    float* hrtab  = (float*)take(4096 * 4);

    int nbN = (n_nodes + 255) / 256;
    int nbE = (n_edges + 255) / 256;

    hipMemsetAsync(deg_i, 0, (size_t)n_nodes * 4, stream);
    hipMemsetAsync(cnt, 0, (size_t)n_graphs * 4, stream);
    hipMemsetAsync(outacc, 0, (size_t)n_graphs * 8, stream);

    k_tab0<<<64, 64, 0, stream>>>(se, ce, Win, bin, h0tab);
    k_tab1<<<64, 64, 0, stream>>>(h0tab, W1l, W1r, b1, hltab, hrtab);
    k_prep<<<nbN, 256, 0, stream>>>(x, batch, ntype, cnt, n_nodes);
    k_count<<<nbE, 256, 0, stream>>>(dst, deg_i, n_edges);
    k_scan1<<<nbN, 256, 0, stream>>>(deg_i, off, bsum, n_nodes);
    k_scan2<<<1, 512, 0, stream>>>(bsum, bofs, nbN);
    k_scan3<<<nbN, 256, 0, stream>>>(off, cursor, bofs, deg_i, inv, n_nodes);
    k_fill<<<nbE, 256, 0, stream>>>(src, dst, cursor, csr, n_edges);
    k_gather1<<<2048, 256, 0, stream>>>(csr, off, deg_i, inv, ntype, hltab, hrtab, h1, n_nodes);
    k_lin2<<<768, 256, 0, stream>>>(h1, W2l, W2r, b2, g1, r1, n_nodes);
    k_gather2<<<2048, 256, 0, stream>>>(csr, off, deg_i, inv, g1, r1, batch, Wout,
                                        outacc, n_nodes);
    k_out<<<(n_graphs * 2 + 255) / 256, 256, 0, stream>>>(outacc, cnt, bout, out, n_graphs);
}

// Round 4
// 311.743 us; speedup vs baseline: 3.3397x; 1.3358x over previous
//
#include <hip/hip_runtime.h>
#include <hip/hip_bf16.h>

// ---------------------------------------------------------------------------
// GNN classifier on MI355X.
//   h0 = relu([shape_emb[x0]|color_emb[x1]] @ W_in + b_in)   -> 64-entry table
//   conv1: h1 = relu( seg_sum(hltab[type[src]],dst)/deg + hrtab[type] )
//          hltab = h0tab@W1l, hrtab = h0tab@W1r + b1          (linearity)
//   conv2 by linearity:  g1 = h1@W2l, r1 = h1@W2r + b2  (dense GEMM)
//          h2 = relu( seg_sum(g1[src],dst)/deg + r1 )
//   out   = seg_sum(h2@W_out, batch)/cnt + b_out   (fused into the gather)
// Aggregations via per-call CSR (counting sort by dst) -> gathers.
//
// R2 lesson (rocprof): full `#pragma unroll` on the 64-step k-loop in k_lin2
// spilled (256 VGPR, 1.9 GB scratch traffic). Keep unroll 2.
// R3 lesson (rocprof): batch is SORTED, so per-node atomicAdd(&cnt[batch[n]])
// is a same-address 64-way serialized atomic -> 108 us. Count nodes in
// k_gather2's run-deferred flush instead (1 atomic per graph-run per wave).
// ---------------------------------------------------------------------------

__global__ void k_tab0(const float* __restrict__ se, const float* __restrict__ ce,
                       const float* __restrict__ Win, const float* __restrict__ bin,
                       float* __restrict__ h0tab) {
    int t = blockIdx.x, j = threadIdx.x;        // 64 blocks x 64 threads
    int s = t >> 3, c = t & 7;
    float acc = bin[j];
    for (int k = 0; k < 64; ++k) {
        acc += se[s * 64 + k] * Win[k * 64 + j];
        acc += ce[c * 64 + k] * Win[(64 + k) * 64 + j];
    }
    h0tab[t * 64 + j] = fmaxf(acc, 0.f);
}

__global__ void k_tab1(const float* __restrict__ h0tab, const float* __restrict__ W1l,
                       const float* __restrict__ W1r, const float* __restrict__ b1,
                       float* __restrict__ hltab, float* __restrict__ hrtab) {
    int t = blockIdx.x, j = threadIdx.x;        // 64 blocks x 64 threads
    float al = 0.f, ar = b1[j];
    for (int k = 0; k < 64; ++k) {
        float h = h0tab[t * 64 + k];
        al += h * W1l[k * 64 + j];
        ar += h * W1r[k * 64 + j];
    }
    hltab[t * 64 + j] = al;
    hrtab[t * 64 + j] = ar;
}

// ntype only; NO atomics (R3 lesson).
__global__ void k_prep(const int* __restrict__ x, int* __restrict__ ntype, int n_nodes) {
    int n = blockIdx.x * 256 + threadIdx.x;
    if (n < n_nodes) {
        int2 v = *(const int2*)(x + 2 * (size_t)n);
        ntype[n] = v.x * 8 + v.y;
    }
}

__global__ void k_count(const int* __restrict__ dst, int* __restrict__ deg_i, int n_edges) {
    int e = blockIdx.x * 256 + threadIdx.x;
    if (e < n_edges) atomicAdd(&deg_i[dst[e]], 1);
}

// exclusive scan, 3-kernel two-level
__global__ void k_scan1(const int* __restrict__ deg_i, int* __restrict__ off,
                        int* __restrict__ bsum, int n) {
    __shared__ int sbuf[2][256];
    int tid = threadIdx.x;
    int i = blockIdx.x * 256 + tid;
    int d = (i < n) ? deg_i[i] : 0;
    int cur = 0;
    sbuf[0][tid] = d;
    __syncthreads();
    for (int ofs = 1; ofs < 256; ofs <<= 1) {
        int v = sbuf[cur][tid];
        if (tid >= ofs) v += sbuf[cur][tid - ofs];
        sbuf[cur ^ 1][tid] = v;
        cur ^= 1;
        __syncthreads();
    }
    if (i < n) off[i] = sbuf[cur][tid] - d;
    if (tid == 255) bsum[blockIdx.x] = sbuf[cur][tid];
}

__global__ void k_scan2(const int* __restrict__ bsum, int* __restrict__ bofs, int nb) {
    __shared__ int sbuf[2][512];
    int tid = threadIdx.x;
    int d = (tid < nb) ? bsum[tid] : 0;
    int cur = 0;
    sbuf[0][tid] = d;
    __syncthreads();
    for (int ofs = 1; ofs < 512; ofs <<= 1) {
        int v = sbuf[cur][tid];
        if (tid >= ofs) v += sbuf[cur][tid - ofs];
        sbuf[cur ^ 1][tid] = v;
        cur ^= 1;
        __syncthreads();
    }
    if (tid < nb) bofs[tid] = sbuf[cur][tid] - d;
}

__global__ void k_scan3(int* __restrict__ off, int* __restrict__ cursor,
                        const int* __restrict__ bofs, const int* __restrict__ deg_i,
                        float* __restrict__ inv, int n) {
    int i = blockIdx.x * 256 + threadIdx.x;
    if (i < n) {
        int o = off[i] + bofs[blockIdx.x];
        off[i] = o;
        cursor[i] = o;
        inv[i] = 1.0f / fmaxf((float)deg_i[i], 1.0f);
    }
}

__global__ void k_fill(const int* __restrict__ src, const int* __restrict__ dst,
                       int* __restrict__ cursor, int* __restrict__ csr, int n_edges) {
    int e = blockIdx.x * 256 + threadIdx.x;
    if (e < n_edges) {
        int pos = atomicAdd(&cursor[dst[e]], 1);
        csr[pos] = src[e];
    }
}

// conv1: wave per node (contiguous chunks), lane = feature dim, tables in LDS.
__global__ __launch_bounds__(256) void k_gather1(
    const int* __restrict__ csr, const int* __restrict__ off,
    const int* __restrict__ deg_i, const float* __restrict__ inv,
    const int* __restrict__ ntype, const float* __restrict__ hltab,
    const float* __restrict__ hrtab, float* __restrict__ h1, int n_nodes) {
    __shared__ float tl[4096];
    __shared__ float tr_[4096];
    for (int i = threadIdx.x; i < 4096; i += 256) { tl[i] = hltab[i]; tr_[i] = hrtab[i]; }
    __syncthreads();
    int lane = threadIdx.x & 63;
    int w = blockIdx.x * 4 + (threadIdx.x >> 6);
    int nw = gridDim.x * 4;
    int per = (n_nodes + nw - 1) / nw;
    int n = w * per;
    int nend = n + per; if (nend > n_nodes) nend = n_nodes;
    for (; n < nend; ++n) {
        int o = off[n], d = deg_i[n];
        float acc = 0.f;
        int i = 0;
        for (; i + 3 < d; i += 4) {
            int s0 = csr[o + i], s1 = csr[o + i + 1];
            int s2 = csr[o + i + 2], s3 = csr[o + i + 3];
            int t0 = ntype[s0], t1 = ntype[s1], t2 = ntype[s2], t3 = ntype[s3];
            acc += (tl[t0 * 64 + lane] + tl[t1 * 64 + lane]) +
                   (tl[t2 * 64 + lane] + tl[t3 * 64 + lane]);
        }
        for (; i < d; ++i) acc += tl[ntype[csr[o + i]] * 64 + lane];
        h1[(size_t)n * 64 + lane] = fmaxf(acc * inv[n] + tr_[ntype[n] * 64 + lane], 0.f);
    }
}

// dense conv2 GEMMs: g1 = h1@W2l, r1 = h1@W2r + b2. LDS-staged h1 tile + weights.
#define SH_LD 68   // 64 + 4 pad: keeps float4 alignment, 2-way (free) bank aliasing
__global__ __launch_bounds__(256) void k_lin2(
    const float* __restrict__ h1, const float* __restrict__ W2l,
    const float* __restrict__ W2r, const float* __restrict__ b2,
    float* __restrict__ g1, float* __restrict__ r1, int n_nodes) {
    __shared__ float sWl[4096];
    __shared__ float sWr[4096];
    __shared__ float sb2[64];
    __shared__ float sh[64 * SH_LD];
    int tid = threadIdx.x;
    for (int i = tid; i < 4096; i += 256) { sWl[i] = W2l[i]; sWr[i] = W2r[i]; }
    if (tid < 64) sb2[tid] = b2[tid];

    int ntile = (n_nodes + 63) >> 6;
    int tr = tid >> 4, tc = tid & 15;
    int r0 = tr * 4, c0 = tc * 4;

    for (int t = blockIdx.x; t < ntile; t += gridDim.x) {
        int n0 = t << 6;
        __syncthreads();   // weights ready (1st iter) / prev readers done
        // cooperative load of 64x64 h1 tile (float4-coalesced), zero-pad tail
        {
            int lim = (n_nodes - n0) * 16;           // valid float4s
            const float4* s4 = (const float4*)(h1 + (size_t)n0 * 64);
            for (int i = tid; i < 1024; i += 256) {
                int row = i >> 4, col = i & 15;
                float4 v = (i < lim) ? s4[i] : make_float4(0.f, 0.f, 0.f, 0.f);
                *(float4*)(sh + row * SH_LD + col * 4) = v;
            }
        }
        __syncthreads();

        float accl[4][4] = {{0.f}}, accr[4][4] = {{0.f}};
#pragma unroll 2            // R2: full unroll spilled (256 VGPR, 1.9GB scratch)
        for (int k = 0; k < 64; k += 4) {
            float4 hv[4];
#pragma unroll
            for (int i = 0; i < 4; ++i)
                hv[i] = *(const float4*)(sh + (r0 + i) * SH_LD + k);
#pragma unroll
            for (int kk = 0; kk < 4; ++kk) {
                float4 wl = *(const float4*)(sWl + (k + kk) * 64 + c0);
                float4 wr = *(const float4*)(sWr + (k + kk) * 64 + c0);
#pragma unroll
                for (int i = 0; i < 4; ++i) {
                    float h = (&hv[i].x)[kk];
                    accl[i][0] += h * wl.x; accr[i][0] += h * wr.x;
                    accl[i][1] += h * wl.y; accr[i][1] += h * wr.y;
                    accl[i][2] += h * wl.z; accr[i][2] += h * wr.z;
                    accl[i][3] += h * wl.w; accr[i][3] += h * wr.w;
                }
            }
        }
#pragma unroll
        for (int i = 0; i < 4; ++i) {
            int n = n0 + r0 + i;
            if (n < n_nodes) {
                float4 gl = make_float4(accl[i][0], accl[i][1], accl[i][2], accl[i][3]);
                float4 rr = make_float4(accr[i][0] + sb2[c0 + 0], accr[i][1] + sb2[c0 + 1],
                                        accr[i][2] + sb2[c0 + 2], accr[i][3] + sb2[c0 + 3]);
                *(float4*)(g1 + (size_t)n * 64 + c0) = gl;
                *(float4*)(r1 + (size_t)n * 64 + c0) = rr;
            }
        }
    }
}

// conv2 aggregation fused with relu, W_out projection, graph pooling, and
// per-graph node counting. Wave owns a contiguous node chunk; batch is sorted
// -> defer atomics until the graph id changes (1-2 flushes per wave).
__global__ __launch_bounds__(256) void k_gather2(
    const int* __restrict__ csr, const int* __restrict__ off,
    const int* __restrict__ deg_i, const float* __restrict__ inv,
    const float* __restrict__ g1, const float* __restrict__ r1,
    const int* __restrict__ batch, const float* __restrict__ Wout,
    float* __restrict__ outacc, float* __restrict__ cnt, int n_nodes) {
    int lane = threadIdx.x & 63;
    int w = blockIdx.x * 4 + (threadIdx.x >> 6);
    int nw = gridDim.x * 4;
    int per = (n_nodes + nw - 1) / nw;
    int n = w * per;
    int nend = n + per; if (nend > n_nodes) nend = n_nodes;
    float wo0 = Wout[lane * 2 + 0], wo1 = Wout[lane * 2 + 1];
    float p0 = 0.f, p1 = 0.f, pc = 0.f;
    int curg = (n < nend) ? (int)batch[n] : -1;
    for (; n < nend; ++n) {
        int o = off[n], d = deg_i[n];
        float acc = 0.f;
        int i = 0;
        for (; i + 3 < d; i += 4) {
            int s0 = csr[o + i], s1 = csr[o + i + 1];
            int s2 = csr[o + i + 2], s3 = csr[o + i + 3];
            float a0 = g1[(size_t)s0 * 64 + lane];
            float a1 = g1[(size_t)s1 * 64 + lane];
            float a2 = g1[(size_t)s2 * 64 + lane];
            float a3 = g1[(size_t)s3 * 64 + lane];
            acc += (a0 + a1) + (a2 + a3);
        }
        for (; i < d; ++i) acc += g1[(size_t)csr[o + i] * 64 + lane];
        float v = fmaxf(acc * inv[n] + r1[(size_t)n * 64 + lane], 0.f);
        int g = batch[n];
        if (g != curg) {            // wave-uniform branch
            float q0 = p0, q1 = p1;
#pragma unroll
            for (int m = 1; m < 64; m <<= 1) { q0 += __shfl_xor(q0, m); q1 += __shfl_xor(q1, m); }
            if (lane == 0 && curg >= 0) {
                atomicAdd(&outacc[curg * 2 + 0], q0);
                atomicAdd(&outacc[curg * 2 + 1], q1);
                atomicAdd(&cnt[curg], pc);
            }
            p0 = 0.f; p1 = 0.f; pc = 0.f; curg = g;
        }
        p0 += v * wo0;
        p1 += v * wo1;
        pc += 1.0f;                 // same on all lanes; flushed from lane 0 only
    }
    {
        float q0 = p0, q1 = p1;
#pragma unroll
        for (int m = 1; m < 64; m <<= 1) { q0 += __shfl_xor(q0, m); q1 += __shfl_xor(q1, m); }
        if (lane == 0 && curg >= 0) {
            atomicAdd(&outacc[curg * 2 + 0], q0);
            atomicAdd(&outacc[curg * 2 + 1], q1);
            atomicAdd(&cnt[curg], pc);
        }
    }
}

__global__ void k_out(const float* __restrict__ outacc, const float* __restrict__ cnt,
                      const float* __restrict__ bout, float* __restrict__ out, int n_graphs) {
    int i = blockIdx.x * 256 + threadIdx.x;
    if (i < n_graphs * 2) {
        int g = i >> 1, c = i & 1;
        out[i] = outacc[i] / fmaxf(cnt[g], 1.0f) + bout[c];
    }
}

extern "C" void kernel_launch(void* const* d_in, const int* in_sizes, int n_in,
                              void* d_out, int out_size, void* d_ws, size_t ws_size,
                              hipStream_t stream) {
    const int* x     = (const int*)d_in[0];
    const int* ei    = (const int*)d_in[1];
    const int* batch = (const int*)d_in[2];
    const float* se   = (const float*)d_in[4];
    const float* ce   = (const float*)d_in[5];
    const float* Win  = (const float*)d_in[6];
    const float* bin  = (const float*)d_in[7];
    const float* W1l  = (const float*)d_in[8];
    const float* b1   = (const float*)d_in[9];
    const float* W1r  = (const float*)d_in[10];
    const float* W2l  = (const float*)d_in[11];
    const float* b2   = (const float*)d_in[12];
    const float* W2r  = (const float*)d_in[13];
    const float* Wout = (const float*)d_in[14];
    const float* bout = (const float*)d_in[15];
    float* out = (float*)d_out;

    int n_nodes  = in_sizes[0] / 2;
    int n_edges  = in_sizes[1] / 2;
    int n_graphs = out_size / 2;
    const int* src = ei;
    const int* dst = ei + n_edges;

    char* p = (char*)d_ws;
    auto take = [&](size_t bytes) { char* r = p; p += (bytes + 255) & ~(size_t)255; return r; };
    float* h1     = (float*)take((size_t)n_nodes * 64 * 4);
    float* g1     = (float*)take((size_t)n_nodes * 64 * 4);
    float* r1     = (float*)take((size_t)n_nodes * 64 * 4);
    int*   csr    = (int*)take((size_t)n_edges * 4);
    int*   ntype  = (int*)take((size_t)n_nodes * 4);
    int*   deg_i  = (int*)take((size_t)n_nodes * 4);
    int*   off    = (int*)take((size_t)n_nodes * 4);
    int*   cursor = (int*)take((size_t)n_nodes * 4);
    float* inv    = (float*)take((size_t)n_nodes * 4);
    int*   bsum   = (int*)take(512 * 4);
    int*   bofs   = (int*)take(512 * 4);
    float* cnt    = (float*)take((size_t)n_graphs * 4);
    float* outacc = (float*)take((size_t)n_graphs * 8);
    float* h0tab  = (float*)take(4096 * 4);
    float* hltab  = (float*)take(4096 * 4);
    float* hrtab  = (float*)take(4096 * 4);

    int nbN = (n_nodes + 255) / 256;
    int nbE = (n_edges + 255) / 256;

    hipMemsetAsync(deg_i, 0, (size_t)n_nodes * 4, stream);
    hipMemsetAsync(cnt, 0, (size_t)n_graphs * 4, stream);
    hipMemsetAsync(outacc, 0, (size_t)n_graphs * 8, stream);

    k_tab0<<<64, 64, 0, stream>>>(se, ce, Win, bin, h0tab);
    k_tab1<<<64, 64, 0, stream>>>(h0tab, W1l, W1r, b1, hltab, hrtab);
    k_prep<<<nbN, 256, 0, stream>>>(x, ntype, n_nodes);
    k_count<<<nbE, 256, 0, stream>>>(dst, deg_i, n_edges);
    k_scan1<<<nbN, 256, 0, stream>>>(deg_i, off, bsum, n_nodes);
    k_scan2<<<1, 512, 0, stream>>>(bsum, bofs, nbN);
    k_scan3<<<nbN, 256, 0, stream>>>(off, cursor, bofs, deg_i, inv, n_nodes);
    k_fill<<<nbE, 256, 0, stream>>>(src, dst, cursor, csr, n_edges);
    k_gather1<<<2048, 256, 0, stream>>>(csr, off, deg_i, inv, ntype, hltab, hrtab, h1, n_nodes);
    k_lin2<<<768, 256, 0, stream>>>(h1, W2l, W2r, b2, g1, r1, n_nodes);
    k_gather2<<<2048, 256, 0, stream>>>(csr, off, deg_i, inv, g1, r1, batch, Wout,
                                        outacc, cnt, n_nodes);
    k_out<<<(n_graphs * 2 + 255) / 256, 256, 0, stream>>>(outacc, cnt, bout, out, n_graphs);
}

// Round 5
// 243.361 us; speedup vs baseline: 4.2781x; 1.2810x over previous
//
#include <hip/hip_runtime.h>
#include <hip/hip_bf16.h>

// ---------------------------------------------------------------------------
// GNN classifier on MI355X.
//   h0 = relu([shape_emb[x0]|color_emb[x1]] @ W_in + b_in)   -> 64-entry table
//   conv1: h1 = relu( seg_sum(hltab[type[src]],dst)/deg + hrtab[type] )
//          hltab = h0tab@W1l, hrtab = h0tab@W1r + b1          (linearity)
//   conv2 by linearity:  g1 = h1@W2l, r1 = h1@W2r + b2  (dense GEMM)
//          h2 = relu( seg_sum(g1[src],dst)/deg + r1 )
//   out   = seg_sum(h2@W_out, batch)/cnt + b_out   (fused into the gather)
// Aggregations via per-call CSR (counting sort by dst) -> gathers.
//
// R2 lesson (rocprof): full `#pragma unroll` on the 64-step k-loop in k_lin2
// spilled (256 VGPR, 1.9 GB scratch traffic). Keep unroll 2.
// R3 lesson (rocprof): batch is SORTED -> per-node atomicAdd on cnt[batch[n]]
// is same-address serialized. Count in gather2's run-deferred flush.
// R4 lesson (rocprof): k_fill's atomicAdd-with-return (pos) made every lane
// wait on a ~400cy memory-side RMW (90 us, VALUBusy 0.3%). Fuse the rank into
// k_count's existing atomic (keep its return), making k_fill a pure
// fire-and-forget scattered store.
// ---------------------------------------------------------------------------

__global__ void k_tab0(const float* __restrict__ se, const float* __restrict__ ce,
                       const float* __restrict__ Win, const float* __restrict__ bin,
                       float* __restrict__ h0tab) {
    int t = blockIdx.x, j = threadIdx.x;        // 64 blocks x 64 threads
    int s = t >> 3, c = t & 7;
    float acc = bin[j];
    for (int k = 0; k < 64; ++k) {
        acc += se[s * 64 + k] * Win[k * 64 + j];
        acc += ce[c * 64 + k] * Win[(64 + k) * 64 + j];
    }
    h0tab[t * 64 + j] = fmaxf(acc, 0.f);
}

__global__ void k_tab1(const float* __restrict__ h0tab, const float* __restrict__ W1l,
                       const float* __restrict__ W1r, const float* __restrict__ b1,
                       float* __restrict__ hltab, float* __restrict__ hrtab) {
    int t = blockIdx.x, j = threadIdx.x;        // 64 blocks x 64 threads
    float al = 0.f, ar = b1[j];
    for (int k = 0; k < 64; ++k) {
        float h = h0tab[t * 64 + k];
        al += h * W1l[k * 64 + j];
        ar += h * W1r[k * 64 + j];
    }
    hltab[t * 64 + j] = al;
    hrtab[t * 64 + j] = ar;
}

// ntype only; NO atomics (R3 lesson).
__global__ void k_prep(const int* __restrict__ x, int* __restrict__ ntype, int n_nodes) {
    int n = blockIdx.x * 256 + threadIdx.x;
    if (n < n_nodes) {
        int2 v = *(const int2*)(x + 2 * (size_t)n);
        ntype[n] = v.x * 8 + v.y;
    }
}

// count in-degree AND record each edge's rank among its dst's edges (R4).
__global__ void k_count(const int* __restrict__ dst, int* __restrict__ deg_i,
                        int* __restrict__ rank, int n_edges) {
    int e = blockIdx.x * 256 + threadIdx.x;
    if (e < n_edges) rank[e] = atomicAdd(&deg_i[dst[e]], 1);
}

// exclusive scan, 3-kernel two-level
__global__ void k_scan1(const int* __restrict__ deg_i, int* __restrict__ off,
                        int* __restrict__ bsum, int n) {
    __shared__ int sbuf[2][256];
    int tid = threadIdx.x;
    int i = blockIdx.x * 256 + tid;
    int d = (i < n) ? deg_i[i] : 0;
    int cur = 0;
    sbuf[0][tid] = d;
    __syncthreads();
    for (int ofs = 1; ofs < 256; ofs <<= 1) {
        int v = sbuf[cur][tid];
        if (tid >= ofs) v += sbuf[cur][tid - ofs];
        sbuf[cur ^ 1][tid] = v;
        cur ^= 1;
        __syncthreads();
    }
    if (i < n) off[i] = sbuf[cur][tid] - d;
    if (tid == 255) bsum[blockIdx.x] = sbuf[cur][tid];
}

__global__ void k_scan2(const int* __restrict__ bsum, int* __restrict__ bofs, int nb) {
    __shared__ int sbuf[2][512];
    int tid = threadIdx.x;
    int d = (tid < nb) ? bsum[tid] : 0;
    int cur = 0;
    sbuf[0][tid] = d;
    __syncthreads();
    for (int ofs = 1; ofs < 512; ofs <<= 1) {
        int v = sbuf[cur][tid];
        if (tid >= ofs) v += sbuf[cur][tid - ofs];
        sbuf[cur ^ 1][tid] = v;
        cur ^= 1;
        __syncthreads();
    }
    if (tid < nb) bofs[tid] = sbuf[cur][tid] - d;
}

__global__ void k_scan3(int* __restrict__ off, const int* __restrict__ bofs,
                        const int* __restrict__ deg_i, float* __restrict__ inv, int n) {
    int i = blockIdx.x * 256 + threadIdx.x;
    if (i < n) {
        off[i] = off[i] + bofs[blockIdx.x];
        inv[i] = 1.0f / fmaxf((float)deg_i[i], 1.0f);
    }
}

// atomic-free scatter: position fully determined by off + rank (R4).
__global__ void k_fill(const int* __restrict__ src, const int* __restrict__ dst,
                       const int* __restrict__ off, const int* __restrict__ rank,
                       int* __restrict__ csr, int n_edges) {
    int e = blockIdx.x * 256 + threadIdx.x;
    if (e < n_edges) {
        csr[off[dst[e]] + rank[e]] = src[e];
    }
}

// conv1: wave per node (contiguous chunks), lane = feature dim, tables in LDS.
__global__ __launch_bounds__(256) void k_gather1(
    const int* __restrict__ csr, const int* __restrict__ off,
    const int* __restrict__ deg_i, const float* __restrict__ inv,
    const int* __restrict__ ntype, const float* __restrict__ hltab,
    const float* __restrict__ hrtab, float* __restrict__ h1, int n_nodes) {
    __shared__ float tl[4096];
    __shared__ float tr_[4096];
    for (int i = threadIdx.x; i < 4096; i += 256) { tl[i] = hltab[i]; tr_[i] = hrtab[i]; }
    __syncthreads();
    int lane = threadIdx.x & 63;
    int w = blockIdx.x * 4 + (threadIdx.x >> 6);
    int nw = gridDim.x * 4;
    int per = (n_nodes + nw - 1) / nw;
    int n = w * per;
    int nend = n + per; if (nend > n_nodes) nend = n_nodes;
    for (; n < nend; ++n) {
        int o = off[n], d = deg_i[n];
        float acc = 0.f;
        int i = 0;
        for (; i + 3 < d; i += 4) {
            int s0 = csr[o + i], s1 = csr[o + i + 1];
            int s2 = csr[o + i + 2], s3 = csr[o + i + 3];
            int t0 = ntype[s0], t1 = ntype[s1], t2 = ntype[s2], t3 = ntype[s3];
            acc += (tl[t0 * 64 + lane] + tl[t1 * 64 + lane]) +
                   (tl[t2 * 64 + lane] + tl[t3 * 64 + lane]);
        }
        for (; i < d; ++i) acc += tl[ntype[csr[o + i]] * 64 + lane];
        h1[(size_t)n * 64 + lane] = fmaxf(acc * inv[n] + tr_[ntype[n] * 64 + lane], 0.f);
    }
}

// dense conv2 GEMMs: g1 = h1@W2l, r1 = h1@W2r + b2. LDS-staged h1 tile + weights.
#define SH_LD 68   // 64 + 4 pad: keeps float4 alignment, 2-way (free) bank aliasing
__global__ __launch_bounds__(256) void k_lin2(
    const float* __restrict__ h1, const float* __restrict__ W2l,
    const float* __restrict__ W2r, const float* __restrict__ b2,
    float* __restrict__ g1, float* __restrict__ r1, int n_nodes) {
    __shared__ float sWl[4096];
    __shared__ float sWr[4096];
    __shared__ float sb2[64];
    __shared__ float sh[64 * SH_LD];
    int tid = threadIdx.x;
    for (int i = tid; i < 4096; i += 256) { sWl[i] = W2l[i]; sWr[i] = W2r[i]; }
    if (tid < 64) sb2[tid] = b2[tid];

    int ntile = (n_nodes + 63) >> 6;
    int tr = tid >> 4, tc = tid & 15;
    int r0 = tr * 4, c0 = tc * 4;

    for (int t = blockIdx.x; t < ntile; t += gridDim.x) {
        int n0 = t << 6;
        __syncthreads();   // weights ready (1st iter) / prev readers done
        // cooperative load of 64x64 h1 tile (float4-coalesced), zero-pad tail
        {
            int lim = (n_nodes - n0) * 16;           // valid float4s
            const float4* s4 = (const float4*)(h1 + (size_t)n0 * 64);
            for (int i = tid; i < 1024; i += 256) {
                int row = i >> 4, col = i & 15;
                float4 v = (i < lim) ? s4[i] : make_float4(0.f, 0.f, 0.f, 0.f);
                *(float4*)(sh + row * SH_LD + col * 4) = v;
            }
        }
        __syncthreads();

        float accl[4][4] = {{0.f}}, accr[4][4] = {{0.f}};
#pragma unroll 2            // R2: full unroll spilled (256 VGPR, 1.9GB scratch)
        for (int k = 0; k < 64; k += 4) {
            float4 hv[4];
#pragma unroll
            for (int i = 0; i < 4; ++i)
                hv[i] = *(const float4*)(sh + (r0 + i) * SH_LD + k);
#pragma unroll
            for (int kk = 0; kk < 4; ++kk) {
                float4 wl = *(const float4*)(sWl + (k + kk) * 64 + c0);
                float4 wr = *(const float4*)(sWr + (k + kk) * 64 + c0);
#pragma unroll
                for (int i = 0; i < 4; ++i) {
                    float h = (&hv[i].x)[kk];
                    accl[i][0] += h * wl.x; accr[i][0] += h * wr.x;
                    accl[i][1] += h * wl.y; accr[i][1] += h * wr.y;
                    accl[i][2] += h * wl.z; accr[i][2] += h * wr.z;
                    accl[i][3] += h * wl.w; accr[i][3] += h * wr.w;
                }
            }
        }
#pragma unroll
        for (int i = 0; i < 4; ++i) {
            int n = n0 + r0 + i;
            if (n < n_nodes) {
                float4 gl = make_float4(accl[i][0], accl[i][1], accl[i][2], accl[i][3]);
                float4 rr = make_float4(accr[i][0] + sb2[c0 + 0], accr[i][1] + sb2[c0 + 1],
                                        accr[i][2] + sb2[c0 + 2], accr[i][3] + sb2[c0 + 3]);
                *(float4*)(g1 + (size_t)n * 64 + c0) = gl;
                *(float4*)(r1 + (size_t)n * 64 + c0) = rr;
            }
        }
    }
}

// conv2 aggregation fused with relu, W_out projection, graph pooling, and
// per-graph node counting. Wave owns a contiguous node chunk; batch is sorted
// -> defer atomics until the graph id changes (1-2 flushes per wave).
__global__ __launch_bounds__(256) void k_gather2(
    const int* __restrict__ csr, const int* __restrict__ off,
    const int* __restrict__ deg_i, const float* __restrict__ inv,
    const float* __restrict__ g1, const float* __restrict__ r1,
    const int* __restrict__ batch, const float* __restrict__ Wout,
    float* __restrict__ outacc, float* __restrict__ cnt, int n_nodes) {
    int lane = threadIdx.x & 63;
    int w = blockIdx.x * 4 + (threadIdx.x >> 6);
    int nw = gridDim.x * 4;
    int per = (n_nodes + nw - 1) / nw;
    int n = w * per;
    int nend = n + per; if (nend > n_nodes) nend = n_nodes;
    float wo0 = Wout[lane * 2 + 0], wo1 = Wout[lane * 2 + 1];
    float p0 = 0.f, p1 = 0.f, pc = 0.f;
    int curg = (n < nend) ? (int)batch[n] : -1;
    for (; n < nend; ++n) {
        int o = off[n], d = deg_i[n];
        float acc = 0.f;
        int i = 0;
        for (; i + 3 < d; i += 4) {
            int s0 = csr[o + i], s1 = csr[o + i + 1];
            int s2 = csr[o + i + 2], s3 = csr[o + i + 3];
            float a0 = g1[(size_t)s0 * 64 + lane];
            float a1 = g1[(size_t)s1 * 64 + lane];
            float a2 = g1[(size_t)s2 * 64 + lane];
            float a3 = g1[(size_t)s3 * 64 + lane];
            acc += (a0 + a1) + (a2 + a3);
        }
        for (; i < d; ++i) acc += g1[(size_t)csr[o + i] * 64 + lane];
        float v = fmaxf(acc * inv[n] + r1[(size_t)n * 64 + lane], 0.f);
        int g = batch[n];
        if (g != curg) {            // wave-uniform branch
            float q0 = p0, q1 = p1;
#pragma unroll
            for (int m = 1; m < 64; m <<= 1) { q0 += __shfl_xor(q0, m); q1 += __shfl_xor(q1, m); }
            if (lane == 0 && curg >= 0) {
                atomicAdd(&outacc[curg * 2 + 0], q0);
                atomicAdd(&outacc[curg * 2 + 1], q1);
                atomicAdd(&cnt[curg], pc);
            }
            p0 = 0.f; p1 = 0.f; pc = 0.f; curg = g;
        }
        p0 += v * wo0;
        p1 += v * wo1;
        pc += 1.0f;                 // same on all lanes; flushed from lane 0 only
    }
    {
        float q0 = p0, q1 = p1;
#pragma unroll
        for (int m = 1; m < 64; m <<= 1) { q0 += __shfl_xor(q0, m); q1 += __shfl_xor(q1, m); }
        if (lane == 0 && curg >= 0) {
            atomicAdd(&outacc[curg * 2 + 0], q0);
            atomicAdd(&outacc[curg * 2 + 1], q1);
            atomicAdd(&cnt[curg], pc);
        }
    }
}

__global__ void k_out(const float* __restrict__ outacc, const float* __restrict__ cnt,
                      const float* __restrict__ bout, float* __restrict__ out, int n_graphs) {
    int i = blockIdx.x * 256 + threadIdx.x;
    if (i < n_graphs * 2) {
        int g = i >> 1, c = i & 1;
        out[i] = outacc[i] / fmaxf(cnt[g], 1.0f) + bout[c];
    }
}

extern "C" void kernel_launch(void* const* d_in, const int* in_sizes, int n_in,
                              void* d_out, int out_size, void* d_ws, size_t ws_size,
                              hipStream_t stream) {
    const int* x     = (const int*)d_in[0];
    const int* ei    = (const int*)d_in[1];
    const int* batch = (const int*)d_in[2];
    const float* se   = (const float*)d_in[4];
    const float* ce   = (const float*)d_in[5];
    const float* Win  = (const float*)d_in[6];
    const float* bin  = (const float*)d_in[7];
    const float* W1l  = (const float*)d_in[8];
    const float* b1   = (const float*)d_in[9];
    const float* W1r  = (const float*)d_in[10];
    const float* W2l  = (const float*)d_in[11];
    const float* b2   = (const float*)d_in[12];
    const float* W2r  = (const float*)d_in[13];
    const float* Wout = (const float*)d_in[14];
    const float* bout = (const float*)d_in[15];
    float* out = (float*)d_out;

    int n_nodes  = in_sizes[0] / 2;
    int n_edges  = in_sizes[1] / 2;
    int n_graphs = out_size / 2;
    const int* src = ei;
    const int* dst = ei + n_edges;

    char* p = (char*)d_ws;
    auto take = [&](size_t bytes) { char* r = p; p += (bytes + 255) & ~(size_t)255; return r; };
    float* h1     = (float*)take((size_t)n_nodes * 64 * 4);
    float* g1     = (float*)take((size_t)n_nodes * 64 * 4);
    float* r1     = (float*)take((size_t)n_nodes * 64 * 4);
    int*   csr    = (int*)take((size_t)n_edges * 4);
    int*   rank   = (int*)take((size_t)n_edges * 4);
    int*   ntype  = (int*)take((size_t)n_nodes * 4);
    int*   deg_i  = (int*)take((size_t)n_nodes * 4);
    int*   off    = (int*)take((size_t)n_nodes * 4);
    float* inv    = (float*)take((size_t)n_nodes * 4);
    int*   bsum   = (int*)take(512 * 4);
    int*   bofs   = (int*)take(512 * 4);
    float* cnt    = (float*)take((size_t)n_graphs * 4);
    float* outacc = (float*)take((size_t)n_graphs * 8);
    float* h0tab  = (float*)take(4096 * 4);
    float* hltab  = (float*)take(4096 * 4);
    float* hrtab  = (float*)take(4096 * 4);

    int nbN = (n_nodes + 255) / 256;
    int nbE = (n_edges + 255) / 256;

    hipMemsetAsync(deg_i, 0, (size_t)n_nodes * 4, stream);
    hipMemsetAsync(cnt, 0, (size_t)n_graphs * 4, stream);
    hipMemsetAsync(outacc, 0, (size_t)n_graphs * 8, stream);

    k_tab0<<<64, 64, 0, stream>>>(se, ce, Win, bin, h0tab);
    k_tab1<<<64, 64, 0, stream>>>(h0tab, W1l, W1r, b1, hltab, hrtab);
    k_prep<<<nbN, 256, 0, stream>>>(x, ntype, n_nodes);
    k_count<<<nbE, 256, 0, stream>>>(dst, deg_i, rank, n_edges);
    k_scan1<<<nbN, 256, 0, stream>>>(deg_i, off, bsum, n_nodes);
    k_scan2<<<1, 512, 0, stream>>>(bsum, bofs, nbN);
    k_scan3<<<nbN, 256, 0, stream>>>(off, bofs, deg_i, inv, n_nodes);
    k_fill<<<nbE, 256, 0, stream>>>(src, dst, off, rank, csr, n_edges);
    k_gather1<<<2048, 256, 0, stream>>>(csr, off, deg_i, inv, ntype, hltab, hrtab, h1, n_nodes);
    k_lin2<<<768, 256, 0, stream>>>(h1, W2l, W2r, b2, g1, r1, n_nodes);
    k_gather2<<<2048, 256, 0, stream>>>(csr, off, deg_i, inv, g1, r1, batch, Wout,
                                        outacc, cnt, n_nodes);
    k_out<<<(n_graphs * 2 + 255) / 256, 256, 0, stream>>>(outacc, cnt, bout, out, n_graphs);
}

// Round 6
// 215.491 us; speedup vs baseline: 4.8314x; 1.1293x over previous
//
#include <hip/hip_runtime.h>
#include <hip/hip_bf16.h>

// ---------------------------------------------------------------------------
// GNN classifier on MI355X.
//   h0 = relu([shape_emb[x0]|color_emb[x1]] @ W_in + b_in)   -> 64-entry table
//   conv1: h1 = relu( seg_sum(hltab[type[src]],dst)/deg + hrtab[type] )
//          hltab = h0tab@W1l, hrtab = h0tab@W1r + b1          (linearity)
//   conv2 by linearity:  g1 = h1@W2l, r1 = h1@W2r + b2  (dense GEMM)
//          h2 = relu( seg_sum(g1[src],dst)/deg + r1 )
//   out   = seg_sum(h2@W_out, batch)/cnt + b_out   (fused into the gather)
// Aggregations via per-call CSR (counting sort by dst) -> gathers.
//
// R2: full unroll in k_lin2 spilled (256 VGPR, 1.9 GB scratch). Keep unroll 2.
// R3: batch is SORTED -> per-node atomicAdd(cnt[batch[n]]) serialized; count
//     in gather2's run-deferred flush instead.
// R4: atomicAdd-with-return in k_fill stalled every lane ~400cy; rank fused
//     into k_count's atomic, k_fill is now a fire-and-forget scatter.
// R5: gather kernels were dominated by WAVE-UNIFORM BROADCAST loads (csr,
//     ntype, node metadata): 64 lanes fetching the same 4B, two dependent
//     global latencies per edge (VALUBusy 25%, HBM 6%). Fix: pack ntype into
//     the CSR value (src | type<<20), load 64 edges coalesced per wave, and
//     broadcast via __shfl (VALU). Node metadata prefetched coalesced per
//     64-node chunk and shuffled out.
// ---------------------------------------------------------------------------

__global__ void k_tab0(const float* __restrict__ se, const float* __restrict__ ce,
                       const float* __restrict__ Win, const float* __restrict__ bin,
                       float* __restrict__ h0tab) {
    int t = blockIdx.x, j = threadIdx.x;        // 64 blocks x 64 threads
    int s = t >> 3, c = t & 7;
    float acc = bin[j];
    for (int k = 0; k < 64; ++k) {
        acc += se[s * 64 + k] * Win[k * 64 + j];
        acc += ce[c * 64 + k] * Win[(64 + k) * 64 + j];
    }
    h0tab[t * 64 + j] = fmaxf(acc, 0.f);
}

__global__ void k_tab1(const float* __restrict__ h0tab, const float* __restrict__ W1l,
                       const float* __restrict__ W1r, const float* __restrict__ b1,
                       float* __restrict__ hltab, float* __restrict__ hrtab) {
    int t = blockIdx.x, j = threadIdx.x;        // 64 blocks x 64 threads
    float al = 0.f, ar = b1[j];
    for (int k = 0; k < 64; ++k) {
        float h = h0tab[t * 64 + k];
        al += h * W1l[k * 64 + j];
        ar += h * W1r[k * 64 + j];
    }
    hltab[t * 64 + j] = al;
    hrtab[t * 64 + j] = ar;
}

// ntype only; NO atomics (R3 lesson).
__global__ void k_prep(const int* __restrict__ x, int* __restrict__ ntype, int n_nodes) {
    int n = blockIdx.x * 256 + threadIdx.x;
    if (n < n_nodes) {
        int2 v = *(const int2*)(x + 2 * (size_t)n);
        ntype[n] = v.x * 8 + v.y;
    }
}

// count in-degree AND record each edge's rank among its dst's edges (R4).
__global__ void k_count(const int* __restrict__ dst, int* __restrict__ deg_i,
                        int* __restrict__ rank, int n_edges) {
    int e = blockIdx.x * 256 + threadIdx.x;
    if (e < n_edges) rank[e] = atomicAdd(&deg_i[dst[e]], 1);
}

// exclusive scan, 3-kernel two-level
__global__ void k_scan1(const int* __restrict__ deg_i, int* __restrict__ off,
                        int* __restrict__ bsum, int n) {
    __shared__ int sbuf[2][256];
    int tid = threadIdx.x;
    int i = blockIdx.x * 256 + tid;
    int d = (i < n) ? deg_i[i] : 0;
    int cur = 0;
    sbuf[0][tid] = d;
    __syncthreads();
    for (int ofs = 1; ofs < 256; ofs <<= 1) {
        int v = sbuf[cur][tid];
        if (tid >= ofs) v += sbuf[cur][tid - ofs];
        sbuf[cur ^ 1][tid] = v;
        cur ^= 1;
        __syncthreads();
    }
    if (i < n) off[i] = sbuf[cur][tid] - d;
    if (tid == 255) bsum[blockIdx.x] = sbuf[cur][tid];
}

__global__ void k_scan2(const int* __restrict__ bsum, int* __restrict__ bofs, int nb) {
    __shared__ int sbuf[2][512];
    int tid = threadIdx.x;
    int d = (tid < nb) ? bsum[tid] : 0;
    int cur = 0;
    sbuf[0][tid] = d;
    __syncthreads();
    for (int ofs = 1; ofs < 512; ofs <<= 1) {
        int v = sbuf[cur][tid];
        if (tid >= ofs) v += sbuf[cur][tid - ofs];
        sbuf[cur ^ 1][tid] = v;
        cur ^= 1;
        __syncthreads();
    }
    if (tid < nb) bofs[tid] = sbuf[cur][tid] - d;
}

__global__ void k_scan3(int* __restrict__ off, const int* __restrict__ bofs,
                        const int* __restrict__ deg_i, float* __restrict__ inv, int n) {
    int i = blockIdx.x * 256 + threadIdx.x;
    if (i < n) {
        off[i] = off[i] + bofs[blockIdx.x];
        inv[i] = 1.0f / fmaxf((float)deg_i[i], 1.0f);
    }
}

// atomic-free scatter; value packs src index (low 20b) and src type (<<20).
__global__ void k_fill(const int* __restrict__ src, const int* __restrict__ dst,
                       const int* __restrict__ off, const int* __restrict__ rank,
                       const int* __restrict__ ntype, int* __restrict__ csrp,
                       int n_edges) {
    int e = blockIdx.x * 256 + threadIdx.x;
    if (e < n_edges) {
        int s = src[e];
        csrp[off[dst[e]] + rank[e]] = s | (ntype[s] << 20);
    }
}

// conv1: wave per node chunk; 64 edges loaded coalesced, types broadcast via
// __shfl; per-edge work is 1 shfl + 1 conflict-free LDS read (R5).
__global__ __launch_bounds__(256) void k_gather1(
    const int* __restrict__ csrp, const int* __restrict__ off,
    const int* __restrict__ deg_i, const float* __restrict__ inv,
    const int* __restrict__ ntype, const float* __restrict__ hltab,
    const float* __restrict__ hrtab, float* __restrict__ h1, int n_nodes) {
    __shared__ float tl[4096];
    __shared__ float tr_[4096];
    for (int i = threadIdx.x; i < 4096; i += 256) { tl[i] = hltab[i]; tr_[i] = hrtab[i]; }
    __syncthreads();
    int lane = threadIdx.x & 63;
    int w = blockIdx.x * 4 + (threadIdx.x >> 6);
    int nw = gridDim.x * 4;
    int per = (n_nodes + nw - 1) / nw;
    int n0 = w * per;
    int n1 = n0 + per; if (n1 > n_nodes) n1 = n_nodes;
    for (int cb = n0; cb < n1; cb += 64) {
        int cn = n1 - cb; if (cn > 64) cn = 64;
        int voff = 0, vdeg = 0, vnt = 0; float vinv = 0.f;
        if (lane < cn) {
            voff = off[cb + lane]; vdeg = deg_i[cb + lane];
            vinv = inv[cb + lane]; vnt  = ntype[cb + lane];
        }
        for (int j = 0; j < cn; ++j) {
            int o = __shfl(voff, j), d = __shfl(vdeg, j);
            float iv = __shfl(vinv, j);
            int tn = __shfl(vnt, j);
            float acc = 0.f;
            for (int base = 0; base < d; base += 64) {
                int rem = d - base; if (rem > 64) rem = 64;
                int v = (lane < rem) ? csrp[o + base + lane] : 0;
                int full = rem & ~3;
                for (int k = 0; k < full; k += 4) {
                    int t0 = __shfl(v, k)     >> 20;
                    int t1 = __shfl(v, k + 1) >> 20;
                    int t2 = __shfl(v, k + 2) >> 20;
                    int t3 = __shfl(v, k + 3) >> 20;
                    acc += (tl[t0 * 64 + lane] + tl[t1 * 64 + lane]) +
                           (tl[t2 * 64 + lane] + tl[t3 * 64 + lane]);
                }
                for (int k = full; k < rem; ++k)
                    acc += tl[(__shfl(v, k) >> 20) * 64 + lane];
            }
            h1[(size_t)(cb + j) * 64 + lane] = fmaxf(acc * iv + tr_[tn * 64 + lane], 0.f);
        }
    }
}

// dense conv2 GEMMs: g1 = h1@W2l, r1 = h1@W2r + b2. LDS-staged h1 tile + weights.
#define SH_LD 68   // 64 + 4 pad: keeps float4 alignment, 2-way (free) bank aliasing
__global__ __launch_bounds__(256) void k_lin2(
    const float* __restrict__ h1, const float* __restrict__ W2l,
    const float* __restrict__ W2r, const float* __restrict__ b2,
    float* __restrict__ g1, float* __restrict__ r1, int n_nodes) {
    __shared__ float sWl[4096];
    __shared__ float sWr[4096];
    __shared__ float sb2[64];
    __shared__ float sh[64 * SH_LD];
    int tid = threadIdx.x;
    for (int i = tid; i < 4096; i += 256) { sWl[i] = W2l[i]; sWr[i] = W2r[i]; }
    if (tid < 64) sb2[tid] = b2[tid];

    int ntile = (n_nodes + 63) >> 6;
    int tr = tid >> 4, tc = tid & 15;
    int r0 = tr * 4, c0 = tc * 4;

    for (int t = blockIdx.x; t < ntile; t += gridDim.x) {
        int n0 = t << 6;
        __syncthreads();   // weights ready (1st iter) / prev readers done
        // cooperative load of 64x64 h1 tile (float4-coalesced), zero-pad tail
        {
            int lim = (n_nodes - n0) * 16;           // valid float4s
            const float4* s4 = (const float4*)(h1 + (size_t)n0 * 64);
            for (int i = tid; i < 1024; i += 256) {
                int row = i >> 4, col = i & 15;
                float4 v = (i < lim) ? s4[i] : make_float4(0.f, 0.f, 0.f, 0.f);
                *(float4*)(sh + row * SH_LD + col * 4) = v;
            }
        }
        __syncthreads();

        float accl[4][4] = {{0.f}}, accr[4][4] = {{0.f}};
#pragma unroll 2            // R2: full unroll spilled (256 VGPR, 1.9GB scratch)
        for (int k = 0; k < 64; k += 4) {
            float4 hv[4];
#pragma unroll
            for (int i = 0; i < 4; ++i)
                hv[i] = *(const float4*)(sh + (r0 + i) * SH_LD + k);
#pragma unroll
            for (int kk = 0; kk < 4; ++kk) {
                float4 wl = *(const float4*)(sWl + (k + kk) * 64 + c0);
                float4 wr = *(const float4*)(sWr + (k + kk) * 64 + c0);
#pragma unroll
                for (int i = 0; i < 4; ++i) {
                    float h = (&hv[i].x)[kk];
                    accl[i][0] += h * wl.x; accr[i][0] += h * wr.x;
                    accl[i][1] += h * wl.y; accr[i][1] += h * wr.y;
                    accl[i][2] += h * wl.z; accr[i][2] += h * wr.z;
                    accl[i][3] += h * wl.w; accr[i][3] += h * wr.w;
                }
            }
        }
#pragma unroll
        for (int i = 0; i < 4; ++i) {
            int n = n0 + r0 + i;
            if (n < n_nodes) {
                float4 gl = make_float4(accl[i][0], accl[i][1], accl[i][2], accl[i][3]);
                float4 rr = make_float4(accr[i][0] + sb2[c0 + 0], accr[i][1] + sb2[c0 + 1],
                                        accr[i][2] + sb2[c0 + 2], accr[i][3] + sb2[c0 + 3]);
                *(float4*)(g1 + (size_t)n * 64 + c0) = gl;
                *(float4*)(r1 + (size_t)n * 64 + c0) = rr;
            }
        }
    }
}

// conv2 aggregation fused with relu, W_out projection, graph pooling, and
// per-graph node counting. Coalesced edge loads + __shfl broadcast (R5);
// run-deferred atomic flush on sorted batch (R3).
__global__ __launch_bounds__(256) void k_gather2(
    const int* __restrict__ csrp, const int* __restrict__ off,
    const int* __restrict__ deg_i, const float* __restrict__ inv,
    const float* __restrict__ g1, const float* __restrict__ r1,
    const int* __restrict__ batch, const float* __restrict__ Wout,
    float* __restrict__ outacc, float* __restrict__ cnt, int n_nodes) {
    int lane = threadIdx.x & 63;
    int w = blockIdx.x * 4 + (threadIdx.x >> 6);
    int nw = gridDim.x * 4;
    int per = (n_nodes + nw - 1) / nw;
    int n0 = w * per;
    int n1 = n0 + per; if (n1 > n_nodes) n1 = n_nodes;
    float wo0 = Wout[lane * 2 + 0], wo1 = Wout[lane * 2 + 1];
    float p0 = 0.f, p1 = 0.f, pc = 0.f;
    int curg = -1;
    for (int cb = n0; cb < n1; cb += 64) {
        int cn = n1 - cb; if (cn > 64) cn = 64;
        int voff = 0, vdeg = 0, vbat = 0; float vinv = 0.f;
        if (lane < cn) {
            voff = off[cb + lane]; vdeg = deg_i[cb + lane];
            vinv = inv[cb + lane]; vbat = batch[cb + lane];
        }
        for (int j = 0; j < cn; ++j) {
            int o = __shfl(voff, j), d = __shfl(vdeg, j), g = __shfl(vbat, j);
            float iv = __shfl(vinv, j);
            float acc = 0.f;
            for (int base = 0; base < d; base += 64) {
                int rem = d - base; if (rem > 64) rem = 64;
                int v = (lane < rem) ? csrp[o + base + lane] : 0;
                int full = rem & ~3;
                for (int k = 0; k < full; k += 4) {
                    int s0 = __shfl(v, k)     & 0xFFFFF;
                    int s1 = __shfl(v, k + 1) & 0xFFFFF;
                    int s2 = __shfl(v, k + 2) & 0xFFFFF;
                    int s3 = __shfl(v, k + 3) & 0xFFFFF;
                    float a0 = g1[(size_t)s0 * 64 + lane];
                    float a1 = g1[(size_t)s1 * 64 + lane];
                    float a2 = g1[(size_t)s2 * 64 + lane];
                    float a3 = g1[(size_t)s3 * 64 + lane];
                    acc += (a0 + a1) + (a2 + a3);
                }
                for (int k = full; k < rem; ++k)
                    acc += g1[(size_t)(__shfl(v, k) & 0xFFFFF) * 64 + lane];
            }
            float val = fmaxf(acc * iv + r1[(size_t)(cb + j) * 64 + lane], 0.f);
            if (g != curg) {        // wave-uniform branch
                float q0 = p0, q1 = p1;
#pragma unroll
                for (int m = 1; m < 64; m <<= 1) { q0 += __shfl_xor(q0, m); q1 += __shfl_xor(q1, m); }
                if (lane == 0 && curg >= 0) {
                    atomicAdd(&outacc[curg * 2 + 0], q0);
                    atomicAdd(&outacc[curg * 2 + 1], q1);
                    atomicAdd(&cnt[curg], pc);
                }
                p0 = 0.f; p1 = 0.f; pc = 0.f; curg = g;
            }
            p0 += val * wo0;
            p1 += val * wo1;
            pc += 1.0f;             // same on all lanes; flushed from lane 0 only
        }
    }
    {
        float q0 = p0, q1 = p1;
#pragma unroll
        for (int m = 1; m < 64; m <<= 1) { q0 += __shfl_xor(q0, m); q1 += __shfl_xor(q1, m); }
        if (lane == 0 && curg >= 0) {
            atomicAdd(&outacc[curg * 2 + 0], q0);
            atomicAdd(&outacc[curg * 2 + 1], q1);
            atomicAdd(&cnt[curg], pc);
        }
    }
}

__global__ void k_out(const float* __restrict__ outacc, const float* __restrict__ cnt,
                      const float* __restrict__ bout, float* __restrict__ out, int n_graphs) {
    int i = blockIdx.x * 256 + threadIdx.x;
    if (i < n_graphs * 2) {
        int g = i >> 1, c = i & 1;
        out[i] = outacc[i] / fmaxf(cnt[g], 1.0f) + bout[c];
    }
}

extern "C" void kernel_launch(void* const* d_in, const int* in_sizes, int n_in,
                              void* d_out, int out_size, void* d_ws, size_t ws_size,
                              hipStream_t stream) {
    const int* x     = (const int*)d_in[0];
    const int* ei    = (const int*)d_in[1];
    const int* batch = (const int*)d_in[2];
    const float* se   = (const float*)d_in[4];
    const float* ce   = (const float*)d_in[5];
    const float* Win  = (const float*)d_in[6];
    const float* bin  = (const float*)d_in[7];
    const float* W1l  = (const float*)d_in[8];
    const float* b1   = (const float*)d_in[9];
    const float* W1r  = (const float*)d_in[10];
    const float* W2l  = (const float*)d_in[11];
    const float* b2   = (const float*)d_in[12];
    const float* W2r  = (const float*)d_in[13];
    const float* Wout = (const float*)d_in[14];
    const float* bout = (const float*)d_in[15];
    float* out = (float*)d_out;

    int n_nodes  = in_sizes[0] / 2;
    int n_edges  = in_sizes[1] / 2;
    int n_graphs = out_size / 2;
    const int* src = ei;
    const int* dst = ei + n_edges;

    char* p = (char*)d_ws;
    auto take = [&](size_t bytes) { char* r = p; p += (bytes + 255) & ~(size_t)255; return r; };
    float* h1     = (float*)take((size_t)n_nodes * 64 * 4);
    float* g1     = (float*)take((size_t)n_nodes * 64 * 4);
    float* r1     = (float*)take((size_t)n_nodes * 64 * 4);
    int*   csrp   = (int*)take((size_t)n_edges * 4);
    int*   rank   = (int*)take((size_t)n_edges * 4);
    int*   ntype  = (int*)take((size_t)n_nodes * 4);
    int*   deg_i  = (int*)take((size_t)n_nodes * 4);
    int*   off    = (int*)take((size_t)n_nodes * 4);
    float* inv    = (float*)take((size_t)n_nodes * 4);
    int*   bsum   = (int*)take(512 * 4);
    int*   bofs   = (int*)take(512 * 4);
    float* cnt    = (float*)take((size_t)n_graphs * 4);
    float* outacc = (float*)take((size_t)n_graphs * 8);
    float* h0tab  = (float*)take(4096 * 4);
    float* hltab  = (float*)take(4096 * 4);
    float* hrtab  = (float*)take(4096 * 4);

    int nbN = (n_nodes + 255) / 256;
    int nbE = (n_edges + 255) / 256;

    hipMemsetAsync(deg_i, 0, (size_t)n_nodes * 4, stream);
    hipMemsetAsync(cnt, 0, (size_t)n_graphs * 4, stream);
    hipMemsetAsync(outacc, 0, (size_t)n_graphs * 8, stream);

    k_tab0<<<64, 64, 0, stream>>>(se, ce, Win, bin, h0tab);
    k_tab1<<<64, 64, 0, stream>>>(h0tab, W1l, W1r, b1, hltab, hrtab);
    k_prep<<<nbN, 256, 0, stream>>>(x, ntype, n_nodes);
    k_count<<<nbE, 256, 0, stream>>>(dst, deg_i, rank, n_edges);
    k_scan1<<<nbN, 256, 0, stream>>>(deg_i, off, bsum, n_nodes);
    k_scan2<<<1, 512, 0, stream>>>(bsum, bofs, nbN);
    k_scan3<<<nbN, 256, 0, stream>>>(off, bofs, deg_i, inv, n_nodes);
    k_fill<<<nbE, 256, 0, stream>>>(src, dst, off, rank, ntype, csrp, n_edges);
    k_gather1<<<2048, 256, 0, stream>>>(csrp, off, deg_i, inv, ntype, hltab, hrtab, h1, n_nodes);
    k_lin2<<<768, 256, 0, stream>>>(h1, W2l, W2r, b2, g1, r1, n_nodes);
    k_gather2<<<2048, 256, 0, stream>>>(csrp, off, deg_i, inv, g1, r1, batch, Wout,
                                        outacc, cnt, n_nodes);
    k_out<<<(n_graphs * 2 + 255) / 256, 256, 0, stream>>>(outacc, cnt, bout, out, n_graphs);
}

// Round 7
// 208.605 us; speedup vs baseline: 4.9909x; 1.0330x over previous
//
#include <hip/hip_runtime.h>
#include <hip/hip_bf16.h>

// ---------------------------------------------------------------------------
// GNN classifier on MI355X.
//   h0 = relu([shape_emb[x0]|color_emb[x1]] @ W_in + b_in)   -> 64-entry table
//   conv1: h1 = relu( seg_sum(hltab[type[src]],dst)/deg + hrtab[type] )
//          hltab = h0tab@W1l, hrtab = h0tab@W1r + b1          (linearity)
//   conv2 by linearity:  g1 = h1@W2l, r1 = h1@W2r + b2  (dense GEMM)
//          h2 = relu( seg_sum(g1[src],dst)/deg + r1 )
//   out   = seg_sum(h2@W_out, batch)/cnt + b_out   (fused into the gather)
// Aggregations via per-call CSR (counting sort by dst) -> gathers.
//
// R2: full unroll in k_lin2 spilled (256 VGPR, 1.9 GB scratch). Keep unroll 2.
// R3: batch is SORTED -> per-node atomicAdd(cnt[batch[n]]) serialized; count
//     in gather2's run-deferred flush instead.
// R4: atomicAdd-with-return in k_fill stalled every lane ~400cy; rank fused
//     into k_count's atomic, k_fill is now a fire-and-forget scatter.
// R5: wave-uniform broadcast loads in the gathers -> coalesced 64-edge loads
//     + __shfl broadcast; ntype packed into the CSR value (src | type<<20).
// R6: k_gather2 is fetch-traffic-bound: 1.2M random 256B g1-row reads miss
//     the 4MB/XCD L2 (~50%) -> 147MB/dispatch over the fabric at 2.9TB/s.
//     Fix: g1 stored as PACKED BF16 (128B rows, 12.8MB total) -> half the
//     bytes per miss and higher L2 hit rate. Error ~4e-6 << 2e-5 threshold.
// ---------------------------------------------------------------------------

__device__ __forceinline__ unsigned bf16rn(float x) {
    unsigned b = __float_as_uint(x);
    return (b + 0x7FFFu + ((b >> 16) & 1u)) >> 16;       // round-to-nearest-even
}
__device__ __forceinline__ unsigned bf16pack2(float lo, float hi) {
    return bf16rn(lo) | (bf16rn(hi) << 16);
}

__global__ void k_tab0(const float* __restrict__ se, const float* __restrict__ ce,
                       const float* __restrict__ Win, const float* __restrict__ bin,
                       float* __restrict__ h0tab) {
    int t = blockIdx.x, j = threadIdx.x;        // 64 blocks x 64 threads
    int s = t >> 3, c = t & 7;
    float acc = bin[j];
    for (int k = 0; k < 64; ++k) {
        acc += se[s * 64 + k] * Win[k * 64 + j];
        acc += ce[c * 64 + k] * Win[(64 + k) * 64 + j];
    }
    h0tab[t * 64 + j] = fmaxf(acc, 0.f);
}

__global__ void k_tab1(const float* __restrict__ h0tab, const float* __restrict__ W1l,
                       const float* __restrict__ W1r, const float* __restrict__ b1,
                       float* __restrict__ hltab, float* __restrict__ hrtab) {
    int t = blockIdx.x, j = threadIdx.x;        // 64 blocks x 64 threads
    float al = 0.f, ar = b1[j];
    for (int k = 0; k < 64; ++k) {
        float h = h0tab[t * 64 + k];
        al += h * W1l[k * 64 + j];
        ar += h * W1r[k * 64 + j];
    }
    hltab[t * 64 + j] = al;
    hrtab[t * 64 + j] = ar;
}

// ntype only; NO atomics (R3 lesson).
__global__ void k_prep(const int* __restrict__ x, int* __restrict__ ntype, int n_nodes) {
    int n = blockIdx.x * 256 + threadIdx.x;
    if (n < n_nodes) {
        int2 v = *(const int2*)(x + 2 * (size_t)n);
        ntype[n] = v.x * 8 + v.y;
    }
}

// count in-degree AND record each edge's rank among its dst's edges (R4).
__global__ void k_count(const int* __restrict__ dst, int* __restrict__ deg_i,
                        int* __restrict__ rank, int n_edges) {
    int e = blockIdx.x * 256 + threadIdx.x;
    if (e < n_edges) rank[e] = atomicAdd(&deg_i[dst[e]], 1);
}

// exclusive scan, 3-kernel two-level
__global__ void k_scan1(const int* __restrict__ deg_i, int* __restrict__ off,
                        int* __restrict__ bsum, int n) {
    __shared__ int sbuf[2][256];
    int tid = threadIdx.x;
    int i = blockIdx.x * 256 + tid;
    int d = (i < n) ? deg_i[i] : 0;
    int cur = 0;
    sbuf[0][tid] = d;
    __syncthreads();
    for (int ofs = 1; ofs < 256; ofs <<= 1) {
        int v = sbuf[cur][tid];
        if (tid >= ofs) v += sbuf[cur][tid - ofs];
        sbuf[cur ^ 1][tid] = v;
        cur ^= 1;
        __syncthreads();
    }
    if (i < n) off[i] = sbuf[cur][tid] - d;
    if (tid == 255) bsum[blockIdx.x] = sbuf[cur][tid];
}

__global__ void k_scan2(const int* __restrict__ bsum, int* __restrict__ bofs, int nb) {
    __shared__ int sbuf[2][512];
    int tid = threadIdx.x;
    int d = (tid < nb) ? bsum[tid] : 0;
    int cur = 0;
    sbuf[0][tid] = d;
    __syncthreads();
    for (int ofs = 1; ofs < 512; ofs <<= 1) {
        int v = sbuf[cur][tid];
        if (tid >= ofs) v += sbuf[cur][tid - ofs];
        sbuf[cur ^ 1][tid] = v;
        cur ^= 1;
        __syncthreads();
    }
    if (tid < nb) bofs[tid] = sbuf[cur][tid] - d;
}

__global__ void k_scan3(int* __restrict__ off, const int* __restrict__ bofs,
                        const int* __restrict__ deg_i, float* __restrict__ inv, int n) {
    int i = blockIdx.x * 256 + threadIdx.x;
    if (i < n) {
        off[i] = off[i] + bofs[blockIdx.x];
        inv[i] = 1.0f / fmaxf((float)deg_i[i], 1.0f);
    }
}

// atomic-free scatter; value packs src index (low 20b) and src type (<<20).
__global__ void k_fill(const int* __restrict__ src, const int* __restrict__ dst,
                       const int* __restrict__ off, const int* __restrict__ rank,
                       const int* __restrict__ ntype, int* __restrict__ csrp,
                       int n_edges) {
    int e = blockIdx.x * 256 + threadIdx.x;
    if (e < n_edges) {
        int s = src[e];
        csrp[off[dst[e]] + rank[e]] = s | (ntype[s] << 20);
    }
}

// conv1: wave per node chunk; 64 edges loaded coalesced, types broadcast via
// __shfl; per-edge work is 1 shfl + 1 conflict-free LDS read (R5).
__global__ __launch_bounds__(256) void k_gather1(
    const int* __restrict__ csrp, const int* __restrict__ off,
    const int* __restrict__ deg_i, const float* __restrict__ inv,
    const int* __restrict__ ntype, const float* __restrict__ hltab,
    const float* __restrict__ hrtab, float* __restrict__ h1, int n_nodes) {
    __shared__ float tl[4096];
    __shared__ float tr_[4096];
    for (int i = threadIdx.x; i < 4096; i += 256) { tl[i] = hltab[i]; tr_[i] = hrtab[i]; }
    __syncthreads();
    int lane = threadIdx.x & 63;
    int w = blockIdx.x * 4 + (threadIdx.x >> 6);
    int nw = gridDim.x * 4;
    int per = (n_nodes + nw - 1) / nw;
    int n0 = w * per;
    int n1 = n0 + per; if (n1 > n_nodes) n1 = n_nodes;
    for (int cb = n0; cb < n1; cb += 64) {
        int cn = n1 - cb; if (cn > 64) cn = 64;
        int voff = 0, vdeg = 0, vnt = 0; float vinv = 0.f;
        if (lane < cn) {
            voff = off[cb + lane]; vdeg = deg_i[cb + lane];
            vinv = inv[cb + lane]; vnt  = ntype[cb + lane];
        }
        for (int j = 0; j < cn; ++j) {
            int o = __shfl(voff, j), d = __shfl(vdeg, j);
            float iv = __shfl(vinv, j);
            int tn = __shfl(vnt, j);
            float acc = 0.f;
            for (int base = 0; base < d; base += 64) {
                int rem = d - base; if (rem > 64) rem = 64;
                int v = (lane < rem) ? csrp[o + base + lane] : 0;
                int full = rem & ~3;
                for (int k = 0; k < full; k += 4) {
                    int t0 = __shfl(v, k)     >> 20;
                    int t1 = __shfl(v, k + 1) >> 20;
                    int t2 = __shfl(v, k + 2) >> 20;
                    int t3 = __shfl(v, k + 3) >> 20;
                    acc += (tl[t0 * 64 + lane] + tl[t1 * 64 + lane]) +
                           (tl[t2 * 64 + lane] + tl[t3 * 64 + lane]);
                }
                for (int k = full; k < rem; ++k)
                    acc += tl[(__shfl(v, k) >> 20) * 64 + lane];
            }
            h1[(size_t)(cb + j) * 64 + lane] = fmaxf(acc * iv + tr_[tn * 64 + lane], 0.f);
        }
    }
}

// dense conv2 GEMMs: g1 = h1@W2l (PACKED BF16, R6), r1 = h1@W2r + b2 (fp32).
#define SH_LD 68   // 64 + 4 pad: keeps float4 alignment, 2-way (free) bank aliasing
__global__ __launch_bounds__(256) void k_lin2(
    const float* __restrict__ h1, const float* __restrict__ W2l,
    const float* __restrict__ W2r, const float* __restrict__ b2,
    unsigned* __restrict__ g1p, float* __restrict__ r1, int n_nodes) {
    __shared__ float sWl[4096];
    __shared__ float sWr[4096];
    __shared__ float sb2[64];
    __shared__ float sh[64 * SH_LD];
    int tid = threadIdx.x;
    for (int i = tid; i < 4096; i += 256) { sWl[i] = W2l[i]; sWr[i] = W2r[i]; }
    if (tid < 64) sb2[tid] = b2[tid];

    int ntile = (n_nodes + 63) >> 6;
    int tr = tid >> 4, tc = tid & 15;
    int r0 = tr * 4, c0 = tc * 4;

    for (int t = blockIdx.x; t < ntile; t += gridDim.x) {
        int n0 = t << 6;
        __syncthreads();   // weights ready (1st iter) / prev readers done
        // cooperative load of 64x64 h1 tile (float4-coalesced), zero-pad tail
        {
            int lim = (n_nodes - n0) * 16;           // valid float4s
            const float4* s4 = (const float4*)(h1 + (size_t)n0 * 64);
            for (int i = tid; i < 1024; i += 256) {
                int row = i >> 4, col = i & 15;
                float4 v = (i < lim) ? s4[i] : make_float4(0.f, 0.f, 0.f, 0.f);
                *(float4*)(sh + row * SH_LD + col * 4) = v;
            }
        }
        __syncthreads();

        float accl[4][4] = {{0.f}}, accr[4][4] = {{0.f}};
#pragma unroll 2            // R2: full unroll spilled (256 VGPR, 1.9GB scratch)
        for (int k = 0; k < 64; k += 4) {
            float4 hv[4];
#pragma unroll
            for (int i = 0; i < 4; ++i)
                hv[i] = *(const float4*)(sh + (r0 + i) * SH_LD + k);
#pragma unroll
            for (int kk = 0; kk < 4; ++kk) {
                float4 wl = *(const float4*)(sWl + (k + kk) * 64 + c0);
                float4 wr = *(const float4*)(sWr + (k + kk) * 64 + c0);
#pragma unroll
                for (int i = 0; i < 4; ++i) {
                    float h = (&hv[i].x)[kk];
                    accl[i][0] += h * wl.x; accr[i][0] += h * wr.x;
                    accl[i][1] += h * wl.y; accr[i][1] += h * wr.y;
                    accl[i][2] += h * wl.z; accr[i][2] += h * wr.z;
                    accl[i][3] += h * wl.w; accr[i][3] += h * wr.w;
                }
            }
        }
#pragma unroll
        for (int i = 0; i < 4; ++i) {
            int n = n0 + r0 + i;
            if (n < n_nodes) {
                uint2 gl;
                gl.x = bf16pack2(accl[i][0], accl[i][1]);
                gl.y = bf16pack2(accl[i][2], accl[i][3]);
                float4 rr = make_float4(accr[i][0] + sb2[c0 + 0], accr[i][1] + sb2[c0 + 1],
                                        accr[i][2] + sb2[c0 + 2], accr[i][3] + sb2[c0 + 3]);
                *(uint2*)(g1p + (size_t)n * 32 + (c0 >> 1)) = gl;
                *(float4*)(r1 + (size_t)n * 64 + c0) = rr;
            }
        }
    }
}

// conv2 aggregation fused with relu, W_out projection, graph pooling, and
// per-graph node counting. g1 rows are packed bf16 (128B): lane pair (2i,2i+1)
// loads the same uint (coalesces to one 128B request) and unpacks its half.
__global__ __launch_bounds__(256) void k_gather2(
    const int* __restrict__ csrp, const int* __restrict__ off,
    const int* __restrict__ deg_i, const float* __restrict__ inv,
    const unsigned* __restrict__ g1p, const float* __restrict__ r1,
    const int* __restrict__ batch, const float* __restrict__ Wout,
    float* __restrict__ outacc, float* __restrict__ cnt, int n_nodes) {
    int lane = threadIdx.x & 63;
    int w = blockIdx.x * 4 + (threadIdx.x >> 6);
    int nw = gridDim.x * 4;
    int per = (n_nodes + nw - 1) / nw;
    int n0 = w * per;
    int n1 = n0 + per; if (n1 > n_nodes) n1 = n_nodes;
    float wo0 = Wout[lane * 2 + 0], wo1 = Wout[lane * 2 + 1];
    int half = lane >> 1;                     // uint index within the 32-uint row
    unsigned shl = (lane & 1) ? 0u : 16u;     // even lane -> low bf16, odd -> high
    float p0 = 0.f, p1 = 0.f, pc = 0.f;
    int curg = -1;
    for (int cb = n0; cb < n1; cb += 64) {
        int cn = n1 - cb; if (cn > 64) cn = 64;
        int voff = 0, vdeg = 0, vbat = 0; float vinv = 0.f;
        if (lane < cn) {
            voff = off[cb + lane]; vdeg = deg_i[cb + lane];
            vinv = inv[cb + lane]; vbat = batch[cb + lane];
        }
        for (int j = 0; j < cn; ++j) {
            int o = __shfl(voff, j), d = __shfl(vdeg, j), g = __shfl(vbat, j);
            float iv = __shfl(vinv, j);
            float acc = 0.f;
            for (int base = 0; base < d; base += 64) {
                int rem = d - base; if (rem > 64) rem = 64;
                int v = (lane < rem) ? csrp[o + base + lane] : 0;
                int full = rem & ~3;
                for (int k = 0; k < full; k += 4) {
                    size_t s0 = (size_t)(__shfl(v, k)     & 0xFFFFF);
                    size_t s1 = (size_t)(__shfl(v, k + 1) & 0xFFFFF);
                    size_t s2 = (size_t)(__shfl(v, k + 2) & 0xFFFFF);
                    size_t s3 = (size_t)(__shfl(v, k + 3) & 0xFFFFF);
                    unsigned u0 = g1p[s0 * 32 + half];
                    unsigned u1 = g1p[s1 * 32 + half];
                    unsigned u2 = g1p[s2 * 32 + half];
                    unsigned u3 = g1p[s3 * 32 + half];
                    float a0 = __uint_as_float((u0 << shl) & 0xFFFF0000u);
                    float a1 = __uint_as_float((u1 << shl) & 0xFFFF0000u);
                    float a2 = __uint_as_float((u2 << shl) & 0xFFFF0000u);
                    float a3 = __uint_as_float((u3 << shl) & 0xFFFF0000u);
                    acc += (a0 + a1) + (a2 + a3);
                }
                for (int k = full; k < rem; ++k) {
                    unsigned u = g1p[(size_t)(__shfl(v, k) & 0xFFFFF) * 32 + half];
                    acc += __uint_as_float((u << shl) & 0xFFFF0000u);
                }
            }
            float val = fmaxf(acc * iv + r1[(size_t)(cb + j) * 64 + lane], 0.f);
            if (g != curg) {        // wave-uniform branch
                float q0 = p0, q1 = p1;
#pragma unroll
                for (int m = 1; m < 64; m <<= 1) { q0 += __shfl_xor(q0, m); q1 += __shfl_xor(q1, m); }
                if (lane == 0 && curg >= 0) {
                    atomicAdd(&outacc[curg * 2 + 0], q0);
                    atomicAdd(&outacc[curg * 2 + 1], q1);
                    atomicAdd(&cnt[curg], pc);
                }
                p0 = 0.f; p1 = 0.f; pc = 0.f; curg = g;
            }
            p0 += val * wo0;
            p1 += val * wo1;
            pc += 1.0f;             // same on all lanes; flushed from lane 0 only
        }
    }
    {
        float q0 = p0, q1 = p1;
#pragma unroll
        for (int m = 1; m < 64; m <<= 1) { q0 += __shfl_xor(q0, m); q1 += __shfl_xor(q1, m); }
        if (lane == 0 && curg >= 0) {
            atomicAdd(&outacc[curg * 2 + 0], q0);
            atomicAdd(&outacc[curg * 2 + 1], q1);
            atomicAdd(&cnt[curg], pc);
        }
    }
}

__global__ void k_out(const float* __restrict__ outacc, const float* __restrict__ cnt,
                      const float* __restrict__ bout, float* __restrict__ out, int n_graphs) {
    int i = blockIdx.x * 256 + threadIdx.x;
    if (i < n_graphs * 2) {
        int g = i >> 1, c = i & 1;
        out[i] = outacc[i] / fmaxf(cnt[g], 1.0f) + bout[c];
    }
}

extern "C" void kernel_launch(void* const* d_in, const int* in_sizes, int n_in,
                              void* d_out, int out_size, void* d_ws, size_t ws_size,
                              hipStream_t stream) {
    const int* x     = (const int*)d_in[0];
    const int* ei    = (const int*)d_in[1];
    const int* batch = (const int*)d_in[2];
    const float* se   = (const float*)d_in[4];
    const float* ce   = (const float*)d_in[5];
    const float* Win  = (const float*)d_in[6];
    const float* bin  = (const float*)d_in[7];
    const float* W1l  = (const float*)d_in[8];
    const float* b1   = (const float*)d_in[9];
    const float* W1r  = (const float*)d_in[10];
    const float* W2l  = (const float*)d_in[11];
    const float* b2   = (const float*)d_in[12];
    const float* W2r  = (const float*)d_in[13];
    const float* Wout = (const float*)d_in[14];
    const float* bout = (const float*)d_in[15];
    float* out = (float*)d_out;

    int n_nodes  = in_sizes[0] / 2;
    int n_edges  = in_sizes[1] / 2;
    int n_graphs = out_size / 2;
    const int* src = ei;
    const int* dst = ei + n_edges;

    char* p = (char*)d_ws;
    auto take = [&](size_t bytes) { char* r = p; p += (bytes + 255) & ~(size_t)255; return r; };
    float*    h1     = (float*)take((size_t)n_nodes * 64 * 4);
    unsigned* g1p    = (unsigned*)take((size_t)n_nodes * 32 * 4);
    float*    r1     = (float*)take((size_t)n_nodes * 64 * 4);
    int*      csrp   = (int*)take((size_t)n_edges * 4);
    int*      rank   = (int*)take((size_t)n_edges * 4);
    int*      ntype  = (int*)take((size_t)n_nodes * 4);
    int*      deg_i  = (int*)take((size_t)n_nodes * 4);
    int*      off    = (int*)take((size_t)n_nodes * 4);
    float*    inv    = (float*)take((size_t)n_nodes * 4);
    int*      bsum   = (int*)take(512 * 4);
    int*      bofs   = (int*)take(512 * 4);
    float*    cnt    = (float*)take((size_t)n_graphs * 4);
    float*    outacc = (float*)take((size_t)n_graphs * 8);
    float*    h0tab  = (float*)take(4096 * 4);
    float*    hltab  = (float*)take(4096 * 4);
    float*    hrtab  = (float*)take(4096 * 4);

    int nbN = (n_nodes + 255) / 256;
    int nbE = (n_edges + 255) / 256;

    hipMemsetAsync(deg_i, 0, (size_t)n_nodes * 4, stream);
    hipMemsetAsync(cnt, 0, (size_t)n_graphs * 4, stream);
    hipMemsetAsync(outacc, 0, (size_t)n_graphs * 8, stream);

    k_tab0<<<64, 64, 0, stream>>>(se, ce, Win, bin, h0tab);
    k_tab1<<<64, 64, 0, stream>>>(h0tab, W1l, W1r, b1, hltab, hrtab);
    k_prep<<<nbN, 256, 0, stream>>>(x, ntype, n_nodes);
    k_count<<<nbE, 256, 0, stream>>>(dst, deg_i, rank, n_edges);
    k_scan1<<<nbN, 256, 0, stream>>>(deg_i, off, bsum, n_nodes);
    k_scan2<<<1, 512, 0, stream>>>(bsum, bofs, nbN);
    k_scan3<<<nbN, 256, 0, stream>>>(off, bofs, deg_i, inv, n_nodes);
    k_fill<<<nbE, 256, 0, stream>>>(src, dst, off, rank, ntype, csrp, n_edges);
    k_gather1<<<2048, 256, 0, stream>>>(csrp, off, deg_i, inv, ntype, hltab, hrtab, h1, n_nodes);
    k_lin2<<<768, 256, 0, stream>>>(h1, W2l, W2r, b2, g1p, r1, n_nodes);
    k_gather2<<<2048, 256, 0, stream>>>(csrp, off, deg_i, inv, g1p, r1, batch, Wout,
                                        outacc, cnt, n_nodes);
    k_out<<<(n_graphs * 2 + 255) / 256, 256, 0, stream>>>(outacc, cnt, bout, out, n_graphs);
}

// Round 8
// 168.402 us; speedup vs baseline: 6.1824x; 1.2387x over previous
//
#include <hip/hip_runtime.h>
#include <hip/hip_bf16.h>

// ---------------------------------------------------------------------------
// GNN classifier on MI355X.
//   h0 = relu([shape_emb[x0]|color_emb[x1]] @ W_in + b_in)   -> 64-entry table
//   conv1: h1 = relu( seg_sum(hltab[type[src]],dst)/deg + hrtab[type] )
//          hltab = h0tab@W1l, hrtab = h0tab@W1r + b1          (linearity)
//   conv2 by linearity:  g1 = h1@W2l, r1 = h1@W2r + b2  (dense GEMM)
//          h2 = relu( seg_sum(g1[src],dst)/deg + r1 )
//   out   = seg_sum(h2@W_out, batch)/cnt + b_out   (fused into the gather)
//
// R2: full unroll in k_lin2 spilled (256 VGPR, 1.9 GB scratch). Keep unroll 2.
// R3: batch is SORTED -> per-node atomicAdd(cnt[batch[n]]) serialized; count
//     in gather2's run-deferred flush instead.
// R4: atomicAdd-with-return stalls every lane ~400cy.
// R5: wave-uniform broadcast loads in the gathers -> coalesced 64-edge loads
//     + __shfl broadcast; ntype packed into the CSR value.
// R6: k_gather2 fetch-bound -> g1 stored as packed bf16 (128B rows).
// R7: k_count's 1.2M device-scope atomics hit the memory-side RMW throughput
//     wall (42MB write-through, 0.9TB/s, 50us); one-atomic-per-edge is already
//     minimal, so the counting sort itself must go. Replaced the whole CSR
//     build with a bucketed LDS-only sort (dst>>8 buckets, per-bucket 256-way
//     LDS counting sort): ZERO device-scope atomics.
// ---------------------------------------------------------------------------

#define NBLK 512   // blocks used by k_hist / k_scatter (chunked edge partition)

__device__ __forceinline__ unsigned bf16rn(float x) {
    unsigned b = __float_as_uint(x);
    return (b + 0x7FFFu + ((b >> 16) & 1u)) >> 16;       // round-to-nearest-even
}
__device__ __forceinline__ unsigned bf16pack2(float lo, float hi) {
    return bf16rn(lo) | (bf16rn(hi) << 16);
}

__global__ void k_tab0(const float* __restrict__ se, const float* __restrict__ ce,
                       const float* __restrict__ Win, const float* __restrict__ bin,
                       float* __restrict__ h0tab) {
    int t = blockIdx.x, j = threadIdx.x;        // 64 blocks x 64 threads
    int s = t >> 3, c = t & 7;
    float acc = bin[j];
    for (int k = 0; k < 64; ++k) {
        acc += se[s * 64 + k] * Win[k * 64 + j];
        acc += ce[c * 64 + k] * Win[(64 + k) * 64 + j];
    }
    h0tab[t * 64 + j] = fmaxf(acc, 0.f);
}

__global__ void k_tab1(const float* __restrict__ h0tab, const float* __restrict__ W1l,
                       const float* __restrict__ W1r, const float* __restrict__ b1,
                       float* __restrict__ hltab, float* __restrict__ hrtab) {
    int t = blockIdx.x, j = threadIdx.x;        // 64 blocks x 64 threads
    float al = 0.f, ar = b1[j];
    for (int k = 0; k < 64; ++k) {
        float h = h0tab[t * 64 + k];
        al += h * W1l[k * 64 + j];
        ar += h * W1r[k * 64 + j];
    }
    hltab[t * 64 + j] = al;
    hrtab[t * 64 + j] = ar;
}

// ntype only; NO atomics (R3 lesson).
__global__ void k_prep(const int* __restrict__ x, int* __restrict__ ntype, int n_nodes) {
    int n = blockIdx.x * 256 + threadIdx.x;
    if (n < n_nodes) {
        int2 v = *(const int2*)(x + 2 * (size_t)n);
        ntype[n] = v.x * 8 + v.y;
    }
}

// ---- bucketed CSR build (R7): LDS atomics only ----------------------------

// per-(bucket,block) histogram. bucket = dst >> 8 (<= 512 buckets).
__global__ __launch_bounds__(256) void k_hist(const int* __restrict__ dst,
                                              int* __restrict__ histT,
                                              int n_edges, int nb) {
    __shared__ int h[512];
    int tid = threadIdx.x, blk = blockIdx.x;
    for (int i = tid; i < nb; i += 256) h[i] = 0;
    __syncthreads();
    int per = (n_edges + NBLK - 1) / NBLK;
    int e0 = blk * per;
    int e1 = e0 + per; if (e1 > n_edges) e1 = n_edges;
    for (int e = e0 + tid; e < e1; e += 256)
        atomicAdd(&h[dst[e] >> 8], 1);
    __syncthreads();
    for (int i = tid; i < nb; i += 256)
        histT[(size_t)i * NBLK + blk] = h[i];      // row b: counts per block
}

// per-bucket exclusive scan over the NBLK block counts.
__global__ void k_bscan(const int* __restrict__ histT, int* __restrict__ blockOff,
                        int* __restrict__ btot) {
    __shared__ int sbuf[2][512];
    int b = blockIdx.x, tid = threadIdx.x;
    int d = histT[(size_t)b * NBLK + tid];
    int cur = 0;
    sbuf[0][tid] = d;
    __syncthreads();
    for (int ofs = 1; ofs < 512; ofs <<= 1) {
        int v = sbuf[cur][tid];
        if (tid >= ofs) v += sbuf[cur][tid - ofs];
        sbuf[cur ^ 1][tid] = v;
        cur ^= 1;
        __syncthreads();
    }
    blockOff[(size_t)b * NBLK + tid] = sbuf[cur][tid] - d;
    if (tid == 511) btot[b] = sbuf[cur][tid];
}

// exclusive scan of bucket totals -> bucket bases.
__global__ void k_bscan2(const int* __restrict__ btot, int* __restrict__ bbase, int nb) {
    __shared__ int sbuf[2][512];
    int tid = threadIdx.x;
    int d = (tid < nb) ? btot[tid] : 0;
    int cur = 0;
    sbuf[0][tid] = d;
    __syncthreads();
    for (int ofs = 1; ofs < 512; ofs <<= 1) {
        int v = sbuf[cur][tid];
        if (tid >= ofs) v += sbuf[cur][tid - ofs];
        sbuf[cur ^ 1][tid] = v;
        cur ^= 1;
        __syncthreads();
    }
    if (tid < nb) bbase[tid] = sbuf[cur][tid] - d;
}

// scatter edges into bucket-grouped order. Packed: src | type<<17 | dstLow<<23
// (n_nodes < 2^17, type < 64, dstLow < 256 -> 31 bits).
__global__ __launch_bounds__(256) void k_scatter(
    const int* __restrict__ src, const int* __restrict__ dst,
    const int* __restrict__ ntype, const int* __restrict__ bbase,
    const int* __restrict__ blockOff, int* __restrict__ bedge,
    int n_edges, int nb) {
    __shared__ int cur[512];
    int tid = threadIdx.x, blk = blockIdx.x;
    for (int i = tid; i < nb; i += 256)
        cur[i] = bbase[i] + blockOff[(size_t)i * NBLK + blk];
    __syncthreads();
    int per = (n_edges + NBLK - 1) / NBLK;
    int e0 = blk * per;
    int e1 = e0 + per; if (e1 > n_edges) e1 = n_edges;
    for (int e = e0 + tid; e < e1; e += 256) {
        int d = dst[e], s = src[e];
        int pos = atomicAdd(&cur[d >> 8], 1);       // LDS atomic (fast)
        bedge[pos] = s | (ntype[s] << 17) | ((d & 255) << 23);
    }
}

// per-bucket 256-way counting sort in LDS; emits deg/off/inv + final csrp
// (same src|type<<20 format the gathers consume).
__global__ __launch_bounds__(256) void k_bsort(
    const int* __restrict__ bedge, const int* __restrict__ bbase,
    const int* __restrict__ btot, int* __restrict__ csrp,
    int* __restrict__ deg, int* __restrict__ off, float* __restrict__ inv,
    int n_nodes) {
    __shared__ int cnt[256];
    __shared__ int sbuf[2][256];
    __shared__ int loff[256];
    int b = blockIdx.x, tid = threadIdx.x;
    int base = bbase[b], tot = btot[b];
    cnt[tid] = 0;
    __syncthreads();
    for (int i = tid; i < tot; i += 256)
        atomicAdd(&cnt[(bedge[base + i] >> 23) & 255], 1);
    __syncthreads();
    int d = cnt[tid];
    int cur = 0;
    sbuf[0][tid] = d;
    __syncthreads();
    for (int ofs = 1; ofs < 256; ofs <<= 1) {
        int v = sbuf[cur][tid];
        if (tid >= ofs) v += sbuf[cur][tid - ofs];
        sbuf[cur ^ 1][tid] = v;
        cur ^= 1;
        __syncthreads();
    }
    loff[tid] = sbuf[cur][tid] - d;                  // exclusive within bucket
    __syncthreads();
    int n = b * 256 + tid;
    if (n < n_nodes) {
        deg[n] = d;
        off[n] = base + loff[tid];
        inv[n] = 1.0f / fmaxf((float)d, 1.0f);
    }
    cnt[tid] = loff[tid];                            // reuse as cursor
    __syncthreads();
    for (int i = tid; i < tot; i += 256) {
        int v = bedge[base + i];
        int pos = atomicAdd(&cnt[(v >> 23) & 255], 1);
        csrp[base + pos] = (v & 0x1FFFF) | (((v >> 17) & 63) << 20);
    }
}

// ---- compute kernels (unchanged from R7) -----------------------------------

__global__ __launch_bounds__(256) void k_gather1(
    const int* __restrict__ csrp, const int* __restrict__ off,
    const int* __restrict__ deg_i, const float* __restrict__ inv,
    const int* __restrict__ ntype, const float* __restrict__ hltab,
    const float* __restrict__ hrtab, float* __restrict__ h1, int n_nodes) {
    __shared__ float tl[4096];
    __shared__ float tr_[4096];
    for (int i = threadIdx.x; i < 4096; i += 256) { tl[i] = hltab[i]; tr_[i] = hrtab[i]; }
    __syncthreads();
    int lane = threadIdx.x & 63;
    int w = blockIdx.x * 4 + (threadIdx.x >> 6);
    int nw = gridDim.x * 4;
    int per = (n_nodes + nw - 1) / nw;
    int n0 = w * per;
    int n1 = n0 + per; if (n1 > n_nodes) n1 = n_nodes;
    for (int cb = n0; cb < n1; cb += 64) {
        int cn = n1 - cb; if (cn > 64) cn = 64;
        int voff = 0, vdeg = 0, vnt = 0; float vinv = 0.f;
        if (lane < cn) {
            voff = off[cb + lane]; vdeg = deg_i[cb + lane];
            vinv = inv[cb + lane]; vnt  = ntype[cb + lane];
        }
        for (int j = 0; j < cn; ++j) {
            int o = __shfl(voff, j), d = __shfl(vdeg, j);
            float iv = __shfl(vinv, j);
            int tn = __shfl(vnt, j);
            float acc = 0.f;
            for (int base = 0; base < d; base += 64) {
                int rem = d - base; if (rem > 64) rem = 64;
                int v = (lane < rem) ? csrp[o + base + lane] : 0;
                int full = rem & ~3;
                for (int k = 0; k < full; k += 4) {
                    int t0 = __shfl(v, k)     >> 20;
                    int t1 = __shfl(v, k + 1) >> 20;
                    int t2 = __shfl(v, k + 2) >> 20;
                    int t3 = __shfl(v, k + 3) >> 20;
                    acc += (tl[t0 * 64 + lane] + tl[t1 * 64 + lane]) +
                           (tl[t2 * 64 + lane] + tl[t3 * 64 + lane]);
                }
                for (int k = full; k < rem; ++k)
                    acc += tl[(__shfl(v, k) >> 20) * 64 + lane];
            }
            h1[(size_t)(cb + j) * 64 + lane] = fmaxf(acc * iv + tr_[tn * 64 + lane], 0.f);
        }
    }
}

#define SH_LD 68   // 64 + 4 pad: keeps float4 alignment, 2-way (free) bank aliasing
__global__ __launch_bounds__(256) void k_lin2(
    const float* __restrict__ h1, const float* __restrict__ W2l,
    const float* __restrict__ W2r, const float* __restrict__ b2,
    unsigned* __restrict__ g1p, float* __restrict__ r1, int n_nodes) {
    __shared__ float sWl[4096];
    __shared__ float sWr[4096];
    __shared__ float sb2[64];
    __shared__ float sh[64 * SH_LD];
    int tid = threadIdx.x;
    for (int i = tid; i < 4096; i += 256) { sWl[i] = W2l[i]; sWr[i] = W2r[i]; }
    if (tid < 64) sb2[tid] = b2[tid];

    int ntile = (n_nodes + 63) >> 6;
    int tr = tid >> 4, tc = tid & 15;
    int r0 = tr * 4, c0 = tc * 4;

    for (int t = blockIdx.x; t < ntile; t += gridDim.x) {
        int n0 = t << 6;
        __syncthreads();
        {
            int lim = (n_nodes - n0) * 16;
            const float4* s4 = (const float4*)(h1 + (size_t)n0 * 64);
            for (int i = tid; i < 1024; i += 256) {
                int row = i >> 4, col = i & 15;
                float4 v = (i < lim) ? s4[i] : make_float4(0.f, 0.f, 0.f, 0.f);
                *(float4*)(sh + row * SH_LD + col * 4) = v;
            }
        }
        __syncthreads();

        float accl[4][4] = {{0.f}}, accr[4][4] = {{0.f}};
#pragma unroll 2            // R2: full unroll spilled (256 VGPR, 1.9GB scratch)
        for (int k = 0; k < 64; k += 4) {
            float4 hv[4];
#pragma unroll
            for (int i = 0; i < 4; ++i)
                hv[i] = *(const float4*)(sh + (r0 + i) * SH_LD + k);
#pragma unroll
            for (int kk = 0; kk < 4; ++kk) {
                float4 wl = *(const float4*)(sWl + (k + kk) * 64 + c0);
                float4 wr = *(const float4*)(sWr + (k + kk) * 64 + c0);
#pragma unroll
                for (int i = 0; i < 4; ++i) {
                    float h = (&hv[i].x)[kk];
                    accl[i][0] += h * wl.x; accr[i][0] += h * wr.x;
                    accl[i][1] += h * wl.y; accr[i][1] += h * wr.y;
                    accl[i][2] += h * wl.z; accr[i][2] += h * wr.z;
                    accl[i][3] += h * wl.w; accr[i][3] += h * wr.w;
                }
            }
        }
#pragma unroll
        for (int i = 0; i < 4; ++i) {
            int n = n0 + r0 + i;
            if (n < n_nodes) {
                uint2 gl;
                gl.x = bf16pack2(accl[i][0], accl[i][1]);
                gl.y = bf16pack2(accl[i][2], accl[i][3]);
                float4 rr = make_float4(accr[i][0] + sb2[c0 + 0], accr[i][1] + sb2[c0 + 1],
                                        accr[i][2] + sb2[c0 + 2], accr[i][3] + sb2[c0 + 3]);
                *(uint2*)(g1p + (size_t)n * 32 + (c0 >> 1)) = gl;
                *(float4*)(r1 + (size_t)n * 64 + c0) = rr;
            }
        }
    }
}

__global__ __launch_bounds__(256) void k_gather2(
    const int* __restrict__ csrp, const int* __restrict__ off,
    const int* __restrict__ deg_i, const float* __restrict__ inv,
    const unsigned* __restrict__ g1p, const float* __restrict__ r1,
    const int* __restrict__ batch, const float* __restrict__ Wout,
    float* __restrict__ outacc, float* __restrict__ cnt, int n_nodes) {
    int lane = threadIdx.x & 63;
    int w = blockIdx.x * 4 + (threadIdx.x >> 6);
    int nw = gridDim.x * 4;
    int per = (n_nodes + nw - 1) / nw;
    int n0 = w * per;
    int n1 = n0 + per; if (n1 > n_nodes) n1 = n_nodes;
    float wo0 = Wout[lane * 2 + 0], wo1 = Wout[lane * 2 + 1];
    int half = lane >> 1;
    unsigned shl = (lane & 1) ? 0u : 16u;
    float p0 = 0.f, p1 = 0.f, pc = 0.f;
    int curg = -1;
    for (int cb = n0; cb < n1; cb += 64) {
        int cn = n1 - cb; if (cn > 64) cn = 64;
        int voff = 0, vdeg = 0, vbat = 0; float vinv = 0.f;
        if (lane < cn) {
            voff = off[cb + lane]; vdeg = deg_i[cb + lane];
            vinv = inv[cb + lane]; vbat = batch[cb + lane];
        }
        for (int j = 0; j < cn; ++j) {
            int o = __shfl(voff, j), d = __shfl(vdeg, j), g = __shfl(vbat, j);
            float iv = __shfl(vinv, j);
            float acc = 0.f;
            for (int base = 0; base < d; base += 64) {
                int rem = d - base; if (rem > 64) rem = 64;
                int v = (lane < rem) ? csrp[o + base + lane] : 0;
                int full = rem & ~3;
                for (int k = 0; k < full; k += 4) {
                    size_t s0 = (size_t)(__shfl(v, k)     & 0xFFFFF);
                    size_t s1 = (size_t)(__shfl(v, k + 1) & 0xFFFFF);
                    size_t s2 = (size_t)(__shfl(v, k + 2) & 0xFFFFF);
                    size_t s3 = (size_t)(__shfl(v, k + 3) & 0xFFFFF);
                    unsigned u0 = g1p[s0 * 32 + half];
                    unsigned u1 = g1p[s1 * 32 + half];
                    unsigned u2 = g1p[s2 * 32 + half];
                    unsigned u3 = g1p[s3 * 32 + half];
                    float a0 = __uint_as_float((u0 << shl) & 0xFFFF0000u);
                    float a1 = __uint_as_float((u1 << shl) & 0xFFFF0000u);
                    float a2 = __uint_as_float((u2 << shl) & 0xFFFF0000u);
                    float a3 = __uint_as_float((u3 << shl) & 0xFFFF0000u);
                    acc += (a0 + a1) + (a2 + a3);
                }
                for (int k = full; k < rem; ++k) {
                    unsigned u = g1p[(size_t)(__shfl(v, k) & 0xFFFFF) * 32 + half];
                    acc += __uint_as_float((u << shl) & 0xFFFF0000u);
                }
            }
            float val = fmaxf(acc * iv + r1[(size_t)(cb + j) * 64 + lane], 0.f);
            if (g != curg) {
                float q0 = p0, q1 = p1;
#pragma unroll
                for (int m = 1; m < 64; m <<= 1) { q0 += __shfl_xor(q0, m); q1 += __shfl_xor(q1, m); }
                if (lane == 0 && curg >= 0) {
                    atomicAdd(&outacc[curg * 2 + 0], q0);
                    atomicAdd(&outacc[curg * 2 + 1], q1);
                    atomicAdd(&cnt[curg], pc);
                }
                p0 = 0.f; p1 = 0.f; pc = 0.f; curg = g;
            }
            p0 += val * wo0;
            p1 += val * wo1;
            pc += 1.0f;
        }
    }
    {
        float q0 = p0, q1 = p1;
#pragma unroll
        for (int m = 1; m < 64; m <<= 1) { q0 += __shfl_xor(q0, m); q1 += __shfl_xor(q1, m); }
        if (lane == 0 && curg >= 0) {
            atomicAdd(&outacc[curg * 2 + 0], q0);
            atomicAdd(&outacc[curg * 2 + 1], q1);
            atomicAdd(&cnt[curg], pc);
        }
    }
}

__global__ void k_out(const float* __restrict__ outacc, const float* __restrict__ cnt,
                      const float* __restrict__ bout, float* __restrict__ out, int n_graphs) {
    int i = blockIdx.x * 256 + threadIdx.x;
    if (i < n_graphs * 2) {
        int g = i >> 1, c = i & 1;
        out[i] = outacc[i] / fmaxf(cnt[g], 1.0f) + bout[c];
    }
}

extern "C" void kernel_launch(void* const* d_in, const int* in_sizes, int n_in,
                              void* d_out, int out_size, void* d_ws, size_t ws_size,
                              hipStream_t stream) {
    const int* x     = (const int*)d_in[0];
    const int* ei    = (const int*)d_in[1];
    const int* batch = (const int*)d_in[2];
    const float* se   = (const float*)d_in[4];
    const float* ce   = (const float*)d_in[5];
    const float* Win  = (const float*)d_in[6];
    const float* bin  = (const float*)d_in[7];
    const float* W1l  = (const float*)d_in[8];
    const float* b1   = (const float*)d_in[9];
    const float* W1r  = (const float*)d_in[10];
    const float* W2l  = (const float*)d_in[11];
    const float* b2   = (const float*)d_in[12];
    const float* W2r  = (const float*)d_in[13];
    const float* Wout = (const float*)d_in[14];
    const float* bout = (const float*)d_in[15];
    float* out = (float*)d_out;

    int n_nodes  = in_sizes[0] / 2;
    int n_edges  = in_sizes[1] / 2;
    int n_graphs = out_size / 2;
    const int* src = ei;
    const int* dst = ei + n_edges;
    int nb = (n_nodes + 255) >> 8;               // buckets (<= 512 for n<131072)

    char* p = (char*)d_ws;
    auto take = [&](size_t bytes) { char* r = p; p += (bytes + 255) & ~(size_t)255; return r; };
    float*    h1     = (float*)take((size_t)n_nodes * 64 * 4);
    unsigned* g1p    = (unsigned*)take((size_t)n_nodes * 32 * 4);
    float*    r1     = (float*)take((size_t)n_nodes * 64 * 4);
    int*      csrp   = (int*)take((size_t)n_edges * 4);
    int*      bedge  = (int*)take((size_t)n_edges * 4);
    int*      ntype  = (int*)take((size_t)n_nodes * 4);
    int*      deg_i  = (int*)take((size_t)n_nodes * 4);
    int*      off    = (int*)take((size_t)n_nodes * 4);
    float*    inv    = (float*)take((size_t)n_nodes * 4);
    int*      histT  = (int*)take((size_t)512 * NBLK * 4);
    int*      blkOff = (int*)take((size_t)512 * NBLK * 4);
    int*      btot   = (int*)take(512 * 4);
    int*      bbase  = (int*)take(512 * 4);
    float*    cnt    = (float*)take((size_t)n_graphs * 4);
    float*    outacc = (float*)take((size_t)n_graphs * 8);
    float*    h0tab  = (float*)take(4096 * 4);
    float*    hltab  = (float*)take(4096 * 4);
    float*    hrtab  = (float*)take(4096 * 4);

    int nbN = (n_nodes + 255) / 256;

    hipMemsetAsync(cnt, 0, (size_t)n_graphs * 4, stream);
    hipMemsetAsync(outacc, 0, (size_t)n_graphs * 8, stream);

    k_tab0<<<64, 64, 0, stream>>>(se, ce, Win, bin, h0tab);
    k_tab1<<<64, 64, 0, stream>>>(h0tab, W1l, W1r, b1, hltab, hrtab);
    k_prep<<<nbN, 256, 0, stream>>>(x, ntype, n_nodes);
    k_hist<<<NBLK, 256, 0, stream>>>(dst, histT, n_edges, nb);
    k_bscan<<<nb, 512, 0, stream>>>(histT, blkOff, btot);
    k_bscan2<<<1, 512, 0, stream>>>(btot, bbase, nb);
    k_scatter<<<NBLK, 256, 0, stream>>>(src, dst, ntype, bbase, blkOff, bedge, n_edges, nb);
    k_bsort<<<nb, 256, 0, stream>>>(bedge, bbase, btot, csrp, deg_i, off, inv, n_nodes);
    k_gather1<<<2048, 256, 0, stream>>>(csrp, off, deg_i, inv, ntype, hltab, hrtab, h1, n_nodes);
    k_lin2<<<768, 256, 0, stream>>>(h1, W2l, W2r, b2, g1p, r1, n_nodes);
    k_gather2<<<2048, 256, 0, stream>>>(csrp, off, deg_i, inv, g1p, r1, batch, Wout,
                                        outacc, cnt, n_nodes);
    k_out<<<(n_graphs * 2 + 255) / 256, 256, 0, stream>>>(outacc, cnt, bout, out, n_graphs);
}

// Round 9
// 162.159 us; speedup vs baseline: 6.4204x; 1.0385x over previous
//
#include <hip/hip_runtime.h>
#include <hip/hip_bf16.h>

// ---------------------------------------------------------------------------
// GNN classifier on MI355X.
//   h0 = relu([shape_emb[x0]|color_emb[x1]] @ W_in + b_in)   -> 64-entry table
//   conv1: h1 = relu( seg_sum(hltab[type[src]],dst)/deg + hrtab[type] )
//          hltab = h0tab@W1l, hrtab = h0tab@W1r + b1          (linearity)
//   conv2 by linearity:  g1 = h1@W2l, r1 = h1@W2r + b2  (dense GEMM)
//          h2 = relu( seg_sum(g1[src],dst)/deg + r1 )
//   out   = seg_sum(h2@W_out, batch)/cnt + b_out   (fused into the gather)
//
// R2: full unroll in k_lin2 spilled (256 VGPR, 1.9 GB scratch). Keep unroll 2.
// R3: batch is SORTED -> run-deferred pooling flush, no per-node atomics.
// R4: atomicAdd-with-return stalls every lane ~400cy.
// R5: wave-uniform broadcast loads -> coalesced 64-edge loads + __shfl.
// R6: gather2 fetch-bound -> g1 packed bf16 (128B rows).
// R7: 1.2M device-scope atomics = memory-side RMW wall -> bucketed LDS sort.
// R8: gather2 now latency*concurrency-bound (same requests, half bytes, BW
//     fell to 1.7TB/s). Fix: 32 lanes per g1 row (lane owns a feature PAIR),
//     2 edges per load instruction, ILP-4 on pairs -> 8 edges in flight per
//     wave (2x MLP), ~35% less VALU per edge. Halves merged via shfl_xor(32).
// ---------------------------------------------------------------------------

#define NBLK 512   // blocks used by k_hist / k_scatter (chunked edge partition)

__device__ __forceinline__ unsigned bf16rn(float x) {
    unsigned b = __float_as_uint(x);
    return (b + 0x7FFFu + ((b >> 16) & 1u)) >> 16;       // round-to-nearest-even
}
__device__ __forceinline__ unsigned bf16pack2(float lo, float hi) {
    return bf16rn(lo) | (bf16rn(hi) << 16);
}

__global__ void k_tab0(const float* __restrict__ se, const float* __restrict__ ce,
                       const float* __restrict__ Win, const float* __restrict__ bin,
                       float* __restrict__ h0tab) {
    int t = blockIdx.x, j = threadIdx.x;        // 64 blocks x 64 threads
    int s = t >> 3, c = t & 7;
    float acc = bin[j];
    for (int k = 0; k < 64; ++k) {
        acc += se[s * 64 + k] * Win[k * 64 + j];
        acc += ce[c * 64 + k] * Win[(64 + k) * 64 + j];
    }
    h0tab[t * 64 + j] = fmaxf(acc, 0.f);
}

__global__ void k_tab1(const float* __restrict__ h0tab, const float* __restrict__ W1l,
                       const float* __restrict__ W1r, const float* __restrict__ b1,
                       float* __restrict__ hltab, float* __restrict__ hrtab) {
    int t = blockIdx.x, j = threadIdx.x;        // 64 blocks x 64 threads
    float al = 0.f, ar = b1[j];
    for (int k = 0; k < 64; ++k) {
        float h = h0tab[t * 64 + k];
        al += h * W1l[k * 64 + j];
        ar += h * W1r[k * 64 + j];
    }
    hltab[t * 64 + j] = al;
    hrtab[t * 64 + j] = ar;
}

// ntype only; NO atomics (R3 lesson).
__global__ void k_prep(const int* __restrict__ x, int* __restrict__ ntype, int n_nodes) {
    int n = blockIdx.x * 256 + threadIdx.x;
    if (n < n_nodes) {
        int2 v = *(const int2*)(x + 2 * (size_t)n);
        ntype[n] = v.x * 8 + v.y;
    }
}

// zero the tiny accumulators (replaces 2 hipMemsetAsync fills, R8).
__global__ void k_zero(float* __restrict__ cnt, float* __restrict__ outacc, int n_graphs) {
    int i = blockIdx.x * 256 + threadIdx.x;
    if (i < n_graphs) cnt[i] = 0.f;
    if (i < 2 * n_graphs) outacc[i] = 0.f;
}

// ---- bucketed CSR build (R7): LDS atomics only ----------------------------

__global__ __launch_bounds__(256) void k_hist(const int* __restrict__ dst,
                                              int* __restrict__ histT,
                                              int n_edges, int nb) {
    __shared__ int h[512];
    int tid = threadIdx.x, blk = blockIdx.x;
    for (int i = tid; i < nb; i += 256) h[i] = 0;
    __syncthreads();
    int per = (n_edges + NBLK - 1) / NBLK;
    int e0 = blk * per;
    int e1 = e0 + per; if (e1 > n_edges) e1 = n_edges;
    for (int e = e0 + tid; e < e1; e += 256)
        atomicAdd(&h[dst[e] >> 8], 1);
    __syncthreads();
    for (int i = tid; i < nb; i += 256)
        histT[(size_t)i * NBLK + blk] = h[i];      // row b: counts per block
}

__global__ void k_bscan(const int* __restrict__ histT, int* __restrict__ blockOff,
                        int* __restrict__ btot) {
    __shared__ int sbuf[2][512];
    int b = blockIdx.x, tid = threadIdx.x;
    int d = histT[(size_t)b * NBLK + tid];
    int cur = 0;
    sbuf[0][tid] = d;
    __syncthreads();
    for (int ofs = 1; ofs < 512; ofs <<= 1) {
        int v = sbuf[cur][tid];
        if (tid >= ofs) v += sbuf[cur][tid - ofs];
        sbuf[cur ^ 1][tid] = v;
        cur ^= 1;
        __syncthreads();
    }
    blockOff[(size_t)b * NBLK + tid] = sbuf[cur][tid] - d;
    if (tid == 511) btot[b] = sbuf[cur][tid];
}

__global__ void k_bscan2(const int* __restrict__ btot, int* __restrict__ bbase, int nb) {
    __shared__ int sbuf[2][512];
    int tid = threadIdx.x;
    int d = (tid < nb) ? btot[tid] : 0;
    int cur = 0;
    sbuf[0][tid] = d;
    __syncthreads();
    for (int ofs = 1; ofs < 512; ofs <<= 1) {
        int v = sbuf[cur][tid];
        if (tid >= ofs) v += sbuf[cur][tid - ofs];
        sbuf[cur ^ 1][tid] = v;
        cur ^= 1;
        __syncthreads();
    }
    if (tid < nb) bbase[tid] = sbuf[cur][tid] - d;
}

// scatter edges into bucket-grouped order. Packed: src | type<<17 | dstLow<<23.
__global__ __launch_bounds__(256) void k_scatter(
    const int* __restrict__ src, const int* __restrict__ dst,
    const int* __restrict__ ntype, const int* __restrict__ bbase,
    const int* __restrict__ blockOff, int* __restrict__ bedge,
    int n_edges, int nb) {
    __shared__ int cur[512];
    int tid = threadIdx.x, blk = blockIdx.x;
    for (int i = tid; i < nb; i += 256)
        cur[i] = bbase[i] + blockOff[(size_t)i * NBLK + blk];
    __syncthreads();
    int per = (n_edges + NBLK - 1) / NBLK;
    int e0 = blk * per;
    int e1 = e0 + per; if (e1 > n_edges) e1 = n_edges;
    for (int e = e0 + tid; e < e1; e += 256) {
        int d = dst[e], s = src[e];
        int pos = atomicAdd(&cur[d >> 8], 1);       // LDS atomic (fast)
        bedge[pos] = s | (ntype[s] << 17) | ((d & 255) << 23);
    }
}

// per-bucket 256-way counting sort in LDS; emits deg/off/inv + final csrp.
__global__ __launch_bounds__(256) void k_bsort(
    const int* __restrict__ bedge, const int* __restrict__ bbase,
    const int* __restrict__ btot, int* __restrict__ csrp,
    int* __restrict__ deg, int* __restrict__ off, float* __restrict__ inv,
    int n_nodes) {
    __shared__ int cnt[256];
    __shared__ int sbuf[2][256];
    __shared__ int loff[256];
    int b = blockIdx.x, tid = threadIdx.x;
    int base = bbase[b], tot = btot[b];
    cnt[tid] = 0;
    __syncthreads();
    for (int i = tid; i < tot; i += 256)
        atomicAdd(&cnt[(bedge[base + i] >> 23) & 255], 1);
    __syncthreads();
    int d = cnt[tid];
    int cur = 0;
    sbuf[0][tid] = d;
    __syncthreads();
    for (int ofs = 1; ofs < 256; ofs <<= 1) {
        int v = sbuf[cur][tid];
        if (tid >= ofs) v += sbuf[cur][tid - ofs];
        sbuf[cur ^ 1][tid] = v;
        cur ^= 1;
        __syncthreads();
    }
    loff[tid] = sbuf[cur][tid] - d;                  // exclusive within bucket
    __syncthreads();
    int n = b * 256 + tid;
    if (n < n_nodes) {
        deg[n] = d;
        off[n] = base + loff[tid];
        inv[n] = 1.0f / fmaxf((float)d, 1.0f);
    }
    cnt[tid] = loff[tid];                            // reuse as cursor
    __syncthreads();
    for (int i = tid; i < tot; i += 256) {
        int v = bedge[base + i];
        int pos = atomicAdd(&cnt[(v >> 23) & 255], 1);
        csrp[base + pos] = (v & 0x1FFFF) | (((v >> 17) & 63) << 20);
    }
}

// ---- compute kernels --------------------------------------------------------

__global__ __launch_bounds__(256) void k_gather1(
    const int* __restrict__ csrp, const int* __restrict__ off,
    const int* __restrict__ deg_i, const float* __restrict__ inv,
    const int* __restrict__ ntype, const float* __restrict__ hltab,
    const float* __restrict__ hrtab, float* __restrict__ h1, int n_nodes) {
    __shared__ float tl[4096];
    __shared__ float tr_[4096];
    for (int i = threadIdx.x; i < 4096; i += 256) { tl[i] = hltab[i]; tr_[i] = hrtab[i]; }
    __syncthreads();
    int lane = threadIdx.x & 63;
    int w = blockIdx.x * 4 + (threadIdx.x >> 6);
    int nw = gridDim.x * 4;
    int per = (n_nodes + nw - 1) / nw;
    int n0 = w * per;
    int n1 = n0 + per; if (n1 > n_nodes) n1 = n_nodes;
    for (int cb = n0; cb < n1; cb += 64) {
        int cn = n1 - cb; if (cn > 64) cn = 64;
        int voff = 0, vdeg = 0, vnt = 0; float vinv = 0.f;
        if (lane < cn) {
            voff = off[cb + lane]; vdeg = deg_i[cb + lane];
            vinv = inv[cb + lane]; vnt  = ntype[cb + lane];
        }
        for (int j = 0; j < cn; ++j) {
            int o = __shfl(voff, j), d = __shfl(vdeg, j);
            float iv = __shfl(vinv, j);
            int tn = __shfl(vnt, j);
            float acc = 0.f;
            for (int base = 0; base < d; base += 64) {
                int rem = d - base; if (rem > 64) rem = 64;
                int v = (lane < rem) ? csrp[o + base + lane] : 0;
                int full = rem & ~3;
                for (int k = 0; k < full; k += 4) {
                    int t0 = __shfl(v, k)     >> 20;
                    int t1 = __shfl(v, k + 1) >> 20;
                    int t2 = __shfl(v, k + 2) >> 20;
                    int t3 = __shfl(v, k + 3) >> 20;
                    acc += (tl[t0 * 64 + lane] + tl[t1 * 64 + lane]) +
                           (tl[t2 * 64 + lane] + tl[t3 * 64 + lane]);
                }
                for (int k = full; k < rem; ++k)
                    acc += tl[(__shfl(v, k) >> 20) * 64 + lane];
            }
            h1[(size_t)(cb + j) * 64 + lane] = fmaxf(acc * iv + tr_[tn * 64 + lane], 0.f);
        }
    }
}

#define SH_LD 68   // 64 + 4 pad: keeps float4 alignment, 2-way (free) bank aliasing
__global__ __launch_bounds__(256) void k_lin2(
    const float* __restrict__ h1, const float* __restrict__ W2l,
    const float* __restrict__ W2r, const float* __restrict__ b2,
    unsigned* __restrict__ g1p, float* __restrict__ r1, int n_nodes) {
    __shared__ float sWl[4096];
    __shared__ float sWr[4096];
    __shared__ float sb2[64];
    __shared__ float sh[64 * SH_LD];
    int tid = threadIdx.x;
    for (int i = tid; i < 4096; i += 256) { sWl[i] = W2l[i]; sWr[i] = W2r[i]; }
    if (tid < 64) sb2[tid] = b2[tid];

    int ntile = (n_nodes + 63) >> 6;
    int tr = tid >> 4, tc = tid & 15;
    int r0 = tr * 4, c0 = tc * 4;

    for (int t = blockIdx.x; t < ntile; t += gridDim.x) {
        int n0 = t << 6;
        __syncthreads();
        {
            int lim = (n_nodes - n0) * 16;
            const float4* s4 = (const float4*)(h1 + (size_t)n0 * 64);
            for (int i = tid; i < 1024; i += 256) {
                int row = i >> 4, col = i & 15;
                float4 v = (i < lim) ? s4[i] : make_float4(0.f, 0.f, 0.f, 0.f);
                *(float4*)(sh + row * SH_LD + col * 4) = v;
            }
        }
        __syncthreads();

        float accl[4][4] = {{0.f}}, accr[4][4] = {{0.f}};
#pragma unroll 2            // R2: full unroll spilled (256 VGPR, 1.9GB scratch)
        for (int k = 0; k < 64; k += 4) {
            float4 hv[4];
#pragma unroll
            for (int i = 0; i < 4; ++i)
                hv[i] = *(const float4*)(sh + (r0 + i) * SH_LD + k);
#pragma unroll
            for (int kk = 0; kk < 4; ++kk) {
                float4 wl = *(const float4*)(sWl + (k + kk) * 64 + c0);
                float4 wr = *(const float4*)(sWr + (k + kk) * 64 + c0);
#pragma unroll
                for (int i = 0; i < 4; ++i) {
                    float h = (&hv[i].x)[kk];
                    accl[i][0] += h * wl.x; accr[i][0] += h * wr.x;
                    accl[i][1] += h * wl.y; accr[i][1] += h * wr.y;
                    accl[i][2] += h * wl.z; accr[i][2] += h * wr.z;
                    accl[i][3] += h * wl.w; accr[i][3] += h * wr.w;
                }
            }
        }
#pragma unroll
        for (int i = 0; i < 4; ++i) {
            int n = n0 + r0 + i;
            if (n < n_nodes) {
                uint2 gl;
                gl.x = bf16pack2(accl[i][0], accl[i][1]);
                gl.y = bf16pack2(accl[i][2], accl[i][3]);
                float4 rr = make_float4(accr[i][0] + sb2[c0 + 0], accr[i][1] + sb2[c0 + 1],
                                        accr[i][2] + sb2[c0 + 2], accr[i][3] + sb2[c0 + 3]);
                *(uint2*)(g1p + (size_t)n * 32 + (c0 >> 1)) = gl;
                *(float4*)(r1 + (size_t)n * 64 + c0) = rr;
            }
        }
    }
}

// conv2 aggregation + relu + W_out + pooling. R8: lane owns a feature PAIR
// (one uint of the 32-uint g1 row); lanes 0-31 take even edges, 32-63 odd.
// One load instruction covers 2 edges; ILP-4 -> 8 edges in flight per wave.
__global__ __launch_bounds__(256) void k_gather2(
    const int* __restrict__ csrp, const int* __restrict__ off,
    const int* __restrict__ deg_i, const float* __restrict__ inv,
    const unsigned* __restrict__ g1p, const float* __restrict__ r1,
    const int* __restrict__ batch, const float* __restrict__ Wout,
    float* __restrict__ outacc, float* __restrict__ cnt, int n_nodes) {
    int lane = threadIdx.x & 63;
    int li = lane & 31;                       // feature-pair index (uint in row)
    int hi = lane >> 5;                       // 0: even edges, 1: odd edges
    float hm = hi ? 0.f : 1.f;                // mask so halves don't double-count
    int w = blockIdx.x * 4 + (threadIdx.x >> 6);
    int nw = gridDim.x * 4;
    int per = (n_nodes + nw - 1) / nw;
    int n0 = w * per;
    int n1 = n0 + per; if (n1 > n_nodes) n1 = n_nodes;
    float4 wo = *(const float4*)(Wout + li * 4);   // W[2li][0..1], W[2li+1][0..1]
    float p0 = 0.f, p1 = 0.f, pc = 0.f;
    int curg = -1;
    for (int cb = n0; cb < n1; cb += 64) {
        int cn = n1 - cb; if (cn > 64) cn = 64;
        int voff = 0, vdeg = 0, vbat = 0; float vinv = 0.f;
        if (lane < cn) {
            voff = off[cb + lane]; vdeg = deg_i[cb + lane];
            vinv = inv[cb + lane]; vbat = batch[cb + lane];
        }
        for (int j = 0; j < cn; ++j) {
            int o = __shfl(voff, j), d = __shfl(vdeg, j), g = __shfl(vbat, j);
            float iv = __shfl(vinv, j);
            float accL = 0.f, accH = 0.f;     // features 2li, 2li+1
            for (int base = 0; base < d; base += 64) {
                int rem = d - base; if (rem > 64) rem = 64;
                int v = (lane < rem) ? csrp[o + base + lane] : 0;
                int k = 0;
                int full8 = rem & ~7;
                for (; k < full8; k += 8) {   // 4 pairs = 8 edges, 4 loads in flight
                    int a0 = __shfl(v, k),     a1 = __shfl(v, k + 1);
                    int a2 = __shfl(v, k + 2), a3 = __shfl(v, k + 3);
                    int a4 = __shfl(v, k + 4), a5 = __shfl(v, k + 5);
                    int a6 = __shfl(v, k + 6), a7 = __shfl(v, k + 7);
                    size_t s0 = (size_t)((hi ? a1 : a0) & 0xFFFFF);
                    size_t s1 = (size_t)((hi ? a3 : a2) & 0xFFFFF);
                    size_t s2 = (size_t)((hi ? a5 : a4) & 0xFFFFF);
                    size_t s3 = (size_t)((hi ? a7 : a6) & 0xFFFFF);
                    unsigned u0 = g1p[s0 * 32 + li];
                    unsigned u1 = g1p[s1 * 32 + li];
                    unsigned u2 = g1p[s2 * 32 + li];
                    unsigned u3 = g1p[s3 * 32 + li];
                    accL += (__uint_as_float(u0 << 16) + __uint_as_float(u1 << 16)) +
                            (__uint_as_float(u2 << 16) + __uint_as_float(u3 << 16));
                    accH += (__uint_as_float(u0 & 0xFFFF0000u) + __uint_as_float(u1 & 0xFFFF0000u)) +
                            (__uint_as_float(u2 & 0xFFFF0000u) + __uint_as_float(u3 & 0xFFFF0000u));
                }
                for (; k + 1 < rem; k += 2) { // single pair
                    int a0 = __shfl(v, k), a1 = __shfl(v, k + 1);
                    size_t s = (size_t)((hi ? a1 : a0) & 0xFFFFF);
                    unsigned u = g1p[s * 32 + li];
                    accL += __uint_as_float(u << 16);
                    accH += __uint_as_float(u & 0xFFFF0000u);
                }
                if (k < rem) {                // odd tail: only hi==0 half counts
                    size_t s = (size_t)(__shfl(v, k) & 0xFFFFF);
                    unsigned u = g1p[s * 32 + li];
                    accL += hm * __uint_as_float(u << 16);
                    accH += hm * __uint_as_float(u & 0xFFFF0000u);
                }
            }
            accL += __shfl_xor(accL, 32);     // merge even/odd halves
            accH += __shfl_xor(accH, 32);
            float2 rv = *(const float2*)(r1 + (size_t)(cb + j) * 64 + 2 * li);
            float v0 = fmaxf(accL * iv + rv.x, 0.f);
            float v1 = fmaxf(accH * iv + rv.y, 0.f);
            if (g != curg) {                  // wave-uniform branch
                float q0 = p0, q1 = p1;
#pragma unroll
                for (int m = 1; m < 64; m <<= 1) { q0 += __shfl_xor(q0, m); q1 += __shfl_xor(q1, m); }
                if (lane == 0 && curg >= 0) {
                    atomicAdd(&outacc[curg * 2 + 0], q0);
                    atomicAdd(&outacc[curg * 2 + 1], q1);
                    atomicAdd(&cnt[curg], pc);
                }
                p0 = 0.f; p1 = 0.f; pc = 0.f; curg = g;
            }
            p0 += hm * (v0 * wo.x + v1 * wo.z);
            p1 += hm * (v0 * wo.y + v1 * wo.w);
            pc += 1.0f;
        }
    }
    {
        float q0 = p0, q1 = p1;
#pragma unroll
        for (int m = 1; m < 64; m <<= 1) { q0 += __shfl_xor(q0, m); q1 += __shfl_xor(q1, m); }
        if (lane == 0 && curg >= 0) {
            atomicAdd(&outacc[curg * 2 + 0], q0);
            atomicAdd(&outacc[curg * 2 + 1], q1);
            atomicAdd(&cnt[curg], pc);
        }
    }
}

__global__ void k_out(const float* __restrict__ outacc, const float* __restrict__ cnt,
                      const float* __restrict__ bout, float* __restrict__ out, int n_graphs) {
    int i = blockIdx.x * 256 + threadIdx.x;
    if (i < n_graphs * 2) {
        int g = i >> 1, c = i & 1;
        out[i] = outacc[i] / fmaxf(cnt[g], 1.0f) + bout[c];
    }
}

extern "C" void kernel_launch(void* const* d_in, const int* in_sizes, int n_in,
                              void* d_out, int out_size, void* d_ws, size_t ws_size,
                              hipStream_t stream) {
    const int* x     = (const int*)d_in[0];
    const int* ei    = (const int*)d_in[1];
    const int* batch = (const int*)d_in[2];
    const float* se   = (const float*)d_in[4];
    const float* ce   = (const float*)d_in[5];
    const float* Win  = (const float*)d_in[6];
    const float* bin  = (const float*)d_in[7];
    const float* W1l  = (const float*)d_in[8];
    const float* b1   = (const float*)d_in[9];
    const float* W1r  = (const float*)d_in[10];
    const float* W2l  = (const float*)d_in[11];
    const float* b2   = (const float*)d_in[12];
    const float* W2r  = (const float*)d_in[13];
    const float* Wout = (const float*)d_in[14];
    const float* bout = (const float*)d_in[15];
    float* out = (float*)d_out;

    int n_nodes  = in_sizes[0] / 2;
    int n_edges  = in_sizes[1] / 2;
    int n_graphs = out_size / 2;
    const int* src = ei;
    const int* dst = ei + n_edges;
    int nb = (n_nodes + 255) >> 8;               // buckets (<= 512 for n<131072)

    char* p = (char*)d_ws;
    auto take = [&](size_t bytes) { char* r = p; p += (bytes + 255) & ~(size_t)255; return r; };
    float*    h1     = (float*)take((size_t)n_nodes * 64 * 4);
    unsigned* g1p    = (unsigned*)take((size_t)n_nodes * 32 * 4);
    float*    r1     = (float*)take((size_t)n_nodes * 64 * 4);
    int*      csrp   = (int*)take((size_t)n_edges * 4);
    int*      bedge  = (int*)take((size_t)n_edges * 4);
    int*      ntype  = (int*)take((size_t)n_nodes * 4);
    int*      deg_i  = (int*)take((size_t)n_nodes * 4);
    int*      off    = (int*)take((size_t)n_nodes * 4);
    float*    inv    = (float*)take((size_t)n_nodes * 4);
    int*      histT  = (int*)take((size_t)512 * NBLK * 4);
    int*      blkOff = (int*)take((size_t)512 * NBLK * 4);
    int*      btot   = (int*)take(512 * 4);
    int*      bbase  = (int*)take(512 * 4);
    float*    cnt    = (float*)take((size_t)n_graphs * 4);
    float*    outacc = (float*)take((size_t)n_graphs * 8);
    float*    h0tab  = (float*)take(4096 * 4);
    float*    hltab  = (float*)take(4096 * 4);
    float*    hrtab  = (float*)take(4096 * 4);

    int nbN = (n_nodes + 255) / 256;

    k_zero<<<(2 * n_graphs + 255) / 256, 256, 0, stream>>>(cnt, outacc, n_graphs);
    k_tab0<<<64, 64, 0, stream>>>(se, ce, Win, bin, h0tab);
    k_tab1<<<64, 64, 0, stream>>>(h0tab, W1l, W1r, b1, hltab, hrtab);
    k_prep<<<nbN, 256, 0, stream>>>(x, ntype, n_nodes);
    k_hist<<<NBLK, 256, 0, stream>>>(dst, histT, n_edges, nb);
    k_bscan<<<nb, 512, 0, stream>>>(histT, blkOff, btot);
    k_bscan2<<<1, 512, 0, stream>>>(btot, bbase, nb);
    k_scatter<<<NBLK, 256, 0, stream>>>(src, dst, ntype, bbase, blkOff, bedge, n_edges, nb);
    k_bsort<<<nb, 256, 0, stream>>>(bedge, bbase, btot, csrp, deg_i, off, inv, n_nodes);
    k_gather1<<<2048, 256, 0, stream>>>(csrp, off, deg_i, inv, ntype, hltab, hrtab, h1, n_nodes);
    k_lin2<<<768, 256, 0, stream>>>(h1, W2l, W2r, b2, g1p, r1, n_nodes);
    k_gather2<<<2048, 256, 0, stream>>>(csrp, off, deg_i, inv, g1p, r1, batch, Wout,
                                        outacc, cnt, n_nodes);
    k_out<<<(n_graphs * 2 + 255) / 256, 256, 0, stream>>>(outacc, cnt, bout, out, n_graphs);
}

// Round 10
// 155.974 us; speedup vs baseline: 6.6750x; 1.0397x over previous
//
#include <hip/hip_runtime.h>
#include <hip/hip_bf16.h>

// ---------------------------------------------------------------------------
// GNN classifier on MI355X.
//   h0 = relu([shape_emb[x0]|color_emb[x1]] @ W_in + b_in)   -> 64-entry table
//   conv1: h1 = relu( seg_sum(hltab[type[src]],dst)/deg + hrtab[type] )
//          hltab = h0tab@W1l, hrtab = h0tab@W1r + b1          (linearity)
//   conv2 by linearity:  g1 = h1@W2l, r1 = h1@W2r + b2  (dense GEMM)
//          h2 = relu( seg_sum(g1[src],dst)/deg + r1 )
//   out   = seg_sum(h2@W_out, batch)/cnt + b_out   (fused into the gather)
//
// R2: full unroll in k_lin2 spilled (256 VGPR, 1.9 GB scratch). Keep unroll 2.
// R3: batch is SORTED -> run-deferred pooling flush, no per-node atomics.
// R4: atomicAdd-with-return stalls every lane ~400cy.
// R5: wave-uniform broadcast loads -> coalesced 64-edge loads + __shfl.
// R6: gather2 fetch-bound -> g1 packed bf16 (128B rows).
// R7: 1.2M device-scope atomics = memory-side RMW wall -> bucketed LDS sort.
// R8: gather2 latency*concurrency-bound -> feature-pair lanes, 2 edges/load.
// R9: intermediate tensors h1 and r1 also packed bf16 (saves ~51MB of
//     streamed traffic across gather1/lin2/gather2; error budget ~8e-6 vs
//     2e-5 threshold); tab0+tab1 fused (tab1 row t needs only h0 row t);
//     k_zero folded into k_prep. 13 -> 11 dispatches.
// ---------------------------------------------------------------------------

#define NBLK 512   // blocks used by k_hist / k_scatter (chunked edge partition)

__device__ __forceinline__ unsigned bf16rn(float x) {
    unsigned b = __float_as_uint(x);
    return (b + 0x7FFFu + ((b >> 16) & 1u)) >> 16;       // round-to-nearest-even
}
__device__ __forceinline__ unsigned bf16pack2(float lo, float hi) {
    return bf16rn(lo) | (bf16rn(hi) << 16);
}

// fused input-MLP + conv1 table build (R9): block t computes h0 row t in LDS,
// then hl/hr rows t from it. 64 blocks x 64 threads.
__global__ void k_tabs(const float* __restrict__ se, const float* __restrict__ ce,
                       const float* __restrict__ Win, const float* __restrict__ bin,
                       const float* __restrict__ W1l, const float* __restrict__ W1r,
                       const float* __restrict__ b1,
                       float* __restrict__ hltab, float* __restrict__ hrtab) {
    __shared__ float sse[64], sce[64], sh0[64];
    int t = blockIdx.x, j = threadIdx.x;
    int s = t >> 3, c = t & 7;
    sse[j] = se[s * 64 + j];
    sce[j] = ce[c * 64 + j];
    __syncthreads();
    float acc = bin[j];
    for (int k = 0; k < 64; ++k) {
        acc += sse[k] * Win[k * 64 + j];
        acc += sce[k] * Win[(64 + k) * 64 + j];
    }
    sh0[j] = fmaxf(acc, 0.f);
    __syncthreads();
    float al = 0.f, ar = b1[j];
    for (int k = 0; k < 64; ++k) {
        float h = sh0[k];
        al += h * W1l[k * 64 + j];
        ar += h * W1r[k * 64 + j];
    }
    hltab[t * 64 + j] = al;
    hrtab[t * 64 + j] = ar;
}

// ntype + zero-init of the tiny accumulators (R9 fusion). NO atomics.
__global__ void k_prep(const int* __restrict__ x, int* __restrict__ ntype,
                       float* __restrict__ cnt, float* __restrict__ outacc,
                       int n_nodes, int n_graphs) {
    int n = blockIdx.x * 256 + threadIdx.x;
    if (n < n_nodes) {
        int2 v = *(const int2*)(x + 2 * (size_t)n);
        ntype[n] = v.x * 8 + v.y;
    }
    if (n < n_graphs) cnt[n] = 0.f;
    if (n < 2 * n_graphs) outacc[n] = 0.f;
}

// ---- bucketed CSR build (R7): LDS atomics only ----------------------------

__global__ __launch_bounds__(256) void k_hist(const int* __restrict__ dst,
                                              int* __restrict__ histT,
                                              int n_edges, int nb) {
    __shared__ int h[512];
    int tid = threadIdx.x, blk = blockIdx.x;
    for (int i = tid; i < nb; i += 256) h[i] = 0;
    __syncthreads();
    int per = (n_edges + NBLK - 1) / NBLK;
    int e0 = blk * per;
    int e1 = e0 + per; if (e1 > n_edges) e1 = n_edges;
    for (int e = e0 + tid; e < e1; e += 256)
        atomicAdd(&h[dst[e] >> 8], 1);
    __syncthreads();
    for (int i = tid; i < nb; i += 256)
        histT[(size_t)i * NBLK + blk] = h[i];      // row b: counts per block
}

__global__ void k_bscan(const int* __restrict__ histT, int* __restrict__ blockOff,
                        int* __restrict__ btot) {
    __shared__ int sbuf[2][512];
    int b = blockIdx.x, tid = threadIdx.x;
    int d = histT[(size_t)b * NBLK + tid];
    int cur = 0;
    sbuf[0][tid] = d;
    __syncthreads();
    for (int ofs = 1; ofs < 512; ofs <<= 1) {
        int v = sbuf[cur][tid];
        if (tid >= ofs) v += sbuf[cur][tid - ofs];
        sbuf[cur ^ 1][tid] = v;
        cur ^= 1;
        __syncthreads();
    }
    blockOff[(size_t)b * NBLK + tid] = sbuf[cur][tid] - d;
    if (tid == 511) btot[b] = sbuf[cur][tid];
}

__global__ void k_bscan2(const int* __restrict__ btot, int* __restrict__ bbase, int nb) {
    __shared__ int sbuf[2][512];
    int tid = threadIdx.x;
    int d = (tid < nb) ? btot[tid] : 0;
    int cur = 0;
    sbuf[0][tid] = d;
    __syncthreads();
    for (int ofs = 1; ofs < 512; ofs <<= 1) {
        int v = sbuf[cur][tid];
        if (tid >= ofs) v += sbuf[cur][tid - ofs];
        sbuf[cur ^ 1][tid] = v;
        cur ^= 1;
        __syncthreads();
    }
    if (tid < nb) bbase[tid] = sbuf[cur][tid] - d;
}

// scatter edges into bucket-grouped order. Packed: src | type<<17 | dstLow<<23.
__global__ __launch_bounds__(256) void k_scatter(
    const int* __restrict__ src, const int* __restrict__ dst,
    const int* __restrict__ ntype, const int* __restrict__ bbase,
    const int* __restrict__ blockOff, int* __restrict__ bedge,
    int n_edges, int nb) {
    __shared__ int cur[512];
    int tid = threadIdx.x, blk = blockIdx.x;
    for (int i = tid; i < nb; i += 256)
        cur[i] = bbase[i] + blockOff[(size_t)i * NBLK + blk];
    __syncthreads();
    int per = (n_edges + NBLK - 1) / NBLK;
    int e0 = blk * per;
    int e1 = e0 + per; if (e1 > n_edges) e1 = n_edges;
    for (int e = e0 + tid; e < e1; e += 256) {
        int d = dst[e], s = src[e];
        int pos = atomicAdd(&cur[d >> 8], 1);       // LDS atomic (fast)
        bedge[pos] = s | (ntype[s] << 17) | ((d & 255) << 23);
    }
}

// per-bucket 256-way counting sort in LDS; emits deg/off/inv + final csrp.
__global__ __launch_bounds__(256) void k_bsort(
    const int* __restrict__ bedge, const int* __restrict__ bbase,
    const int* __restrict__ btot, int* __restrict__ csrp,
    int* __restrict__ deg, int* __restrict__ off, float* __restrict__ inv,
    int n_nodes) {
    __shared__ int cnt[256];
    __shared__ int sbuf[2][256];
    __shared__ int loff[256];
    int b = blockIdx.x, tid = threadIdx.x;
    int base = bbase[b], tot = btot[b];
    cnt[tid] = 0;
    __syncthreads();
    for (int i = tid; i < tot; i += 256)
        atomicAdd(&cnt[(bedge[base + i] >> 23) & 255], 1);
    __syncthreads();
    int d = cnt[tid];
    int cur = 0;
    sbuf[0][tid] = d;
    __syncthreads();
    for (int ofs = 1; ofs < 256; ofs <<= 1) {
        int v = sbuf[cur][tid];
        if (tid >= ofs) v += sbuf[cur][tid - ofs];
        sbuf[cur ^ 1][tid] = v;
        cur ^= 1;
        __syncthreads();
    }
    loff[tid] = sbuf[cur][tid] - d;                  // exclusive within bucket
    __syncthreads();
    int n = b * 256 + tid;
    if (n < n_nodes) {
        deg[n] = d;
        off[n] = base + loff[tid];
        inv[n] = 1.0f / fmaxf((float)d, 1.0f);
    }
    cnt[tid] = loff[tid];                            // reuse as cursor
    __syncthreads();
    for (int i = tid; i < tot; i += 256) {
        int v = bedge[base + i];
        int pos = atomicAdd(&cnt[(v >> 23) & 255], 1);
        csrp[base + pos] = (v & 0x1FFFF) | (((v >> 17) & 63) << 20);
    }
}

// ---- compute kernels --------------------------------------------------------

// conv1; h1 written as PACKED BF16 rows (R9).
__global__ __launch_bounds__(256) void k_gather1(
    const int* __restrict__ csrp, const int* __restrict__ off,
    const int* __restrict__ deg_i, const float* __restrict__ inv,
    const int* __restrict__ ntype, const float* __restrict__ hltab,
    const float* __restrict__ hrtab, unsigned* __restrict__ h1p, int n_nodes) {
    __shared__ float tl[4096];
    __shared__ float tr_[4096];
    for (int i = threadIdx.x; i < 4096; i += 256) { tl[i] = hltab[i]; tr_[i] = hrtab[i]; }
    __syncthreads();
    int lane = threadIdx.x & 63;
    int w = blockIdx.x * 4 + (threadIdx.x >> 6);
    int nw = gridDim.x * 4;
    int per = (n_nodes + nw - 1) / nw;
    int n0 = w * per;
    int n1 = n0 + per; if (n1 > n_nodes) n1 = n_nodes;
    for (int cb = n0; cb < n1; cb += 64) {
        int cn = n1 - cb; if (cn > 64) cn = 64;
        int voff = 0, vdeg = 0, vnt = 0; float vinv = 0.f;
        if (lane < cn) {
            voff = off[cb + lane]; vdeg = deg_i[cb + lane];
            vinv = inv[cb + lane]; vnt  = ntype[cb + lane];
        }
        for (int j = 0; j < cn; ++j) {
            int o = __shfl(voff, j), d = __shfl(vdeg, j);
            float iv = __shfl(vinv, j);
            int tn = __shfl(vnt, j);
            float acc = 0.f;
            for (int base = 0; base < d; base += 64) {
                int rem = d - base; if (rem > 64) rem = 64;
                int v = (lane < rem) ? csrp[o + base + lane] : 0;
                int full = rem & ~3;
                for (int k = 0; k < full; k += 4) {
                    int t0 = __shfl(v, k)     >> 20;
                    int t1 = __shfl(v, k + 1) >> 20;
                    int t2 = __shfl(v, k + 2) >> 20;
                    int t3 = __shfl(v, k + 3) >> 20;
                    acc += (tl[t0 * 64 + lane] + tl[t1 * 64 + lane]) +
                           (tl[t2 * 64 + lane] + tl[t3 * 64 + lane]);
                }
                for (int k = full; k < rem; ++k)
                    acc += tl[(__shfl(v, k) >> 20) * 64 + lane];
            }
            float val = fmaxf(acc * iv + tr_[tn * 64 + lane], 0.f);
            float vhi = __shfl_down(val, 1);
            if (!(lane & 1))
                h1p[(size_t)(cb + j) * 32 + (lane >> 1)] = bf16pack2(val, vhi);
        }
    }
}

// dense conv2 GEMMs from bf16 h1 (unpacked into fp32 LDS tile during staging);
// g1 and r1 both written as packed bf16.
#define SH_LD 68   // 64 + 4 pad: keeps float4 alignment, 2-way (free) bank aliasing
__global__ __launch_bounds__(256) void k_lin2(
    const unsigned* __restrict__ h1p, const float* __restrict__ W2l,
    const float* __restrict__ W2r, const float* __restrict__ b2,
    unsigned* __restrict__ g1p, unsigned* __restrict__ r1p, int n_nodes) {
    __shared__ float sWl[4096];
    __shared__ float sWr[4096];
    __shared__ float sb2[64];
    __shared__ float sh[64 * SH_LD];
    int tid = threadIdx.x;
    for (int i = tid; i < 4096; i += 256) { sWl[i] = W2l[i]; sWr[i] = W2r[i]; }
    if (tid < 64) sb2[tid] = b2[tid];

    int ntile = (n_nodes + 63) >> 6;
    int tr = tid >> 4, tc = tid & 15;
    int r0 = tr * 4, c0 = tc * 4;

    for (int t = blockIdx.x; t < ntile; t += gridDim.x) {
        int n0 = t << 6;
        __syncthreads();
        {
            // 64 rows x 32 uints (bf16 pairs) = 512 uint4; unpack to fp32 LDS
            int lim4 = (n_nodes - n0) * 8;           // valid uint4s
            const uint4* s4 = (const uint4*)(h1p + (size_t)n0 * 32);
            for (int i = tid; i < 512; i += 256) {
                uint4 u = (i < lim4) ? s4[i] : make_uint4(0u, 0u, 0u, 0u);
                float* dp = sh + (i >> 3) * SH_LD + (i & 7) * 8;
                dp[0] = __uint_as_float(u.x << 16); dp[1] = __uint_as_float(u.x & 0xFFFF0000u);
                dp[2] = __uint_as_float(u.y << 16); dp[3] = __uint_as_float(u.y & 0xFFFF0000u);
                dp[4] = __uint_as_float(u.z << 16); dp[5] = __uint_as_float(u.z & 0xFFFF0000u);
                dp[6] = __uint_as_float(u.w << 16); dp[7] = __uint_as_float(u.w & 0xFFFF0000u);
            }
        }
        __syncthreads();

        float accl[4][4] = {{0.f}}, accr[4][4] = {{0.f}};
#pragma unroll 2            // R2: full unroll spilled (256 VGPR, 1.9GB scratch)
        for (int k = 0; k < 64; k += 4) {
            float4 hv[4];
#pragma unroll
            for (int i = 0; i < 4; ++i)
                hv[i] = *(const float4*)(sh + (r0 + i) * SH_LD + k);
#pragma unroll
            for (int kk = 0; kk < 4; ++kk) {
                float4 wl = *(const float4*)(sWl + (k + kk) * 64 + c0);
                float4 wr = *(const float4*)(sWr + (k + kk) * 64 + c0);
#pragma unroll
                for (int i = 0; i < 4; ++i) {
                    float h = (&hv[i].x)[kk];
                    accl[i][0] += h * wl.x; accr[i][0] += h * wr.x;
                    accl[i][1] += h * wl.y; accr[i][1] += h * wr.y;
                    accl[i][2] += h * wl.z; accr[i][2] += h * wr.z;
                    accl[i][3] += h * wl.w; accr[i][3] += h * wr.w;
                }
            }
        }
#pragma unroll
        for (int i = 0; i < 4; ++i) {
            int n = n0 + r0 + i;
            if (n < n_nodes) {
                uint2 gl, rp;
                gl.x = bf16pack2(accl[i][0], accl[i][1]);
                gl.y = bf16pack2(accl[i][2], accl[i][3]);
                rp.x = bf16pack2(accr[i][0] + sb2[c0 + 0], accr[i][1] + sb2[c0 + 1]);
                rp.y = bf16pack2(accr[i][2] + sb2[c0 + 2], accr[i][3] + sb2[c0 + 3]);
                *(uint2*)(g1p + (size_t)n * 32 + (c0 >> 1)) = gl;
                *(uint2*)(r1p + (size_t)n * 32 + (c0 >> 1)) = rp;
            }
        }
    }
}

// conv2 aggregation + relu + W_out + pooling. R8 scheme: lane owns a feature
// PAIR; lanes 0-31 even edges, 32-63 odd. r1 now packed bf16 (R9).
__global__ __launch_bounds__(256) void k_gather2(
    const int* __restrict__ csrp, const int* __restrict__ off,
    const int* __restrict__ deg_i, const float* __restrict__ inv,
    const unsigned* __restrict__ g1p, const unsigned* __restrict__ r1p,
    const int* __restrict__ batch, const float* __restrict__ Wout,
    float* __restrict__ outacc, float* __restrict__ cnt, int n_nodes) {
    int lane = threadIdx.x & 63;
    int li = lane & 31;                       // feature-pair index (uint in row)
    int hi = lane >> 5;                       // 0: even edges, 1: odd edges
    float hm = hi ? 0.f : 1.f;                // mask so halves don't double-count
    int w = blockIdx.x * 4 + (threadIdx.x >> 6);
    int nw = gridDim.x * 4;
    int per = (n_nodes + nw - 1) / nw;
    int n0 = w * per;
    int n1 = n0 + per; if (n1 > n_nodes) n1 = n_nodes;
    float4 wo = *(const float4*)(Wout + li * 4);   // W[2li][0..1], W[2li+1][0..1]
    float p0 = 0.f, p1 = 0.f, pc = 0.f;
    int curg = -1;
    for (int cb = n0; cb < n1; cb += 64) {
        int cn = n1 - cb; if (cn > 64) cn = 64;
        int voff = 0, vdeg = 0, vbat = 0; float vinv = 0.f;
        if (lane < cn) {
            voff = off[cb + lane]; vdeg = deg_i[cb + lane];
            vinv = inv[cb + lane]; vbat = batch[cb + lane];
        }
        for (int j = 0; j < cn; ++j) {
            int o = __shfl(voff, j), d = __shfl(vdeg, j), g = __shfl(vbat, j);
            float iv = __shfl(vinv, j);
            float accL = 0.f, accH = 0.f;     // features 2li, 2li+1
            for (int base = 0; base < d; base += 64) {
                int rem = d - base; if (rem > 64) rem = 64;
                int v = (lane < rem) ? csrp[o + base + lane] : 0;
                int k = 0;
                int full8 = rem & ~7;
                for (; k < full8; k += 8) {   // 4 pairs = 8 edges, 4 loads in flight
                    int a0 = __shfl(v, k),     a1 = __shfl(v, k + 1);
                    int a2 = __shfl(v, k + 2), a3 = __shfl(v, k + 3);
                    int a4 = __shfl(v, k + 4), a5 = __shfl(v, k + 5);
                    int a6 = __shfl(v, k + 6), a7 = __shfl(v, k + 7);
                    size_t s0 = (size_t)((hi ? a1 : a0) & 0xFFFFF);
                    size_t s1 = (size_t)((hi ? a3 : a2) & 0xFFFFF);
                    size_t s2 = (size_t)((hi ? a5 : a4) & 0xFFFFF);
                    size_t s3 = (size_t)((hi ? a7 : a6) & 0xFFFFF);
                    unsigned u0 = g1p[s0 * 32 + li];
                    unsigned u1 = g1p[s1 * 32 + li];
                    unsigned u2 = g1p[s2 * 32 + li];
                    unsigned u3 = g1p[s3 * 32 + li];
                    accL += (__uint_as_float(u0 << 16) + __uint_as_float(u1 << 16)) +
                            (__uint_as_float(u2 << 16) + __uint_as_float(u3 << 16));
                    accH += (__uint_as_float(u0 & 0xFFFF0000u) + __uint_as_float(u1 & 0xFFFF0000u)) +
                            (__uint_as_float(u2 & 0xFFFF0000u) + __uint_as_float(u3 & 0xFFFF0000u));
                }
                for (; k + 1 < rem; k += 2) { // single pair
                    int a0 = __shfl(v, k), a1 = __shfl(v, k + 1);
                    size_t s = (size_t)((hi ? a1 : a0) & 0xFFFFF);
                    unsigned u = g1p[s * 32 + li];
                    accL += __uint_as_float(u << 16);
                    accH += __uint_as_float(u & 0xFFFF0000u);
                }
                if (k < rem) {                // odd tail: only hi==0 half counts
                    size_t s = (size_t)(__shfl(v, k) & 0xFFFFF);
                    unsigned u = g1p[s * 32 + li];
                    accL += hm * __uint_as_float(u << 16);
                    accH += hm * __uint_as_float(u & 0xFFFF0000u);
                }
            }
            accL += __shfl_xor(accL, 32);     // merge even/odd halves
            accH += __shfl_xor(accH, 32);
            unsigned ur = r1p[(size_t)(cb + j) * 32 + li];
            float v0 = fmaxf(accL * iv + __uint_as_float(ur << 16), 0.f);
            float v1 = fmaxf(accH * iv + __uint_as_float(ur & 0xFFFF0000u), 0.f);
            if (g != curg) {                  // wave-uniform branch
                float q0 = p0, q1 = p1;
#pragma unroll
                for (int m = 1; m < 64; m <<= 1) { q0 += __shfl_xor(q0, m); q1 += __shfl_xor(q1, m); }
                if (lane == 0 && curg >= 0) {
                    atomicAdd(&outacc[curg * 2 + 0], q0);
                    atomicAdd(&outacc[curg * 2 + 1], q1);
                    atomicAdd(&cnt[curg], pc);
                }
                p0 = 0.f; p1 = 0.f; pc = 0.f; curg = g;
            }
            p0 += hm * (v0 * wo.x + v1 * wo.z);
            p1 += hm * (v0 * wo.y + v1 * wo.w);
            pc += 1.0f;
        }
    }
    {
        float q0 = p0, q1 = p1;
#pragma unroll
        for (int m = 1; m < 64; m <<= 1) { q0 += __shfl_xor(q0, m); q1 += __shfl_xor(q1, m); }
        if (lane == 0 && curg >= 0) {
            atomicAdd(&outacc[curg * 2 + 0], q0);
            atomicAdd(&outacc[curg * 2 + 1], q1);
            atomicAdd(&cnt[curg], pc);
        }
    }
}

__global__ void k_out(const float* __restrict__ outacc, const float* __restrict__ cnt,
                      const float* __restrict__ bout, float* __restrict__ out, int n_graphs) {
    int i = blockIdx.x * 256 + threadIdx.x;
    if (i < n_graphs * 2) {
        int g = i >> 1, c = i & 1;
        out[i] = outacc[i] / fmaxf(cnt[g], 1.0f) + bout[c];
    }
}

extern "C" void kernel_launch(void* const* d_in, const int* in_sizes, int n_in,
                              void* d_out, int out_size, void* d_ws, size_t ws_size,
                              hipStream_t stream) {
    const int* x     = (const int*)d_in[0];
    const int* ei    = (const int*)d_in[1];
    const int* batch = (const int*)d_in[2];
    const float* se   = (const float*)d_in[4];
    const float* ce   = (const float*)d_in[5];
    const float* Win  = (const float*)d_in[6];
    const float* bin  = (const float*)d_in[7];
    const float* W1l  = (const float*)d_in[8];
    const float* b1   = (const float*)d_in[9];
    const float* W1r  = (const float*)d_in[10];
    const float* W2l  = (const float*)d_in[11];
    const float* b2   = (const float*)d_in[12];
    const float* W2r  = (const float*)d_in[13];
    const float* Wout = (const float*)d_in[14];
    const float* bout = (const float*)d_in[15];
    float* out = (float*)d_out;

    int n_nodes  = in_sizes[0] / 2;
    int n_edges  = in_sizes[1] / 2;
    int n_graphs = out_size / 2;
    const int* src = ei;
    const int* dst = ei + n_edges;
    int nb = (n_nodes + 255) >> 8;               // buckets (<= 512 for n<131072)

    char* p = (char*)d_ws;
    auto take = [&](size_t bytes) { char* r = p; p += (bytes + 255) & ~(size_t)255; return r; };
    unsigned* h1p    = (unsigned*)take((size_t)n_nodes * 32 * 4);
    unsigned* g1p    = (unsigned*)take((size_t)n_nodes * 32 * 4);
    unsigned* r1p    = (unsigned*)take((size_t)n_nodes * 32 * 4);
    int*      csrp   = (int*)take((size_t)n_edges * 4);
    int*      bedge  = (int*)take((size_t)n_edges * 4);
    int*      ntype  = (int*)take((size_t)n_nodes * 4);
    int*      deg_i  = (int*)take((size_t)n_nodes * 4);
    int*      off    = (int*)take((size_t)n_nodes * 4);
    float*    inv    = (float*)take((size_t)n_nodes * 4);
    int*      histT  = (int*)take((size_t)512 * NBLK * 4);
    int*      blkOff = (int*)take((size_t)512 * NBLK * 4);
    int*      btot   = (int*)take(512 * 4);
    int*      bbase  = (int*)take(512 * 4);
    float*    cnt    = (float*)take((size_t)n_graphs * 4);
    float*    outacc = (float*)take((size_t)n_graphs * 8);
    float*    hltab  = (float*)take(4096 * 4);
    float*    hrtab  = (float*)take(4096 * 4);

    int nbN = (n_nodes + 255) / 256;

    k_tabs<<<64, 64, 0, stream>>>(se, ce, Win, bin, W1l, W1r, b1, hltab, hrtab);
    k_prep<<<nbN, 256, 0, stream>>>(x, ntype, cnt, outacc, n_nodes, n_graphs);
    k_hist<<<NBLK, 256, 0, stream>>>(dst, histT, n_edges, nb);
    k_bscan<<<nb, 512, 0, stream>>>(histT, blkOff, btot);
    k_bscan2<<<1, 512, 0, stream>>>(btot, bbase, nb);
    k_scatter<<<NBLK, 256, 0, stream>>>(src, dst, ntype, bbase, blkOff, bedge, n_edges, nb);
    k_bsort<<<nb, 256, 0, stream>>>(bedge, bbase, btot, csrp, deg_i, off, inv, n_nodes);
    k_gather1<<<2048, 256, 0, stream>>>(csrp, off, deg_i, inv, ntype, hltab, hrtab, h1p, n_nodes);
    k_lin2<<<768, 256, 0, stream>>>(h1p, W2l, W2r, b2, g1p, r1p, n_nodes);
    k_gather2<<<2048, 256, 0, stream>>>(csrp, off, deg_i, inv, g1p, r1p, batch, Wout,
                                        outacc, cnt, n_nodes);
    k_out<<<(n_graphs * 2 + 255) / 256, 256, 0, stream>>>(outacc, cnt, bout, out, n_graphs);
}

// Round 11
// 132.043 us; speedup vs baseline: 7.8848x; 1.1812x over previous
//
#include <hip/hip_runtime.h>
#include <hip/hip_bf16.h>

// ---------------------------------------------------------------------------
// GNN classifier on MI355X.
//   h0 = relu([shape_emb[x0]|color_emb[x1]] @ W_in + b_in)   -> 64-entry table
//   conv1: h1 = relu( seg_sum(hltab[type[src]],dst)/deg + hrtab[type] )
//   conv2 by linearity:  g1 = h1@W2l, r1 = h1@W2r + b2  (bf16 MFMA GEMM)
//          h2 = relu( seg_sum(g1[src],dst)/deg + r1 )
//   out   = seg_sum(h2@W_out, batch)/cnt + b_out   (fused into the gather)
//
// R2: full-unroll spill lesson. R3: sorted batch -> deferred pooling flush.
// R4: no atomic-with-return on critical path. R5: coalesced edge loads +
// __shfl broadcast. R6: packed-bf16 intermediates halve gather traffic.
// R7: bucketed LDS sort replaces 1.2M device-scope atomics. R8: feature-pair
// lanes double gather2 MLP. R9: h1/r1 bf16; fused tab kernels.
// R10: (a) k_lin2 rewritten on mfma_f32_16x16x32_bf16 (h1 already bf16;
//      weights bf16 per-block): 21us VALU GEMM -> ~8us memory-bound.
//      (b) dispatches 11 -> 8: tabs+prep+hist as disjoint block ranges of one
//      launch; k_bscan2 deleted (bucket bases recomputed by a wave scan of
//      btot inside k_scatter / k_bsort).
// ---------------------------------------------------------------------------

#define NBLK 512   // blocks used by hist / scatter (chunked edge partition)

typedef __attribute__((ext_vector_type(8))) short bf16x8;
typedef __attribute__((ext_vector_type(4))) float f32x4;

__device__ __forceinline__ unsigned bf16rn(float x) {
    unsigned b = __float_as_uint(x);
    return (b + 0x7FFFu + ((b >> 16) & 1u)) >> 16;       // round-to-nearest-even
}
__device__ __forceinline__ unsigned bf16pack2(float lo, float hi) {
    return bf16rn(lo) | (bf16rn(hi) << 16);
}

// exclusive scan of btot[0..nb) into bb[0..512) (LDS), done by wave 0.
__device__ __forceinline__ void scan_btot(const int* __restrict__ btot, int nb,
                                          int* __restrict__ bb) {
    int tid = threadIdx.x;
    if (tid < 64) {
        int v[8]; int s = 0;
#pragma unroll
        for (int e = 0; e < 8; ++e) {
            int idx = tid * 8 + e;
            v[e] = s;
            s += (idx < nb) ? btot[idx] : 0;
        }
        int ex = s;
#pragma unroll
        for (int ofs = 1; ofs < 64; ofs <<= 1) {
            int t = __shfl_up(ex, ofs);
            if (tid >= ofs) ex += t;
        }
        ex -= s;                                  // exclusive prefix of lane sums
#pragma unroll
        for (int e = 0; e < 8; ++e) bb[tid * 8 + e] = ex + v[e];
    }
    __syncthreads();
}

// fused front-end: blocks [0,NBLK) histogram; [NBLK,NBLK+64) build tables;
// [NBLK+64, ...) ntype + accumulator zeroing. Disjoint roles, no stragglers.
__global__ __launch_bounds__(256) void k_front(
    const int* __restrict__ dst, int* __restrict__ histT, int n_edges, int nb,
    const float* __restrict__ se, const float* __restrict__ ce,
    const float* __restrict__ Win, const float* __restrict__ bin,
    const float* __restrict__ W1l, const float* __restrict__ W1r,
    const float* __restrict__ b1, float* __restrict__ hltab, float* __restrict__ hrtab,
    const int* __restrict__ x, int* __restrict__ ntype,
    float* __restrict__ cnt, float* __restrict__ outacc, int n_nodes, int n_graphs) {
    int blk = blockIdx.x, tid = threadIdx.x;
    if (blk < NBLK) {                                       // ---- histogram
        __shared__ int h[512];
        for (int i = tid; i < nb; i += 256) h[i] = 0;
        __syncthreads();
        int per = (n_edges + NBLK - 1) / NBLK;
        int e0 = blk * per;
        int e1 = e0 + per; if (e1 > n_edges) e1 = n_edges;
        for (int e = e0 + tid; e < e1; e += 256)
            atomicAdd(&h[dst[e] >> 8], 1);
        __syncthreads();
        for (int i = tid; i < nb; i += 256)
            histT[(size_t)i * NBLK + blk] = h[i];
    } else if (blk < NBLK + 64) {                           // ---- tables
        __shared__ float sse[64], sce[64], sh0[64];
        int t = blk - NBLK, j = tid;
        if (j < 64) {
            int s = t >> 3, c = t & 7;
            sse[j] = se[s * 64 + j];
            sce[j] = ce[c * 64 + j];
        }
        __syncthreads();
        if (j < 64) {
            float acc = bin[j];
            for (int k = 0; k < 64; ++k) {
                acc += sse[k] * Win[k * 64 + j];
                acc += sce[k] * Win[(64 + k) * 64 + j];
            }
            sh0[j] = fmaxf(acc, 0.f);
        }
        __syncthreads();
        if (j < 64) {
            float al = 0.f, ar = b1[j];
            for (int k = 0; k < 64; ++k) {
                float h = sh0[k];
                al += h * W1l[k * 64 + j];
                ar += h * W1r[k * 64 + j];
            }
            hltab[t * 64 + j] = al;
            hrtab[t * 64 + j] = ar;
        }
    } else {                                                // ---- prep + zero
        int n = (blk - NBLK - 64) * 256 + tid;
        if (n < n_nodes) {
            int2 v = *(const int2*)(x + 2 * (size_t)n);
            ntype[n] = v.x * 8 + v.y;
        }
        if (n < n_graphs) cnt[n] = 0.f;
        if (n < 2 * n_graphs) outacc[n] = 0.f;
    }
}

// per-bucket exclusive scan over the NBLK block counts.
__global__ void k_bscan(const int* __restrict__ histT, int* __restrict__ blockOff,
                        int* __restrict__ btot) {
    __shared__ int sbuf[2][512];
    int b = blockIdx.x, tid = threadIdx.x;
    int d = histT[(size_t)b * NBLK + tid];
    int cur = 0;
    sbuf[0][tid] = d;
    __syncthreads();
    for (int ofs = 1; ofs < 512; ofs <<= 1) {
        int v = sbuf[cur][tid];
        if (tid >= ofs) v += sbuf[cur][tid - ofs];
        sbuf[cur ^ 1][tid] = v;
        cur ^= 1;
        __syncthreads();
    }
    blockOff[(size_t)b * NBLK + tid] = sbuf[cur][tid] - d;
    if (tid == 511) btot[b] = sbuf[cur][tid];
}

// scatter edges into bucket-grouped order; bucket bases recomputed locally.
__global__ __launch_bounds__(256) void k_scatter(
    const int* __restrict__ src, const int* __restrict__ dst,
    const int* __restrict__ ntype, const int* __restrict__ btot,
    const int* __restrict__ blockOff, int* __restrict__ bedge,
    int n_edges, int nb) {
    __shared__ int bb[512];
    __shared__ int cur[512];
    int tid = threadIdx.x, blk = blockIdx.x;
    scan_btot(btot, nb, bb);
    for (int i = tid; i < nb; i += 256)
        cur[i] = bb[i] + blockOff[(size_t)i * NBLK + blk];
    __syncthreads();
    int per = (n_edges + NBLK - 1) / NBLK;
    int e0 = blk * per;
    int e1 = e0 + per; if (e1 > n_edges) e1 = n_edges;
    for (int e = e0 + tid; e < e1; e += 256) {
        int d = dst[e], s = src[e];
        int pos = atomicAdd(&cur[d >> 8], 1);       // LDS atomic (fast)
        bedge[pos] = s | (ntype[s] << 17) | ((d & 255) << 23);
    }
}

// per-bucket 256-way counting sort in LDS; emits deg/off/inv + final csrp.
__global__ __launch_bounds__(256) void k_bsort(
    const int* __restrict__ bedge, const int* __restrict__ btot,
    int* __restrict__ csrp, int* __restrict__ deg, int* __restrict__ off,
    float* __restrict__ inv, int n_nodes, int nb) {
    __shared__ int bb[512];
    __shared__ int cnt[256];
    __shared__ int sbuf[2][256];
    __shared__ int loff[256];
    int b = blockIdx.x, tid = threadIdx.x;
    scan_btot(btot, nb, bb);
    int base = bb[b], tot = btot[b];
    cnt[tid] = 0;
    __syncthreads();
    for (int i = tid; i < tot; i += 256)
        atomicAdd(&cnt[(bedge[base + i] >> 23) & 255], 1);
    __syncthreads();
    int d = cnt[tid];
    int cur = 0;
    sbuf[0][tid] = d;
    __syncthreads();
    for (int ofs = 1; ofs < 256; ofs <<= 1) {
        int v = sbuf[cur][tid];
        if (tid >= ofs) v += sbuf[cur][tid - ofs];
        sbuf[cur ^ 1][tid] = v;
        cur ^= 1;
        __syncthreads();
    }
    loff[tid] = sbuf[cur][tid] - d;                  // exclusive within bucket
    __syncthreads();
    int n = b * 256 + tid;
    if (n < n_nodes) {
        deg[n] = d;
        off[n] = base + loff[tid];
        inv[n] = 1.0f / fmaxf((float)d, 1.0f);
    }
    cnt[tid] = loff[tid];                            // reuse as cursor
    __syncthreads();
    for (int i = tid; i < tot; i += 256) {
        int v = bedge[base + i];
        int pos = atomicAdd(&cnt[(v >> 23) & 255], 1);
        csrp[base + pos] = (v & 0x1FFFF) | (((v >> 17) & 63) << 20);
    }
}

// ---- compute kernels --------------------------------------------------------

// conv1; h1 written as PACKED BF16 rows.
__global__ __launch_bounds__(256) void k_gather1(
    const int* __restrict__ csrp, const int* __restrict__ off,
    const int* __restrict__ deg_i, const float* __restrict__ inv,
    const int* __restrict__ ntype, const float* __restrict__ hltab,
    const float* __restrict__ hrtab, unsigned* __restrict__ h1p, int n_nodes) {
    __shared__ float tl[4096];
    __shared__ float tr_[4096];
    for (int i = threadIdx.x; i < 4096; i += 256) { tl[i] = hltab[i]; tr_[i] = hrtab[i]; }
    __syncthreads();
    int lane = threadIdx.x & 63;
    int w = blockIdx.x * 4 + (threadIdx.x >> 6);
    int nw = gridDim.x * 4;
    int per = (n_nodes + nw - 1) / nw;
    int n0 = w * per;
    int n1 = n0 + per; if (n1 > n_nodes) n1 = n_nodes;
    for (int cb = n0; cb < n1; cb += 64) {
        int cn = n1 - cb; if (cn > 64) cn = 64;
        int voff = 0, vdeg = 0, vnt = 0; float vinv = 0.f;
        if (lane < cn) {
            voff = off[cb + lane]; vdeg = deg_i[cb + lane];
            vinv = inv[cb + lane]; vnt  = ntype[cb + lane];
        }
        for (int j = 0; j < cn; ++j) {
            int o = __shfl(voff, j), d = __shfl(vdeg, j);
            float iv = __shfl(vinv, j);
            int tn = __shfl(vnt, j);
            float acc = 0.f;
            for (int base = 0; base < d; base += 64) {
                int rem = d - base; if (rem > 64) rem = 64;
                int v = (lane < rem) ? csrp[o + base + lane] : 0;
                int full = rem & ~3;
                for (int k = 0; k < full; k += 4) {
                    int t0 = __shfl(v, k)     >> 20;
                    int t1 = __shfl(v, k + 1) >> 20;
                    int t2 = __shfl(v, k + 2) >> 20;
                    int t3 = __shfl(v, k + 3) >> 20;
                    acc += (tl[t0 * 64 + lane] + tl[t1 * 64 + lane]) +
                           (tl[t2 * 64 + lane] + tl[t3 * 64 + lane]);
                }
                for (int k = full; k < rem; ++k)
                    acc += tl[(__shfl(v, k) >> 20) * 64 + lane];
            }
            float val = fmaxf(acc * iv + tr_[tn * 64 + lane], 0.f);
            float vhi = __shfl_down(val, 1);
            if (!(lane & 1))
                h1p[(size_t)(cb + j) * 32 + (lane >> 1)] = bf16pack2(val, vhi);
        }
    }
}

// conv2 dense GEMMs on MFMA bf16 (R10): g1 = h1@W2l, r1 = h1@W2r + b2.
// Tile = 64 nodes; wave w owns rows 16w..16w+15. A-frag straight from h1p
// (layout already matches: lane holds row l&15, k = (l>>4)*8..+7). B-frags
// pre-arranged per-lane in LDS (conflict-free ds_read_b128).
__global__ __launch_bounds__(256) void k_lin2(
    const unsigned* __restrict__ h1p, const float* __restrict__ W2l,
    const float* __restrict__ W2r, const float* __restrict__ b2,
    unsigned* __restrict__ g1p, unsigned* __restrict__ r1p, int n_nodes) {
    __shared__ uint4 sB[2][4][2][64];    // [mat][nblk][kstep][lane]
    __shared__ float sb2[64];
    int tid = threadIdx.x;
    for (int i = tid; i < 1024; i += 256) {
        int mat = i >> 9, nb = (i >> 7) & 3, ks = (i >> 6) & 1, ln = i & 63;
        const float* W = mat ? W2r : W2l;
        int col = nb * 16 + (ln & 15);
        int kbase = ks * 32 + (ln >> 4) * 8;
        unsigned p0 = bf16pack2(W[(kbase + 0) * 64 + col], W[(kbase + 1) * 64 + col]);
        unsigned p1 = bf16pack2(W[(kbase + 2) * 64 + col], W[(kbase + 3) * 64 + col]);
        unsigned p2 = bf16pack2(W[(kbase + 4) * 64 + col], W[(kbase + 5) * 64 + col]);
        unsigned p3 = bf16pack2(W[(kbase + 6) * 64 + col], W[(kbase + 7) * 64 + col]);
        sB[mat][nb][ks][ln] = make_uint4(p0, p1, p2, p3);
    }
    if (tid < 64) sb2[tid] = b2[tid];
    __syncthreads();

    int w = tid >> 6, lane = tid & 63;
    int kg = lane >> 4;
    unsigned short* gh = (unsigned short*)g1p;
    unsigned short* rh = (unsigned short*)r1p;
    int ntile = (n_nodes + 63) >> 6;

    for (int t = blockIdx.x; t < ntile; t += gridDim.x) {
        int n0 = t << 6;
        int row = n0 + w * 16 + (lane & 15);
        int rowc = row < n_nodes ? row : n_nodes - 1;
        uint4 a0u = *(const uint4*)(h1p + (size_t)rowc * 32 + kg * 4);
        uint4 a1u = *(const uint4*)(h1p + (size_t)rowc * 32 + 16 + kg * 4);
        bf16x8 A0 = __builtin_bit_cast(bf16x8, a0u);
        bf16x8 A1 = __builtin_bit_cast(bf16x8, a1u);

        f32x4 accg[4], accr[4];
#pragma unroll
        for (int nb = 0; nb < 4; ++nb) {
            f32x4 z = {0.f, 0.f, 0.f, 0.f};
            bf16x8 Bg0 = __builtin_bit_cast(bf16x8, sB[0][nb][0][lane]);
            bf16x8 Bg1 = __builtin_bit_cast(bf16x8, sB[0][nb][1][lane]);
            bf16x8 Br0 = __builtin_bit_cast(bf16x8, sB[1][nb][0][lane]);
            bf16x8 Br1 = __builtin_bit_cast(bf16x8, sB[1][nb][1][lane]);
            accg[nb] = __builtin_amdgcn_mfma_f32_16x16x32_bf16(A0, Bg0, z, 0, 0, 0);
            accg[nb] = __builtin_amdgcn_mfma_f32_16x16x32_bf16(A1, Bg1, accg[nb], 0, 0, 0);
            accr[nb] = __builtin_amdgcn_mfma_f32_16x16x32_bf16(A0, Br0, z, 0, 0, 0);
            accr[nb] = __builtin_amdgcn_mfma_f32_16x16x32_bf16(A1, Br1, accr[nb], 0, 0, 0);
        }
        // C/D layout (verified, guide §3): col = lane&15, row = (lane>>4)*4 + reg
#pragma unroll
        for (int nb = 0; nb < 4; ++nb) {
            int col = nb * 16 + (lane & 15);
            float bias = sb2[col];
#pragma unroll
            for (int reg = 0; reg < 4; ++reg) {
                int r2 = n0 + w * 16 + kg * 4 + reg;
                if (r2 < n_nodes) {
                    gh[(size_t)r2 * 64 + col] = (unsigned short)bf16rn(accg[nb][reg]);
                    rh[(size_t)r2 * 64 + col] = (unsigned short)bf16rn(accr[nb][reg] + bias);
                }
            }
        }
    }
}

// conv2 aggregation + relu + W_out + pooling (R8 feature-pair scheme).
__global__ __launch_bounds__(256) void k_gather2(
    const int* __restrict__ csrp, const int* __restrict__ off,
    const int* __restrict__ deg_i, const float* __restrict__ inv,
    const unsigned* __restrict__ g1p, const unsigned* __restrict__ r1p,
    const int* __restrict__ batch, const float* __restrict__ Wout,
    float* __restrict__ outacc, float* __restrict__ cnt, int n_nodes) {
    int lane = threadIdx.x & 63;
    int li = lane & 31;                       // feature-pair index (uint in row)
    int hi = lane >> 5;                       // 0: even edges, 1: odd edges
    float hm = hi ? 0.f : 1.f;                // mask so halves don't double-count
    int w = blockIdx.x * 4 + (threadIdx.x >> 6);
    int nw = gridDim.x * 4;
    int per = (n_nodes + nw - 1) / nw;
    int n0 = w * per;
    int n1 = n0 + per; if (n1 > n_nodes) n1 = n_nodes;
    float4 wo = *(const float4*)(Wout + li * 4);   // W[2li][0..1], W[2li+1][0..1]
    float p0 = 0.f, p1 = 0.f, pc = 0.f;
    int curg = -1;
    for (int cb = n0; cb < n1; cb += 64) {
        int cn = n1 - cb; if (cn > 64) cn = 64;
        int voff = 0, vdeg = 0, vbat = 0; float vinv = 0.f;
        if (lane < cn) {
            voff = off[cb + lane]; vdeg = deg_i[cb + lane];
            vinv = inv[cb + lane]; vbat = batch[cb + lane];
        }
        for (int j = 0; j < cn; ++j) {
            int o = __shfl(voff, j), d = __shfl(vdeg, j), g = __shfl(vbat, j);
            float iv = __shfl(vinv, j);
            float accL = 0.f, accH = 0.f;     // features 2li, 2li+1
            for (int base = 0; base < d; base += 64) {
                int rem = d - base; if (rem > 64) rem = 64;
                int v = (lane < rem) ? csrp[o + base + lane] : 0;
                int k = 0;
                int full8 = rem & ~7;
                for (; k < full8; k += 8) {   // 4 pairs = 8 edges, 4 loads in flight
                    int a0 = __shfl(v, k),     a1 = __shfl(v, k + 1);
                    int a2 = __shfl(v, k + 2), a3 = __shfl(v, k + 3);
                    int a4 = __shfl(v, k + 4), a5 = __shfl(v, k + 5);
                    int a6 = __shfl(v, k + 6), a7 = __shfl(v, k + 7);
                    size_t s0 = (size_t)((hi ? a1 : a0) & 0xFFFFF);
                    size_t s1 = (size_t)((hi ? a3 : a2) & 0xFFFFF);
                    size_t s2 = (size_t)((hi ? a5 : a4) & 0xFFFFF);
                    size_t s3 = (size_t)((hi ? a7 : a6) & 0xFFFFF);
                    unsigned u0 = g1p[s0 * 32 + li];
                    unsigned u1 = g1p[s1 * 32 + li];
                    unsigned u2 = g1p[s2 * 32 + li];
                    unsigned u3 = g1p[s3 * 32 + li];
                    accL += (__uint_as_float(u0 << 16) + __uint_as_float(u1 << 16)) +
                            (__uint_as_float(u2 << 16) + __uint_as_float(u3 << 16));
                    accH += (__uint_as_float(u0 & 0xFFFF0000u) + __uint_as_float(u1 & 0xFFFF0000u)) +
                            (__uint_as_float(u2 & 0xFFFF0000u) + __uint_as_float(u3 & 0xFFFF0000u));
                }
                for (; k + 1 < rem; k += 2) { // single pair
                    int a0 = __shfl(v, k), a1 = __shfl(v, k + 1);
                    size_t s = (size_t)((hi ? a1 : a0) & 0xFFFFF);
                    unsigned u = g1p[s * 32 + li];
                    accL += __uint_as_float(u << 16);
                    accH += __uint_as_float(u & 0xFFFF0000u);
                }
                if (k < rem) {                // odd tail: only hi==0 half counts
                    size_t s = (size_t)(__shfl(v, k) & 0xFFFFF);
                    unsigned u = g1p[s * 32 + li];
                    accL += hm * __uint_as_float(u << 16);
                    accH += hm * __uint_as_float(u & 0xFFFF0000u);
                }
            }
            accL += __shfl_xor(accL, 32);     // merge even/odd halves
            accH += __shfl_xor(accH, 32);
            unsigned ur = r1p[(size_t)(cb + j) * 32 + li];
            float v0 = fmaxf(accL * iv + __uint_as_float(ur << 16), 0.f);
            float v1 = fmaxf(accH * iv + __uint_as_float(ur & 0xFFFF0000u), 0.f);
            if (g != curg) {                  // wave-uniform branch
                float q0 = p0, q1 = p1;
#pragma unroll
                for (int m = 1; m < 64; m <<= 1) { q0 += __shfl_xor(q0, m); q1 += __shfl_xor(q1, m); }
                if (lane == 0 && curg >= 0) {
                    atomicAdd(&outacc[curg * 2 + 0], q0);
                    atomicAdd(&outacc[curg * 2 + 1], q1);
                    atomicAdd(&cnt[curg], pc);
                }
                p0 = 0.f; p1 = 0.f; pc = 0.f; curg = g;
            }
            p0 += hm * (v0 * wo.x + v1 * wo.z);
            p1 += hm * (v0 * wo.y + v1 * wo.w);
            pc += 1.0f;
        }
    }
    {
        float q0 = p0, q1 = p1;
#pragma unroll
        for (int m = 1; m < 64; m <<= 1) { q0 += __shfl_xor(q0, m); q1 += __shfl_xor(q1, m); }
        if (lane == 0 && curg >= 0) {
            atomicAdd(&outacc[curg * 2 + 0], q0);
            atomicAdd(&outacc[curg * 2 + 1], q1);
            atomicAdd(&cnt[curg], pc);
        }
    }
}

__global__ void k_out(const float* __restrict__ outacc, const float* __restrict__ cnt,
                      const float* __restrict__ bout, float* __restrict__ out, int n_graphs) {
    int i = blockIdx.x * 256 + threadIdx.x;
    if (i < n_graphs * 2) {
        int g = i >> 1, c = i & 1;
        out[i] = outacc[i] / fmaxf(cnt[g], 1.0f) + bout[c];
    }
}

extern "C" void kernel_launch(void* const* d_in, const int* in_sizes, int n_in,
                              void* d_out, int out_size, void* d_ws, size_t ws_size,
                              hipStream_t stream) {
    const int* x     = (const int*)d_in[0];
    const int* ei    = (const int*)d_in[1];
    const int* batch = (const int*)d_in[2];
    const float* se   = (const float*)d_in[4];
    const float* ce   = (const float*)d_in[5];
    const float* Win  = (const float*)d_in[6];
    const float* bin  = (const float*)d_in[7];
    const float* W1l  = (const float*)d_in[8];
    const float* b1   = (const float*)d_in[9];
    const float* W1r  = (const float*)d_in[10];
    const float* W2l  = (const float*)d_in[11];
    const float* b2   = (const float*)d_in[12];
    const float* W2r  = (const float*)d_in[13];
    const float* Wout = (const float*)d_in[14];
    const float* bout = (const float*)d_in[15];
    float* out = (float*)d_out;

    int n_nodes  = in_sizes[0] / 2;
    int n_edges  = in_sizes[1] / 2;
    int n_graphs = out_size / 2;
    const int* src = ei;
    const int* dst = ei + n_edges;
    int nb = (n_nodes + 255) >> 8;               // buckets (<= 512 for n<131072)

    char* p = (char*)d_ws;
    auto take = [&](size_t bytes) { char* r = p; p += (bytes + 255) & ~(size_t)255; return r; };
    unsigned* h1p    = (unsigned*)take((size_t)n_nodes * 32 * 4);
    unsigned* g1p    = (unsigned*)take((size_t)n_nodes * 32 * 4);
    unsigned* r1p    = (unsigned*)take((size_t)n_nodes * 32 * 4);
    int*      csrp   = (int*)take((size_t)n_edges * 4);
    int*      bedge  = (int*)take((size_t)n_edges * 4);
    int*      ntype  = (int*)take((size_t)n_nodes * 4);
    int*      deg_i  = (int*)take((size_t)n_nodes * 4);
    int*      off    = (int*)take((size_t)n_nodes * 4);
    float*    inv    = (float*)take((size_t)n_nodes * 4);
    int*      histT  = (int*)take((size_t)512 * NBLK * 4);
    int*      blkOff = (int*)take((size_t)512 * NBLK * 4);
    int*      btot   = (int*)take(512 * 4);
    float*    cnt    = (float*)take((size_t)n_graphs * 4);
    float*    outacc = (float*)take((size_t)n_graphs * 8);
    float*    hltab  = (float*)take(4096 * 4);
    float*    hrtab  = (float*)take(4096 * 4);

    int nbN = (n_nodes + 255) / 256;

    k_front<<<NBLK + 64 + nbN, 256, 0, stream>>>(dst, histT, n_edges, nb,
                                                 se, ce, Win, bin, W1l, W1r, b1,
                                                 hltab, hrtab, x, ntype, cnt, outacc,
                                                 n_nodes, n_graphs);
    k_bscan<<<nb, 512, 0, stream>>>(histT, blkOff, btot);
    k_scatter<<<NBLK, 256, 0, stream>>>(src, dst, ntype, btot, blkOff, bedge, n_edges, nb);
    k_bsort<<<nb, 256, 0, stream>>>(bedge, btot, csrp, deg_i, off, inv, n_nodes, nb);
    k_gather1<<<2048, 256, 0, stream>>>(csrp, off, deg_i, inv, ntype, hltab, hrtab, h1p, n_nodes);
    k_lin2<<<1024, 256, 0, stream>>>(h1p, W2l, W2r, b2, g1p, r1p, n_nodes);
    k_gather2<<<2048, 256, 0, stream>>>(csrp, off, deg_i, inv, g1p, r1p, batch, Wout,
                                        outacc, cnt, n_nodes);
    k_out<<<(n_graphs * 2 + 255) / 256, 256, 0, stream>>>(outacc, cnt, bout, out, n_graphs);
}